// Round 1
// baseline (1421.779 us; speedup 1.0000x reference)
//
#include <hip/hip_runtime.h>
#include <hip/hip_bf16.h>
#include <math.h>

#define BQ 100
#define SB 8
#define SS 4096
#define DD 256
#define HH 8
#define HDD 32

// ---------------- any_pos: OR-reduce (prev_mask>0) over S per (b,q) row ----
__global__ void anypos_kernel(const float* __restrict__ mask, int* __restrict__ anyp, int Slen) {
    int row = blockIdx.x, tid = threadIdx.x;
    __shared__ int red[256];
    int l = 0;
    for (int s = tid; s < Slen; s += 256)
        l |= (mask[(size_t)row * Slen + s] > 0.f) ? 1 : 0;
    red[tid] = l; __syncthreads();
    for (int off = 128; off > 0; off >>= 1) {
        if (tid < off) red[tid] |= red[tid + off];
        __syncthreads();
    }
    if (tid == 0) anyp[row] = red[0];
}

// ---------------- LayerNorm over D=256, one block per row -------------------
__global__ void ln_kernel(const float* __restrict__ x, const float* __restrict__ g,
                          const float* __restrict__ b, float* __restrict__ y) {
    int row = blockIdx.x, tid = threadIdx.x;
    __shared__ float red[256];
    float v = x[(size_t)row * DD + tid];
    red[tid] = v; __syncthreads();
    for (int off = 128; off > 0; off >>= 1) {
        if (tid < off) red[tid] += red[tid + off];
        __syncthreads();
    }
    float mu = red[0] * (1.0f / DD);
    __syncthreads();
    float dv = v - mu;
    red[tid] = dv * dv; __syncthreads();
    for (int off = 128; off > 0; off >>= 1) {
        if (tid < off) red[tid] += red[tid + off];
        __syncthreads();
    }
    float var = red[0] * (1.0f / DD);
    float r = rsqrtf(var + 1e-5f);
    y[(size_t)row * DD + tid] = dv * r * g[tid] + b[tid];
}

// ---------------- generic NT GEMM: C[m,n] = dot(A[m,:],W[n,:]) + bias[n] ----
// mode 0: none; 1: gelu(exact); 2: += res[m,n]
#define BM 64
#define BN 64
#define BK 16
__global__ void gemm_nt(const float* __restrict__ A, const float* __restrict__ W,
                        const float* __restrict__ bias, const float* __restrict__ res,
                        float* __restrict__ C, int M, int N, int K, int mode) {
    __shared__ float As[BK][BM + 1];
    __shared__ float Ws[BK][BN + 1];
    int tid = threadIdx.x;
    int tx = tid % 16, ty = tid / 16;
    int lrow = tid / 4;            // 0..63
    int lcol = (tid % 4) * 4;      // 0,4,8,12
    float acc[4][4] = {};

    for (int k0 = 0; k0 < K; k0 += BK) {
        int am = blockIdx.y * BM + lrow;
        float4 av = make_float4(0.f, 0.f, 0.f, 0.f);
        if (am < M) av = *(const float4*)(A + (size_t)am * K + k0 + lcol);
        As[lcol + 0][lrow] = av.x; As[lcol + 1][lrow] = av.y;
        As[lcol + 2][lrow] = av.z; As[lcol + 3][lrow] = av.w;
        int wn = blockIdx.x * BN + lrow;   // N is always a multiple of 64 here
        float4 wv = *(const float4*)(W + (size_t)wn * K + k0 + lcol);
        Ws[lcol + 0][lrow] = wv.x; Ws[lcol + 1][lrow] = wv.y;
        Ws[lcol + 2][lrow] = wv.z; Ws[lcol + 3][lrow] = wv.w;
        __syncthreads();
#pragma unroll
        for (int kk = 0; kk < BK; kk++) {
            float aR[4], bR[4];
#pragma unroll
            for (int i = 0; i < 4; i++) aR[i] = As[kk][ty * 4 + i];
#pragma unroll
            for (int j = 0; j < 4; j++) bR[j] = Ws[kk][tx * 4 + j];
#pragma unroll
            for (int i = 0; i < 4; i++)
#pragma unroll
                for (int j = 0; j < 4; j++) acc[i][j] += aR[i] * bR[j];
        }
        __syncthreads();
    }

#pragma unroll
    for (int i = 0; i < 4; i++) {
        int m = blockIdx.y * BM + ty * 4 + i;
        if (m >= M) continue;
#pragma unroll
        for (int j = 0; j < 4; j++) {
            int n = blockIdx.x * BN + tx * 4 + j;
            float v = acc[i][j] + bias[n];
            if (mode == 1) {
                v = 0.5f * v * (1.0f + erff(v * 0.70710678118654752f));
            } else if (mode == 2) {
                v += res[(size_t)m * N + n];
            }
            C[(size_t)m * N + n] = v;
        }
    }
}

// ---------------- attention: one block per (q,h,b); 2-pass softmax in LDS ---
// scores[s] = scale * dot(Q[qrow, qo0+h*32 .. +32], K[b*Slen+s, ko0+h*32 ..])
// + optional mask bias. Out[qrow, oo0+h*32+d] = sum_s p[s] V[b*Slen+s, vo0+h*32+d]
__global__ void attn_kernel(const float* __restrict__ Qm, int sq, int qo0,
                            const float* __restrict__ Km, int sk, int ko0,
                            const float* __restrict__ Vm, int sv, int vo0,
                            const float* __restrict__ mask, const int* __restrict__ anyp,
                            float* __restrict__ Out, int so, int oo0,
                            int Slen, int Qlen, float scale) {
    int q = blockIdx.x, h = blockIdx.y, b = blockIdx.z;
    int tid = threadIdx.x;
    __shared__ float qv[32];
    __shared__ float sc[4096];
    __shared__ float red[256];
    __shared__ float part[8][33];
    int qrow = b * Qlen + q;
    if (tid < 32) qv[tid] = Qm[(size_t)qrow * sq + qo0 + h * HDD + tid] * scale;
    __syncthreads();

    bool use_mask = (mask != nullptr) && (anyp[qrow] != 0);
    float lmax = -1e30f;
    for (int s = tid; s < Slen; s += 256) {
        const float* kp = Km + (size_t)(b * Slen + s) * sk + ko0 + h * HDD;
        float dot = 0.f;
#pragma unroll
        for (int d = 0; d < HDD; d += 4) {
            float4 k4 = *(const float4*)(kp + d);
            dot += qv[d] * k4.x + qv[d + 1] * k4.y + qv[d + 2] * k4.z + qv[d + 3] * k4.w;
        }
        if (use_mask && !(mask[(size_t)qrow * Slen + s] > 0.f)) dot -= 10000.f;
        sc[s] = dot;
        lmax = fmaxf(lmax, dot);
    }
    red[tid] = lmax; __syncthreads();
    for (int off = 128; off > 0; off >>= 1) {
        if (tid < off) red[tid] = fmaxf(red[tid], red[tid + off]);
        __syncthreads();
    }
    float m = red[0];
    __syncthreads();
    float lsum = 0.f;
    for (int s = tid; s < Slen; s += 256) {
        float e = __expf(sc[s] - m);
        sc[s] = e;
        lsum += e;
    }
    red[tid] = lsum; __syncthreads();
    for (int off = 128; off > 0; off >>= 1) {
        if (tid < off) red[tid] += red[tid + off];
        __syncthreads();
    }
    float inv = 1.0f / red[0];

    int d = tid & 31, g = tid >> 5;
    float acc = 0.f;
    for (int s = g; s < Slen; s += 8)
        acc += sc[s] * Vm[(size_t)(b * Slen + s) * sv + vo0 + h * HDD + d];
    part[g][d] = acc; __syncthreads();
    if (g == 0) {
        float t = 0.f;
#pragma unroll
        for (int gg = 0; gg < 8; gg++) t += part[gg][d];
        Out[(size_t)qrow * so + oo0 + h * HDD + d] = t * inv;
    }
}

extern "C" void kernel_launch(void* const* d_in, const int* in_sizes, int n_in,
                              void* d_out, int out_size, void* d_ws, size_t ws_size,
                              hipStream_t stream) {
    const float* queries    = (const float*)d_in[0];
    const float* pixel_feat = (const float*)d_in[1];
    const float* prev_mask  = (const float*)d_in[2];
    const float* cross_in_w  = (const float*)d_in[3];
    const float* cross_in_b  = (const float*)d_in[4];
    const float* cross_out_w = (const float*)d_in[5];
    const float* cross_out_b = (const float*)d_in[6];
    const float* self_in_w   = (const float*)d_in[7];
    const float* self_in_b   = (const float*)d_in[8];
    const float* self_out_w  = (const float*)d_in[9];
    const float* self_out_b  = (const float*)d_in[10];
    const float* ln_cross_g  = (const float*)d_in[11];
    const float* ln_cross_b  = (const float*)d_in[12];
    const float* ln_self_g   = (const float*)d_in[13];
    const float* ln_self_b   = (const float*)d_in[14];
    const float* ln_ffn_g    = (const float*)d_in[15];
    const float* ln_ffn_b    = (const float*)d_in[16];
    const float* ffn_w1 = (const float*)d_in[17];
    const float* ffn_b1 = (const float*)d_in[18];
    const float* ffn_w2 = (const float*)d_in[19];
    const float* ffn_b2 = (const float*)d_in[20];
    float* out = (float*)d_out;

    const int NQ = SB * BQ;        // 800 query rows
    const int NK = SB * SS;        // 32768 kv rows

    // workspace layout
    int*   anyp   = (int*)d_ws;                 // 800 ints (pad to 1024)
    float* ws     = (float*)d_ws + 1024;
    float* ln_buf   = ws;              ws += (size_t)NQ * DD;     // 204800
    float* q_cross  = ws;              ws += (size_t)NQ * DD;
    float* Kbuf     = ws;              ws += (size_t)NK * DD;     // 8.4M
    float* Vbuf     = ws;              ws += (size_t)NK * DD;
    float* attn_out = ws;              ws += (size_t)NQ * DD;
    float* queries1 = ws;              ws += (size_t)NQ * DD;
    float* qkv      = ws;              ws += (size_t)NQ * 3 * DD; // 614400
    float* attn2    = ws;              ws += (size_t)NQ * DD;
    float* queries2 = ws;              ws += (size_t)NQ * DD;
    float* ffn_h    = ws;              ws += (size_t)NQ * 4 * DD; // 819200

    const float scale = 0.17677669529663687f;  // 1/sqrt(32)

    // mask row flags
    anypos_kernel<<<NQ, 256, 0, stream>>>(prev_mask, anyp, SS);

    // ---- cross attention ----
    ln_kernel<<<NQ, 256, 0, stream>>>(queries, ln_cross_g, ln_cross_b, ln_buf);
    // q projection: (800x256)@(256x256)^T
    gemm_nt<<<dim3(DD / BN, (NQ + BM - 1) / BM), 256, 0, stream>>>(
        ln_buf, cross_in_w, cross_in_b, nullptr, q_cross, NQ, DD, DD, 0);
    // K projection: (32768x256)@(256x256)^T
    gemm_nt<<<dim3(DD / BN, NK / BM), 256, 0, stream>>>(
        pixel_feat, cross_in_w + (size_t)DD * DD, cross_in_b + DD, nullptr,
        Kbuf, NK, DD, DD, 0);
    // V projection
    gemm_nt<<<dim3(DD / BN, NK / BM), 256, 0, stream>>>(
        pixel_feat, cross_in_w + (size_t)2 * DD * DD, cross_in_b + 2 * DD, nullptr,
        Vbuf, NK, DD, DD, 0);
    attn_kernel<<<dim3(BQ, HH, SB), 256, 0, stream>>>(
        q_cross, DD, 0, Kbuf, DD, 0, Vbuf, DD, 0,
        prev_mask, anyp, attn_out, DD, 0, SS, BQ, scale);
    // out projection + residual
    gemm_nt<<<dim3(DD / BN, (NQ + BM - 1) / BM), 256, 0, stream>>>(
        attn_out, cross_out_w, cross_out_b, queries, queries1, NQ, DD, DD, 2);

    // ---- self attention ----
    ln_kernel<<<NQ, 256, 0, stream>>>(queries1, ln_self_g, ln_self_b, ln_buf);
    gemm_nt<<<dim3(3 * DD / BN, (NQ + BM - 1) / BM), 256, 0, stream>>>(
        ln_buf, self_in_w, self_in_b, nullptr, qkv, NQ, 3 * DD, DD, 0);
    attn_kernel<<<dim3(BQ, HH, SB), 256, 0, stream>>>(
        qkv, 3 * DD, 0, qkv, 3 * DD, DD, qkv, 3 * DD, 2 * DD,
        nullptr, nullptr, attn2, DD, 0, BQ, BQ, scale);
    gemm_nt<<<dim3(DD / BN, (NQ + BM - 1) / BM), 256, 0, stream>>>(
        attn2, self_out_w, self_out_b, queries1, queries2, NQ, DD, DD, 2);

    // ---- FFN ----
    ln_kernel<<<NQ, 256, 0, stream>>>(queries2, ln_ffn_g, ln_ffn_b, ln_buf);
    gemm_nt<<<dim3(4 * DD / BN, (NQ + BM - 1) / BM), 256, 0, stream>>>(
        ln_buf, ffn_w1, ffn_b1, nullptr, ffn_h, NQ, 4 * DD, DD, 1);
    gemm_nt<<<dim3(DD / BN, (NQ + BM - 1) / BM), 256, 0, stream>>>(
        ffn_h, ffn_w2, ffn_b2, queries2, out, NQ, DD, 4 * DD, 2);
}

// Round 2
// 721.720 us; speedup vs baseline: 1.9700x; 1.9700x over previous
//
#include <hip/hip_runtime.h>
#include <hip/hip_bf16.h>
#include <math.h>

#define BQ 100
#define SB 8
#define SS 4096
#define DD 256
#define HH 8
#define HDD 32

// ---------------- any_pos: OR-reduce (prev_mask>0) over S per (b,q) row ----
__global__ void anypos_kernel(const float* __restrict__ mask, int* __restrict__ anyp, int Slen) {
    int row = blockIdx.x, tid = threadIdx.x;
    __shared__ int red[256];
    int l = 0;
    for (int s = tid; s < Slen; s += 256)
        l |= (mask[(size_t)row * Slen + s] > 0.f) ? 1 : 0;
    red[tid] = l; __syncthreads();
    for (int off = 128; off > 0; off >>= 1) {
        if (tid < off) red[tid] |= red[tid + off];
        __syncthreads();
    }
    if (tid == 0) anyp[row] = red[0];
}

// ---------------- LayerNorm over D=256, one block per row -------------------
__global__ void ln_kernel(const float* __restrict__ x, const float* __restrict__ g,
                          const float* __restrict__ b, float* __restrict__ y) {
    int row = blockIdx.x, tid = threadIdx.x;
    __shared__ float red[256];
    float v = x[(size_t)row * DD + tid];
    red[tid] = v; __syncthreads();
    for (int off = 128; off > 0; off >>= 1) {
        if (tid < off) red[tid] += red[tid + off];
        __syncthreads();
    }
    float mu = red[0] * (1.0f / DD);
    __syncthreads();
    float dv = v - mu;
    red[tid] = dv * dv; __syncthreads();
    for (int off = 128; off > 0; off >>= 1) {
        if (tid < off) red[tid] += red[tid + off];
        __syncthreads();
    }
    float var = red[0] * (1.0f / DD);
    float r = rsqrtf(var + 1e-5f);
    y[(size_t)row * DD + tid] = dv * r * g[tid] + b[tid];
}

// ---------------- generic NT GEMM: C[m,n] = dot(A[m,:],W[n,:]) + bias[n] ----
// mode 0: none; 1: gelu(exact); 2: += res[m,n]
#define BM 64
#define BN 64
#define BK 16
__global__ void gemm_nt(const float* __restrict__ A, const float* __restrict__ W,
                        const float* __restrict__ bias, const float* __restrict__ res,
                        float* __restrict__ C, int M, int N, int K, int mode) {
    __shared__ float As[BK][BM + 1];
    __shared__ float Ws[BK][BN + 1];
    int tid = threadIdx.x;
    int tx = tid % 16, ty = tid / 16;
    int lrow = tid / 4;            // 0..63
    int lcol = (tid % 4) * 4;      // 0,4,8,12
    float acc[4][4] = {};

    for (int k0 = 0; k0 < K; k0 += BK) {
        int am = blockIdx.y * BM + lrow;
        float4 av = make_float4(0.f, 0.f, 0.f, 0.f);
        if (am < M) av = *(const float4*)(A + (size_t)am * K + k0 + lcol);
        As[lcol + 0][lrow] = av.x; As[lcol + 1][lrow] = av.y;
        As[lcol + 2][lrow] = av.z; As[lcol + 3][lrow] = av.w;
        int wn = blockIdx.x * BN + lrow;   // N is always a multiple of 64 here
        float4 wv = *(const float4*)(W + (size_t)wn * K + k0 + lcol);
        Ws[lcol + 0][lrow] = wv.x; Ws[lcol + 1][lrow] = wv.y;
        Ws[lcol + 2][lrow] = wv.z; Ws[lcol + 3][lrow] = wv.w;
        __syncthreads();
#pragma unroll
        for (int kk = 0; kk < BK; kk++) {
            float aR[4], bR[4];
#pragma unroll
            for (int i = 0; i < 4; i++) aR[i] = As[kk][ty * 4 + i];
#pragma unroll
            for (int j = 0; j < 4; j++) bR[j] = Ws[kk][tx * 4 + j];
#pragma unroll
            for (int i = 0; i < 4; i++)
#pragma unroll
                for (int j = 0; j < 4; j++) acc[i][j] += aR[i] * bR[j];
        }
        __syncthreads();
    }

#pragma unroll
    for (int i = 0; i < 4; i++) {
        int m = blockIdx.y * BM + ty * 4 + i;
        if (m >= M) continue;
#pragma unroll
        for (int j = 0; j < 4; j++) {
            int n = blockIdx.x * BN + tx * 4 + j;
            float v = acc[i][j] + bias[n];
            if (mode == 1) {
                v = 0.5f * v * (1.0f + erff(v * 0.70710678118654752f));
            } else if (mode == 2) {
                v += res[(size_t)m * N + n];
            }
            C[(size_t)m * N + n] = v;
        }
    }
}

// ---------------- flash-style cross attention ------------------------------
// grid (4, H, B): 32-query tile per block, full S sweep with online softmax.
// K/V tiles staged in LDS (coalesced), mask bias staged in LDS.
#define QT 32
#define ST 128
#define KST 36          // K/V/Q LDS row stride (floats), 16B aligned, odd*4 banks
#define PST 132         // P LDS row stride

__global__ void cross_attn_kernel(const float* __restrict__ Qm,
                                  const float* __restrict__ Km,
                                  const float* __restrict__ Vm,
                                  const float* __restrict__ mask,
                                  const int* __restrict__ anyp,
                                  float* __restrict__ Out) {
    __shared__ __align__(16) float Qs[QT][KST];
    __shared__ __align__(16) float Ks[ST][KST];
    __shared__ __align__(16) float Vs[ST][KST];
    __shared__ __align__(16) float Ps[QT][PST];
    __shared__ float red[QT][33];      // reused: row-max partials, then row-sum partials
    __shared__ float m_s[QT], alpha_s[QT], l_s[QT], rowflag[QT];

    const int qt = blockIdx.x, h = blockIdx.y, b = blockIdx.z;
    const int t = threadIdx.x;
    const int q0 = qt * QT;
    const int qlim = min(BQ - q0, QT);           // 32 or 4

    // ---- stage Q (pre-scaled), init per-row state ----
    {
        int q = t / 8, c0 = (t % 8) * 4;
        float4 v = make_float4(0.f, 0.f, 0.f, 0.f);
        if (q < qlim)
            v = *(const float4*)(Qm + (size_t)(b * BQ + q0 + q) * DD + h * HDD + c0);
        const float sc = 0.17677669529663687f;   // 1/sqrt(32)
        Qs[q][c0 + 0] = v.x * sc; Qs[q][c0 + 1] = v.y * sc;
        Qs[q][c0 + 2] = v.z * sc; Qs[q][c0 + 3] = v.w * sc;
        if (t < QT) {
            m_s[t] = -1e30f;
            l_s[t] = 0.f;
            rowflag[t] = (t < qlim && anyp[b * BQ + q0 + t] != 0) ? 1.f : 0.f;
        }
    }

    float o0 = 0.f, o1 = 0.f, o2 = 0.f, o3 = 0.f;
    const int qq = t % 32;              // PV: output row
    const int d4 = (t / 32) * 4;        // PV: output col base
    const int qg = t % 8, sg = t / 8;   // QK microtile coords

    for (int s0 = 0; s0 < SS; s0 += ST) {
        __syncthreads();   // prev-iter readers of Ks/Vs/Ps done; init visible (1st iter)

        // ---- cooperative K/V tile load (coalesced float4) ----
        {
            int r = t / 2, c0 = (t % 2) * 16;
            const float* kp = Km + (size_t)(b * SS + s0 + r) * DD + h * HDD + c0;
            const float* vp = Vm + (size_t)(b * SS + s0 + r) * DD + h * HDD + c0;
#pragma unroll
            for (int u = 0; u < 16; u += 4) {
                float4 kv = *(const float4*)(kp + u);
                float4 vv = *(const float4*)(vp + u);
                *(float4*)&Ks[r][c0 + u] = kv;
                *(float4*)&Vs[r][c0 + u] = vv;
            }
        }
        // ---- stage mask bias tile into Ps ----
        {
            int q = t / 8, c0 = (t % 8) * 16;
            if (rowflag[q] != 0.f) {
                const float* mp = mask + (size_t)(b * BQ + q0 + q) * SS + s0 + c0;
#pragma unroll
                for (int u = 0; u < 16; u += 4) {
                    float4 mv = *(const float4*)(mp + u);
                    float4 bv;
                    bv.x = mv.x > 0.f ? 0.f : -10000.f;
                    bv.y = mv.y > 0.f ? 0.f : -10000.f;
                    bv.z = mv.z > 0.f ? 0.f : -10000.f;
                    bv.w = mv.w > 0.f ? 0.f : -10000.f;
                    *(float4*)&Ps[q][c0 + u] = bv;
                }
            } else {
                float4 z = make_float4(0.f, 0.f, 0.f, 0.f);
#pragma unroll
                for (int u = 0; u < 16; u += 4)
                    *(float4*)&Ps[q][c0 + u] = z;
            }
        }
        __syncthreads();   // K/V/bias tiles ready

        // ---- QK^T: 4x4 microtile per thread ----
        float acc[4][4] = {};
#pragma unroll
        for (int dc = 0; dc < HDD; dc += 4) {
            float4 qv[4], kv[4];
#pragma unroll
            for (int i = 0; i < 4; i++) qv[i] = *(const float4*)&Qs[qg * 4 + i][dc];
#pragma unroll
            for (int j = 0; j < 4; j++) kv[j] = *(const float4*)&Ks[sg * 4 + j][dc];
#pragma unroll
            for (int i = 0; i < 4; i++)
#pragma unroll
                for (int j = 0; j < 4; j++)
                    acc[i][j] += qv[i].x * kv[j].x + qv[i].y * kv[j].y +
                                 qv[i].z * kv[j].z + qv[i].w * kv[j].w;
        }
        // ---- add bias, local row max ----
#pragma unroll
        for (int i = 0; i < 4; i++) {
            float4 bv = *(const float4*)&Ps[qg * 4 + i][sg * 4];
            acc[i][0] += bv.x; acc[i][1] += bv.y; acc[i][2] += bv.z; acc[i][3] += bv.w;
            float lm = fmaxf(fmaxf(acc[i][0], acc[i][1]), fmaxf(acc[i][2], acc[i][3]));
            red[qg * 4 + i][sg] = lm;
        }
        __syncthreads();   // red (max partials) ready; Ps bias consumed

        if (t < QT) {
            float mt = -1e30f;
#pragma unroll
            for (int k = 0; k < 32; k++) mt = fmaxf(mt, red[t][k]);
            float mold = m_s[t];
            float mn = fmaxf(mold, mt);
            m_s[t] = mn;
            alpha_s[t] = __expf(mold - mn);
        }
        __syncthreads();   // m_s/alpha_s ready; red free; Ps free

        // ---- p = exp(score - m), write Ps + row-sum partials ----
#pragma unroll
        for (int i = 0; i < 4; i++) {
            float m_row = m_s[qg * 4 + i];
            float4 pv;
            pv.x = __expf(acc[i][0] - m_row);
            pv.y = __expf(acc[i][1] - m_row);
            pv.z = __expf(acc[i][2] - m_row);
            pv.w = __expf(acc[i][3] - m_row);
            *(float4*)&Ps[qg * 4 + i][sg * 4] = pv;
            red[qg * 4 + i][sg] = pv.x + pv.y + pv.z + pv.w;
        }
        __syncthreads();   // Ps(p), red(sum partials) ready

        // ---- l update (one thread per row) ----
        if (t < QT) {
            float ts = 0.f;
#pragma unroll
            for (int k = 0; k < 32; k++) ts += red[t][k];
            l_s[t] = l_s[t] * alpha_s[t] + ts;
        }
        // ---- O rescale + PV ----
        float al = alpha_s[qq];
        o0 *= al; o1 *= al; o2 *= al; o3 *= al;
#pragma unroll 8
        for (int sc = 0; sc < ST; sc += 4) {
            float4 pv = *(const float4*)&Ps[qq][sc];
            float4 v0 = *(const float4*)&Vs[sc + 0][d4];
            float4 v1 = *(const float4*)&Vs[sc + 1][d4];
            float4 v2 = *(const float4*)&Vs[sc + 2][d4];
            float4 v3 = *(const float4*)&Vs[sc + 3][d4];
            o0 += pv.x * v0.x + pv.y * v1.x + pv.z * v2.x + pv.w * v3.x;
            o1 += pv.x * v0.y + pv.y * v1.y + pv.z * v2.y + pv.w * v3.y;
            o2 += pv.x * v0.z + pv.y * v1.z + pv.z * v2.z + pv.w * v3.z;
            o3 += pv.x * v0.w + pv.y * v1.w + pv.z * v2.w + pv.w * v3.w;
        }
    }
    __syncthreads();   // final l_s visible to all

    if (qq < qlim) {
        float rinv = 1.0f / l_s[qq];
        float4 ov = make_float4(o0 * rinv, o1 * rinv, o2 * rinv, o3 * rinv);
        *(float4*)(Out + (size_t)(b * BQ + q0 + qq) * DD + h * HDD + d4) = ov;
    }
}

// ---------------- attention (small-S path, used for self-attn) -------------
__global__ void attn_kernel(const float* __restrict__ Qm, int sq, int qo0,
                            const float* __restrict__ Km, int sk, int ko0,
                            const float* __restrict__ Vm, int sv, int vo0,
                            const float* __restrict__ mask, const int* __restrict__ anyp,
                            float* __restrict__ Out, int so, int oo0,
                            int Slen, int Qlen, float scale) {
    int q = blockIdx.x, h = blockIdx.y, b = blockIdx.z;
    int tid = threadIdx.x;
    __shared__ float qv[32];
    __shared__ float sc[4096];
    __shared__ float red[256];
    __shared__ float part[8][33];
    int qrow = b * Qlen + q;
    if (tid < 32) qv[tid] = Qm[(size_t)qrow * sq + qo0 + h * HDD + tid] * scale;
    __syncthreads();

    bool use_mask = (mask != nullptr) && (anyp[qrow] != 0);
    float lmax = -1e30f;
    for (int s = tid; s < Slen; s += 256) {
        const float* kp = Km + (size_t)(b * Slen + s) * sk + ko0 + h * HDD;
        float dot = 0.f;
#pragma unroll
        for (int d = 0; d < HDD; d += 4) {
            float4 k4 = *(const float4*)(kp + d);
            dot += qv[d] * k4.x + qv[d + 1] * k4.y + qv[d + 2] * k4.z + qv[d + 3] * k4.w;
        }
        if (use_mask && !(mask[(size_t)qrow * Slen + s] > 0.f)) dot -= 10000.f;
        sc[s] = dot;
        lmax = fmaxf(lmax, dot);
    }
    red[tid] = lmax; __syncthreads();
    for (int off = 128; off > 0; off >>= 1) {
        if (tid < off) red[tid] = fmaxf(red[tid], red[tid + off]);
        __syncthreads();
    }
    float m = red[0];
    __syncthreads();
    float lsum = 0.f;
    for (int s = tid; s < Slen; s += 256) {
        float e = __expf(sc[s] - m);
        sc[s] = e;
        lsum += e;
    }
    red[tid] = lsum; __syncthreads();
    for (int off = 128; off > 0; off >>= 1) {
        if (tid < off) red[tid] += red[tid + off];
        __syncthreads();
    }
    float inv = 1.0f / red[0];

    int d = tid & 31, g = tid >> 5;
    float acc = 0.f;
    for (int s = g; s < Slen; s += 8)
        acc += sc[s] * Vm[(size_t)(b * Slen + s) * sv + vo0 + h * HDD + d];
    part[g][d] = acc; __syncthreads();
    if (g == 0) {
        float t = 0.f;
#pragma unroll
        for (int gg = 0; gg < 8; gg++) t += part[gg][d];
        Out[(size_t)qrow * so + oo0 + h * HDD + d] = t * inv;
    }
}

extern "C" void kernel_launch(void* const* d_in, const int* in_sizes, int n_in,
                              void* d_out, int out_size, void* d_ws, size_t ws_size,
                              hipStream_t stream) {
    const float* queries    = (const float*)d_in[0];
    const float* pixel_feat = (const float*)d_in[1];
    const float* prev_mask  = (const float*)d_in[2];
    const float* cross_in_w  = (const float*)d_in[3];
    const float* cross_in_b  = (const float*)d_in[4];
    const float* cross_out_w = (const float*)d_in[5];
    const float* cross_out_b = (const float*)d_in[6];
    const float* self_in_w   = (const float*)d_in[7];
    const float* self_in_b   = (const float*)d_in[8];
    const float* self_out_w  = (const float*)d_in[9];
    const float* self_out_b  = (const float*)d_in[10];
    const float* ln_cross_g  = (const float*)d_in[11];
    const float* ln_cross_b  = (const float*)d_in[12];
    const float* ln_self_g   = (const float*)d_in[13];
    const float* ln_self_b   = (const float*)d_in[14];
    const float* ln_ffn_g    = (const float*)d_in[15];
    const float* ln_ffn_b    = (const float*)d_in[16];
    const float* ffn_w1 = (const float*)d_in[17];
    const float* ffn_b1 = (const float*)d_in[18];
    const float* ffn_w2 = (const float*)d_in[19];
    const float* ffn_b2 = (const float*)d_in[20];
    float* out = (float*)d_out;

    const int NQ = SB * BQ;        // 800 query rows
    const int NK = SB * SS;        // 32768 kv rows

    // workspace layout
    int*   anyp   = (int*)d_ws;                 // 800 ints (pad to 1024)
    float* ws     = (float*)d_ws + 1024;
    float* ln_buf   = ws;              ws += (size_t)NQ * DD;
    float* q_cross  = ws;              ws += (size_t)NQ * DD;
    float* Kbuf     = ws;              ws += (size_t)NK * DD;
    float* Vbuf     = ws;              ws += (size_t)NK * DD;
    float* attn_out = ws;              ws += (size_t)NQ * DD;
    float* queries1 = ws;              ws += (size_t)NQ * DD;
    float* qkv      = ws;              ws += (size_t)NQ * 3 * DD;
    float* attn2    = ws;              ws += (size_t)NQ * DD;
    float* queries2 = ws;              ws += (size_t)NQ * DD;
    float* ffn_h    = ws;              ws += (size_t)NQ * 4 * DD;

    const float scale = 0.17677669529663687f;  // 1/sqrt(32)

    // mask row flags
    anypos_kernel<<<NQ, 256, 0, stream>>>(prev_mask, anyp, SS);

    // ---- cross attention ----
    ln_kernel<<<NQ, 256, 0, stream>>>(queries, ln_cross_g, ln_cross_b, ln_buf);
    gemm_nt<<<dim3(DD / BN, (NQ + BM - 1) / BM), 256, 0, stream>>>(
        ln_buf, cross_in_w, cross_in_b, nullptr, q_cross, NQ, DD, DD, 0);
    gemm_nt<<<dim3(DD / BN, NK / BM), 256, 0, stream>>>(
        pixel_feat, cross_in_w + (size_t)DD * DD, cross_in_b + DD, nullptr,
        Kbuf, NK, DD, DD, 0);
    gemm_nt<<<dim3(DD / BN, NK / BM), 256, 0, stream>>>(
        pixel_feat, cross_in_w + (size_t)2 * DD * DD, cross_in_b + 2 * DD, nullptr,
        Vbuf, NK, DD, DD, 0);
    cross_attn_kernel<<<dim3(4, HH, SB), 256, 0, stream>>>(
        q_cross, Kbuf, Vbuf, prev_mask, anyp, attn_out);
    gemm_nt<<<dim3(DD / BN, (NQ + BM - 1) / BM), 256, 0, stream>>>(
        attn_out, cross_out_w, cross_out_b, queries, queries1, NQ, DD, DD, 2);

    // ---- self attention ----
    ln_kernel<<<NQ, 256, 0, stream>>>(queries1, ln_self_g, ln_self_b, ln_buf);
    gemm_nt<<<dim3(3 * DD / BN, (NQ + BM - 1) / BM), 256, 0, stream>>>(
        ln_buf, self_in_w, self_in_b, nullptr, qkv, NQ, 3 * DD, DD, 0);
    attn_kernel<<<dim3(BQ, HH, SB), 256, 0, stream>>>(
        qkv, 3 * DD, 0, qkv, 3 * DD, DD, qkv, 3 * DD, 2 * DD,
        nullptr, nullptr, attn2, DD, 0, BQ, BQ, scale);
    gemm_nt<<<dim3(DD / BN, (NQ + BM - 1) / BM), 256, 0, stream>>>(
        attn2, self_out_w, self_out_b, queries1, queries2, NQ, DD, DD, 2);

    // ---- FFN ----
    ln_kernel<<<NQ, 256, 0, stream>>>(queries2, ln_ffn_g, ln_ffn_b, ln_buf);
    gemm_nt<<<dim3(4 * DD / BN, (NQ + BM - 1) / BM), 256, 0, stream>>>(
        ln_buf, ffn_w1, ffn_b1, nullptr, ffn_h, NQ, 4 * DD, DD, 1);
    gemm_nt<<<dim3(DD / BN, (NQ + BM - 1) / BM), 256, 0, stream>>>(
        ffn_h, ffn_w2, ffn_b2, queries2, out, NQ, DD, 4 * DD, 2);
}

// Round 3
// 530.539 us; speedup vs baseline: 2.6799x; 1.3604x over previous
//
#include <hip/hip_runtime.h>
#include <hip/hip_bf16.h>
#include <math.h>

#define BQ 100
#define SB 8
#define SS 4096
#define DD 256
#define HH 8
#define HDD 32
#define NSPLIT 4
#define SCHUNK (SS / NSPLIT)   // 1024

// ---------------- any_pos: OR-reduce (prev_mask>0) over S per (b,q) row ----
__global__ void anypos_kernel(const float* __restrict__ mask, int* __restrict__ anyp, int Slen) {
    int row = blockIdx.x, tid = threadIdx.x;
    __shared__ int red[256];
    int l = 0;
    for (int s = tid; s < Slen; s += 256)
        l |= (mask[(size_t)row * Slen + s] > 0.f) ? 1 : 0;
    red[tid] = l; __syncthreads();
    for (int off = 128; off > 0; off >>= 1) {
        if (tid < off) red[tid] |= red[tid + off];
        __syncthreads();
    }
    if (tid == 0) anyp[row] = red[0];
}

// ---------------- LayerNorm over D=256, one block per row -------------------
__global__ void ln_kernel(const float* __restrict__ x, const float* __restrict__ g,
                          const float* __restrict__ b, float* __restrict__ y) {
    int row = blockIdx.x, tid = threadIdx.x;
    __shared__ float red[256];
    float v = x[(size_t)row * DD + tid];
    red[tid] = v; __syncthreads();
    for (int off = 128; off > 0; off >>= 1) {
        if (tid < off) red[tid] += red[tid + off];
        __syncthreads();
    }
    float mu = red[0] * (1.0f / DD);
    __syncthreads();
    float dv = v - mu;
    red[tid] = dv * dv; __syncthreads();
    for (int off = 128; off > 0; off >>= 1) {
        if (tid < off) red[tid] += red[tid + off];
        __syncthreads();
    }
    float var = red[0] * (1.0f / DD);
    float r = rsqrtf(var + 1e-5f);
    y[(size_t)row * DD + tid] = dv * r * g[tid] + b[tid];
}

// ---------------- generic fp32 NT GEMM (small M paths) ----------------------
// mode 0: none; 1: gelu(exact); 2: += res[m,n]
#define BM 64
#define BN 64
#define BK 16
__global__ void gemm_nt(const float* __restrict__ A, const float* __restrict__ W,
                        const float* __restrict__ bias, const float* __restrict__ res,
                        float* __restrict__ C, int M, int N, int K, int mode) {
    __shared__ float As[BK][BM + 1];
    __shared__ float Ws[BK][BN + 1];
    int tid = threadIdx.x;
    int tx = tid % 16, ty = tid / 16;
    int lrow = tid / 4;
    int lcol = (tid % 4) * 4;
    float acc[4][4] = {};

    for (int k0 = 0; k0 < K; k0 += BK) {
        int am = blockIdx.y * BM + lrow;
        float4 av = make_float4(0.f, 0.f, 0.f, 0.f);
        if (am < M) av = *(const float4*)(A + (size_t)am * K + k0 + lcol);
        As[lcol + 0][lrow] = av.x; As[lcol + 1][lrow] = av.y;
        As[lcol + 2][lrow] = av.z; As[lcol + 3][lrow] = av.w;
        int wn = blockIdx.x * BN + lrow;
        float4 wv = *(const float4*)(W + (size_t)wn * K + k0 + lcol);
        Ws[lcol + 0][lrow] = wv.x; Ws[lcol + 1][lrow] = wv.y;
        Ws[lcol + 2][lrow] = wv.z; Ws[lcol + 3][lrow] = wv.w;
        __syncthreads();
#pragma unroll
        for (int kk = 0; kk < BK; kk++) {
            float aR[4], bR[4];
#pragma unroll
            for (int i = 0; i < 4; i++) aR[i] = As[kk][ty * 4 + i];
#pragma unroll
            for (int j = 0; j < 4; j++) bR[j] = Ws[kk][tx * 4 + j];
#pragma unroll
            for (int i = 0; i < 4; i++)
#pragma unroll
                for (int j = 0; j < 4; j++) acc[i][j] += aR[i] * bR[j];
        }
        __syncthreads();
    }

#pragma unroll
    for (int i = 0; i < 4; i++) {
        int m = blockIdx.y * BM + ty * 4 + i;
        if (m >= M) continue;
#pragma unroll
        for (int j = 0; j < 4; j++) {
            int n = blockIdx.x * BN + tx * 4 + j;
            float v = acc[i][j] + bias[n];
            if (mode == 1) {
                v = 0.5f * v * (1.0f + erff(v * 0.70710678118654752f));
            } else if (mode == 2) {
                v += res[(size_t)m * N + n];
            }
            C[(size_t)m * N + n] = v;
        }
    }
}

// ---------------- bf16 MFMA GEMM: fused K+V projection ----------------------
// C[m,n] = dot(A[m,:], W[n,:]) + bias[n]; A fp32 (M x K), W fp32 (N x K),
// converted to bf16 in staging. Tile 128x128x32, 4 waves, 16x16x32 MFMA.
typedef __attribute__((ext_vector_type(8))) short bf16x8;
typedef __attribute__((ext_vector_type(4))) float f32x4;
#define TM 128
#define TN 128
#define TK 32
#define LSTR 40   // LDS row stride in bf16 elems: 80B = 5*16B (aligned, conflict-free)

__device__ inline unsigned short f2bf(float f) {
    union { float f; unsigned u; } v; v.f = f;
    unsigned r = v.u + 0x7fff + ((v.u >> 16) & 1);
    return (unsigned short)(r >> 16);
}

__global__ __launch_bounds__(256, 2) void gemm_kv_mfma(
        const float* __restrict__ A, const float* __restrict__ W,
        const float* __restrict__ bias, float* __restrict__ C,
        int M, int N, int K) {
    __shared__ unsigned short As[TM][LSTR];
    __shared__ unsigned short Bs[TN][LSTR];
    int tid = threadIdx.x;
    int wave = tid / 64, lane = tid % 64;
    int m0 = blockIdx.y * TM, n0 = blockIdx.x * TN;
    int wm = (wave % 2) * 64, wn = (wave / 2) * 64;
    int lr = tid / 4;
    int lc = (tid % 4) * 8;
    int fr = lane % 16, quad = lane / 16;

    f32x4 acc[4][4] = {};   // acc[mi][ni]

    for (int k0 = 0; k0 < K; k0 += TK) {
        __syncthreads();
        // stage A rows lr, lr+64 and W rows lr, lr+64 (fp32 -> bf16)
#pragma unroll
        for (int half = 0; half < 2; half++) {
            int r = lr + half * 64;
            float4 a0 = *(const float4*)(A + (size_t)(m0 + r) * K + k0 + lc);
            float4 a1 = *(const float4*)(A + (size_t)(m0 + r) * K + k0 + lc + 4);
            uint4 pa;
            pa.x = (unsigned)f2bf(a0.x) | ((unsigned)f2bf(a0.y) << 16);
            pa.y = (unsigned)f2bf(a0.z) | ((unsigned)f2bf(a0.w) << 16);
            pa.z = (unsigned)f2bf(a1.x) | ((unsigned)f2bf(a1.y) << 16);
            pa.w = (unsigned)f2bf(a1.z) | ((unsigned)f2bf(a1.w) << 16);
            *(uint4*)&As[r][lc] = pa;
            float4 b0 = *(const float4*)(W + (size_t)(n0 + r) * K + k0 + lc);
            float4 b1 = *(const float4*)(W + (size_t)(n0 + r) * K + k0 + lc + 4);
            uint4 pb;
            pb.x = (unsigned)f2bf(b0.x) | ((unsigned)f2bf(b0.y) << 16);
            pb.y = (unsigned)f2bf(b0.z) | ((unsigned)f2bf(b0.w) << 16);
            pb.z = (unsigned)f2bf(b1.x) | ((unsigned)f2bf(b1.y) << 16);
            pb.w = (unsigned)f2bf(b1.z) | ((unsigned)f2bf(b1.w) << 16);
            *(uint4*)&Bs[n0 >= 0 ? r : r][lc] = pb;   // Bs row r
        }
        __syncthreads();
        bf16x8 af[4], bf[4];
#pragma unroll
        for (int mi = 0; mi < 4; mi++)
            af[mi] = *(const bf16x8*)&As[wm + mi * 16 + fr][quad * 8];
#pragma unroll
        for (int ni = 0; ni < 4; ni++)
            bf[ni] = *(const bf16x8*)&Bs[wn + ni * 16 + fr][quad * 8];
#pragma unroll
        for (int mi = 0; mi < 4; mi++)
#pragma unroll
            for (int ni = 0; ni < 4; ni++)
                acc[mi][ni] = __builtin_amdgcn_mfma_f32_16x16x32_bf16(
                    af[mi], bf[ni], acc[mi][ni], 0, 0, 0);
    }

    float bv[4];
#pragma unroll
    for (int ni = 0; ni < 4; ni++) bv[ni] = bias[n0 + wn + ni * 16 + fr];
#pragma unroll
    for (int mi = 0; mi < 4; mi++) {
#pragma unroll
        for (int ni = 0; ni < 4; ni++) {
            int n = n0 + wn + ni * 16 + fr;
#pragma unroll
            for (int r = 0; r < 4; r++) {
                int m = m0 + wm + mi * 16 + quad * 4 + r;
                C[(size_t)m * N + n] = acc[mi][ni][r] + bv[ni];
            }
        }
    }
}

// ---------------- flash-style cross attention, split-S ----------------------
// grid (4, H, B*NSPLIT): 32-query tile, S-chunk of 1024, online softmax.
// Writes unnormalized O + (m,l) stats; combine kernel merges splits.
#define QT 32
#define ST 128
#define KST 36
#define PST 132

__global__ void cross_attn_kernel(const float* __restrict__ Qm,
                                  const float* __restrict__ Km, int skv,
                                  const float* __restrict__ Vm,
                                  const float* __restrict__ mask,
                                  const int* __restrict__ anyp,
                                  float* __restrict__ Opart,
                                  float* __restrict__ mpart,
                                  float* __restrict__ lpart) {
    __shared__ __align__(16) float Qs[QT][KST];
    __shared__ __align__(16) float Ks[ST][KST];
    __shared__ __align__(16) float Vs[ST][KST];
    __shared__ __align__(16) float Ps[QT][PST];
    __shared__ float red[QT][33];
    __shared__ float m_s[QT], alpha_s[QT], l_s[QT], rowflag[QT];

    const int qt = blockIdx.x, h = blockIdx.y;
    const int b = blockIdx.z / NSPLIT, sp = blockIdx.z % NSPLIT;
    const int t = threadIdx.x;
    const int q0 = qt * QT;
    const int qlim = min(BQ - q0, QT);

    {
        int q = t / 8, c0 = (t % 8) * 4;
        float4 v = make_float4(0.f, 0.f, 0.f, 0.f);
        if (q < qlim)
            v = *(const float4*)(Qm + (size_t)(b * BQ + q0 + q) * DD + h * HDD + c0);
        const float sc = 0.17677669529663687f;
        Qs[q][c0 + 0] = v.x * sc; Qs[q][c0 + 1] = v.y * sc;
        Qs[q][c0 + 2] = v.z * sc; Qs[q][c0 + 3] = v.w * sc;
        if (t < QT) {
            m_s[t] = -1e30f;
            l_s[t] = 0.f;
            rowflag[t] = (t < qlim && anyp[b * BQ + q0 + t] != 0) ? 1.f : 0.f;
        }
    }

    float o0 = 0.f, o1 = 0.f, o2 = 0.f, o3 = 0.f;
    const int qq = t % 32;
    const int d4 = (t / 32) * 4;
    const int qg = t % 8, sg = t / 8;

    const int send = (sp + 1) * SCHUNK;
    for (int s0 = sp * SCHUNK; s0 < send; s0 += ST) {
        __syncthreads();
        {
            int r = t / 2, c0 = (t % 2) * 16;
            const float* kp = Km + (size_t)(b * SS + s0 + r) * skv + h * HDD + c0;
            const float* vp = Vm + (size_t)(b * SS + s0 + r) * skv + h * HDD + c0;
#pragma unroll
            for (int u = 0; u < 16; u += 4) {
                float4 kv = *(const float4*)(kp + u);
                float4 vv = *(const float4*)(vp + u);
                *(float4*)&Ks[r][c0 + u] = kv;
                *(float4*)&Vs[r][c0 + u] = vv;
            }
        }
        {
            int q = t / 8, c0 = (t % 8) * 16;
            if (rowflag[q] != 0.f) {
                const float* mp = mask + (size_t)(b * BQ + q0 + q) * SS + s0 + c0;
#pragma unroll
                for (int u = 0; u < 16; u += 4) {
                    float4 mv = *(const float4*)(mp + u);
                    float4 bvv;
                    bvv.x = mv.x > 0.f ? 0.f : -10000.f;
                    bvv.y = mv.y > 0.f ? 0.f : -10000.f;
                    bvv.z = mv.z > 0.f ? 0.f : -10000.f;
                    bvv.w = mv.w > 0.f ? 0.f : -10000.f;
                    *(float4*)&Ps[q][c0 + u] = bvv;
                }
            } else {
                float4 z = make_float4(0.f, 0.f, 0.f, 0.f);
#pragma unroll
                for (int u = 0; u < 16; u += 4)
                    *(float4*)&Ps[q][c0 + u] = z;
            }
        }
        __syncthreads();

        float acc[4][4] = {};
#pragma unroll
        for (int dc = 0; dc < HDD; dc += 4) {
            float4 qv[4], kv[4];
#pragma unroll
            for (int i = 0; i < 4; i++) qv[i] = *(const float4*)&Qs[qg * 4 + i][dc];
#pragma unroll
            for (int j = 0; j < 4; j++) kv[j] = *(const float4*)&Ks[sg * 4 + j][dc];
#pragma unroll
            for (int i = 0; i < 4; i++)
#pragma unroll
                for (int j = 0; j < 4; j++)
                    acc[i][j] += qv[i].x * kv[j].x + qv[i].y * kv[j].y +
                                 qv[i].z * kv[j].z + qv[i].w * kv[j].w;
        }
#pragma unroll
        for (int i = 0; i < 4; i++) {
            float4 bvv = *(const float4*)&Ps[qg * 4 + i][sg * 4];
            acc[i][0] += bvv.x; acc[i][1] += bvv.y; acc[i][2] += bvv.z; acc[i][3] += bvv.w;
            float lm = fmaxf(fmaxf(acc[i][0], acc[i][1]), fmaxf(acc[i][2], acc[i][3]));
            red[qg * 4 + i][sg] = lm;
        }
        __syncthreads();

        if (t < QT) {
            float mt = -1e30f;
#pragma unroll
            for (int k = 0; k < 32; k++) mt = fmaxf(mt, red[t][k]);
            float mold = m_s[t];
            float mn = fmaxf(mold, mt);
            m_s[t] = mn;
            alpha_s[t] = __expf(mold - mn);
        }
        __syncthreads();

#pragma unroll
        for (int i = 0; i < 4; i++) {
            float m_row = m_s[qg * 4 + i];
            float4 pv;
            pv.x = __expf(acc[i][0] - m_row);
            pv.y = __expf(acc[i][1] - m_row);
            pv.z = __expf(acc[i][2] - m_row);
            pv.w = __expf(acc[i][3] - m_row);
            *(float4*)&Ps[qg * 4 + i][sg * 4] = pv;
            red[qg * 4 + i][sg] = pv.x + pv.y + pv.z + pv.w;
        }
        __syncthreads();

        if (t < QT) {
            float ts = 0.f;
#pragma unroll
            for (int k = 0; k < 32; k++) ts += red[t][k];
            l_s[t] = l_s[t] * alpha_s[t] + ts;
        }
        float al = alpha_s[qq];
        o0 *= al; o1 *= al; o2 *= al; o3 *= al;
#pragma unroll 8
        for (int sc = 0; sc < ST; sc += 4) {
            float4 pv = *(const float4*)&Ps[qq][sc];
            float4 v0 = *(const float4*)&Vs[sc + 0][d4];
            float4 v1 = *(const float4*)&Vs[sc + 1][d4];
            float4 v2 = *(const float4*)&Vs[sc + 2][d4];
            float4 v3 = *(const float4*)&Vs[sc + 3][d4];
            o0 += pv.x * v0.x + pv.y * v1.x + pv.z * v2.x + pv.w * v3.x;
            o1 += pv.x * v0.y + pv.y * v1.y + pv.z * v2.y + pv.w * v3.y;
            o2 += pv.x * v0.z + pv.y * v1.z + pv.z * v2.z + pv.w * v3.z;
            o3 += pv.x * v0.w + pv.y * v1.w + pv.z * v2.w + pv.w * v3.w;
        }
    }
    __syncthreads();

    int part = b * NSPLIT + sp;
    if (t < qlim) {
        mpart[((size_t)part * HH + h) * BQ + q0 + t] = m_s[t];
        lpart[((size_t)part * HH + h) * BQ + q0 + t] = l_s[t];
    }
    if (qq < qlim) {
        float* op = Opart + ((size_t)part * BQ + q0 + qq) * DD + h * HDD + d4;
        op[0] = o0; op[1] = o1; op[2] = o2; op[3] = o3;
    }
}

// ---------------- split-S combine: exact log-sum-exp merge ------------------
__global__ void attn_combine_kernel(const float* __restrict__ Opart,
                                    const float* __restrict__ mpart,
                                    const float* __restrict__ lpart,
                                    float* __restrict__ Out) {
    int row = blockIdx.x;             // b*BQ + q
    int b = row / BQ, q = row % BQ;
    int t = threadIdx.x;
    int h = t / 32, d = t % 32;
    float mv[NSPLIT];
    float m_star = -1e30f;
#pragma unroll
    for (int sp = 0; sp < NSPLIT; sp++) {
        mv[sp] = mpart[((size_t)(b * NSPLIT + sp) * HH + h) * BQ + q];
        m_star = fmaxf(m_star, mv[sp]);
    }
    float l_star = 0.f, o = 0.f;
#pragma unroll
    for (int sp = 0; sp < NSPLIT; sp++) {
        float w = __expf(mv[sp] - m_star);
        l_star += lpart[((size_t)(b * NSPLIT + sp) * HH + h) * BQ + q] * w;
        o += Opart[((size_t)(b * NSPLIT + sp) * BQ + q) * DD + h * HDD + d] * w;
    }
    Out[(size_t)row * DD + h * HDD + d] = o / l_star;
}

// ---------------- attention (small-S path, used for self-attn) --------------
__global__ void attn_kernel(const float* __restrict__ Qm, int sq, int qo0,
                            const float* __restrict__ Km, int sk, int ko0,
                            const float* __restrict__ Vm, int sv, int vo0,
                            float* __restrict__ Out, int so, int oo0,
                            int Slen, int Qlen, float scale) {
    int q = blockIdx.x, h = blockIdx.y, b = blockIdx.z;
    int tid = threadIdx.x;
    __shared__ float qv[32];
    __shared__ float sc[4096];
    __shared__ float red[256];
    __shared__ float part[8][33];
    int qrow = b * Qlen + q;
    if (tid < 32) qv[tid] = Qm[(size_t)qrow * sq + qo0 + h * HDD + tid] * scale;
    __syncthreads();

    float lmax = -1e30f;
    for (int s = tid; s < Slen; s += 256) {
        const float* kp = Km + (size_t)(b * Slen + s) * sk + ko0 + h * HDD;
        float dot = 0.f;
#pragma unroll
        for (int d = 0; d < HDD; d += 4) {
            float4 k4 = *(const float4*)(kp + d);
            dot += qv[d] * k4.x + qv[d + 1] * k4.y + qv[d + 2] * k4.z + qv[d + 3] * k4.w;
        }
        sc[s] = dot;
        lmax = fmaxf(lmax, dot);
    }
    red[tid] = lmax; __syncthreads();
    for (int off = 128; off > 0; off >>= 1) {
        if (tid < off) red[tid] = fmaxf(red[tid], red[tid + off]);
        __syncthreads();
    }
    float m = red[0];
    __syncthreads();
    float lsum = 0.f;
    for (int s = tid; s < Slen; s += 256) {
        float e = __expf(sc[s] - m);
        sc[s] = e;
        lsum += e;
    }
    red[tid] = lsum; __syncthreads();
    for (int off = 128; off > 0; off >>= 1) {
        if (tid < off) red[tid] += red[tid + off];
        __syncthreads();
    }
    float inv = 1.0f / red[0];

    int d = tid & 31, g = tid >> 5;
    float acc = 0.f;
    for (int s = g; s < Slen; s += 8)
        acc += sc[s] * Vm[(size_t)(b * Slen + s) * sv + vo0 + h * HDD + d];
    part[g][d] = acc; __syncthreads();
    if (g == 0) {
        float t = 0.f;
#pragma unroll
        for (int gg = 0; gg < 8; gg++) t += part[gg][d];
        Out[(size_t)qrow * so + oo0 + h * HDD + d] = t * inv;
    }
}

extern "C" void kernel_launch(void* const* d_in, const int* in_sizes, int n_in,
                              void* d_out, int out_size, void* d_ws, size_t ws_size,
                              hipStream_t stream) {
    const float* queries    = (const float*)d_in[0];
    const float* pixel_feat = (const float*)d_in[1];
    const float* prev_mask  = (const float*)d_in[2];
    const float* cross_in_w  = (const float*)d_in[3];
    const float* cross_in_b  = (const float*)d_in[4];
    const float* cross_out_w = (const float*)d_in[5];
    const float* cross_out_b = (const float*)d_in[6];
    const float* self_in_w   = (const float*)d_in[7];
    const float* self_in_b   = (const float*)d_in[8];
    const float* self_out_w  = (const float*)d_in[9];
    const float* self_out_b  = (const float*)d_in[10];
    const float* ln_cross_g  = (const float*)d_in[11];
    const float* ln_cross_b  = (const float*)d_in[12];
    const float* ln_self_g   = (const float*)d_in[13];
    const float* ln_self_b   = (const float*)d_in[14];
    const float* ln_ffn_g    = (const float*)d_in[15];
    const float* ln_ffn_b    = (const float*)d_in[16];
    const float* ffn_w1 = (const float*)d_in[17];
    const float* ffn_b1 = (const float*)d_in[18];
    const float* ffn_w2 = (const float*)d_in[19];
    const float* ffn_b2 = (const float*)d_in[20];
    float* out = (float*)d_out;

    const int NQ = SB * BQ;        // 800
    const int NK = SB * SS;        // 32768

    int*   anyp   = (int*)d_ws;
    float* ws     = (float*)d_ws + 1024;
    float* ln_buf   = ws;              ws += (size_t)NQ * DD;
    float* q_cross  = ws;              ws += (size_t)NQ * DD;
    float* KVbuf    = ws;              ws += (size_t)NK * 2 * DD;       // 32768 x 512
    float* attn_out = ws;              ws += (size_t)NQ * DD;
    float* queries1 = ws;              ws += (size_t)NQ * DD;
    float* qkv      = ws;              ws += (size_t)NQ * 3 * DD;
    float* attn2    = ws;              ws += (size_t)NQ * DD;
    float* queries2 = ws;              ws += (size_t)NQ * DD;
    float* ffn_h    = ws;              ws += (size_t)NQ * 4 * DD;
    float* Opart    = ws;              ws += (size_t)SB * NSPLIT * BQ * DD;
    float* mpart    = ws;              ws += (size_t)SB * NSPLIT * HH * BQ;
    float* lpart    = ws;              ws += (size_t)SB * NSPLIT * HH * BQ;

    const float scale = 0.17677669529663687f;

    anypos_kernel<<<NQ, 256, 0, stream>>>(prev_mask, anyp, SS);

    // ---- cross attention ----
    ln_kernel<<<NQ, 256, 0, stream>>>(queries, ln_cross_g, ln_cross_b, ln_buf);
    gemm_nt<<<dim3(DD / BN, (NQ + BM - 1) / BM), 256, 0, stream>>>(
        ln_buf, cross_in_w, cross_in_b, nullptr, q_cross, NQ, DD, DD, 0);
    // fused K+V projection: (32768x256) @ (512x256)^T -> 32768x512 [K|V]
    gemm_kv_mfma<<<dim3(2 * DD / TN, NK / TM), 256, 0, stream>>>(
        pixel_feat, cross_in_w + (size_t)DD * DD, cross_in_b + DD,
        KVbuf, NK, 2 * DD, DD);
    cross_attn_kernel<<<dim3(4, HH, SB * NSPLIT), 256, 0, stream>>>(
        q_cross, KVbuf, 2 * DD, KVbuf + DD, prev_mask, anyp,
        Opart, mpart, lpart);
    attn_combine_kernel<<<NQ, 256, 0, stream>>>(Opart, mpart, lpart, attn_out);
    gemm_nt<<<dim3(DD / BN, (NQ + BM - 1) / BM), 256, 0, stream>>>(
        attn_out, cross_out_w, cross_out_b, queries, queries1, NQ, DD, DD, 2);

    // ---- self attention ----
    ln_kernel<<<NQ, 256, 0, stream>>>(queries1, ln_self_g, ln_self_b, ln_buf);
    gemm_nt<<<dim3(3 * DD / BN, (NQ + BM - 1) / BM), 256, 0, stream>>>(
        ln_buf, self_in_w, self_in_b, nullptr, qkv, NQ, 3 * DD, DD, 0);
    attn_kernel<<<dim3(BQ, HH, SB), 256, 0, stream>>>(
        qkv, 3 * DD, 0, qkv, 3 * DD, DD, qkv, 3 * DD, 2 * DD,
        attn2, DD, 0, BQ, BQ, scale);
    gemm_nt<<<dim3(DD / BN, (NQ + BM - 1) / BM), 256, 0, stream>>>(
        attn2, self_out_w, self_out_b, queries1, queries2, NQ, DD, DD, 2);

    // ---- FFN ----
    ln_kernel<<<NQ, 256, 0, stream>>>(queries2, ln_ffn_g, ln_ffn_b, ln_buf);
    gemm_nt<<<dim3(4 * DD / BN, (NQ + BM - 1) / BM), 256, 0, stream>>>(
        ln_buf, ffn_w1, ffn_b1, nullptr, ffn_h, NQ, 4 * DD, DD, 1);
    gemm_nt<<<dim3(DD / BN, (NQ + BM - 1) / BM), 256, 0, stream>>>(
        ffn_h, ffn_w2, ffn_b2, queries2, out, NQ, DD, 4 * DD, 2);
}

// Round 4
// 436.135 us; speedup vs baseline: 3.2600x; 1.2165x over previous
//
#include <hip/hip_runtime.h>
#include <hip/hip_bf16.h>
#include <math.h>

#define BQ 100
#define SB 8
#define SS 4096
#define DD 256
#define HH 8
#define HDD 32
#define NSPLIT 4
#define SCHUNK (SS / NSPLIT)   // 1024

typedef __attribute__((ext_vector_type(8))) short bf16x8;
typedef __attribute__((ext_vector_type(4))) float f32x4;

__device__ inline unsigned short f2bf(float f) {
    union { float f; unsigned u; } v; v.f = f;
    unsigned r = v.u + 0x7fff + ((v.u >> 16) & 1);
    return (unsigned short)(r >> 16);
}

// ---------------- mask pack: bit s of row (b,q); all-ones if row empty ------
__global__ void maskpack_kernel(const float* __restrict__ mask, unsigned* __restrict__ Mbits) {
    int row = blockIdx.x, t = threadIdx.x;
    int w = t >> 6, lane = t & 63;
    __shared__ unsigned words[128];
    __shared__ unsigned orred[4];
    unsigned lor = 0;
    for (int i = 0; i < 16; i++) {
        int s = (w * 16 + i) * 64 + lane;
        unsigned long long bal = __ballot(mask[(size_t)row * SS + s] > 0.f);
        if (lane == 0) {
            words[(w * 16 + i) * 2] = (unsigned)bal;
            words[(w * 16 + i) * 2 + 1] = (unsigned)(bal >> 32);
        }
        lor |= (unsigned)(bal | (bal >> 32));
    }
    if (lane == 0) orred[w] = lor;
    __syncthreads();
    unsigned anyv = orred[0] | orred[1] | orred[2] | orred[3];
    if (t < 128) Mbits[(size_t)row * 128 + t] = anyv ? words[t] : 0xFFFFFFFFu;
}

// ---------------- LayerNorm over D=256, one block per row -------------------
__global__ void ln_kernel(const float* __restrict__ x, const float* __restrict__ g,
                          const float* __restrict__ b, float* __restrict__ y) {
    int row = blockIdx.x, tid = threadIdx.x;
    __shared__ float red[256];
    float v = x[(size_t)row * DD + tid];
    red[tid] = v; __syncthreads();
    for (int off = 128; off > 0; off >>= 1) {
        if (tid < off) red[tid] += red[tid + off];
        __syncthreads();
    }
    float mu = red[0] * (1.0f / DD);
    __syncthreads();
    float dv = v - mu;
    red[tid] = dv * dv; __syncthreads();
    for (int off = 128; off > 0; off >>= 1) {
        if (tid < off) red[tid] += red[tid + off];
        __syncthreads();
    }
    float var = red[0] * (1.0f / DD);
    float r = rsqrtf(var + 1e-5f);
    y[(size_t)row * DD + tid] = dv * r * g[tid] + b[tid];
}

// ---------------- generic fp32 NT GEMM (small M paths) ----------------------
#define BM 64
#define BN 64
#define BK 16
__global__ void gemm_nt(const float* __restrict__ A, const float* __restrict__ W,
                        const float* __restrict__ bias, const float* __restrict__ res,
                        float* __restrict__ C, int M, int N, int K, int mode) {
    __shared__ float As[BK][BM + 1];
    __shared__ float Ws[BK][BN + 1];
    int tid = threadIdx.x;
    int tx = tid % 16, ty = tid / 16;
    int lrow = tid / 4;
    int lcol = (tid % 4) * 4;
    float acc[4][4] = {};

    for (int k0 = 0; k0 < K; k0 += BK) {
        int am = blockIdx.y * BM + lrow;
        float4 av = make_float4(0.f, 0.f, 0.f, 0.f);
        if (am < M) av = *(const float4*)(A + (size_t)am * K + k0 + lcol);
        As[lcol + 0][lrow] = av.x; As[lcol + 1][lrow] = av.y;
        As[lcol + 2][lrow] = av.z; As[lcol + 3][lrow] = av.w;
        int wn = blockIdx.x * BN + lrow;
        float4 wv = *(const float4*)(W + (size_t)wn * K + k0 + lcol);
        Ws[lcol + 0][lrow] = wv.x; Ws[lcol + 1][lrow] = wv.y;
        Ws[lcol + 2][lrow] = wv.z; Ws[lcol + 3][lrow] = wv.w;
        __syncthreads();
#pragma unroll
        for (int kk = 0; kk < BK; kk++) {
            float aR[4], bR[4];
#pragma unroll
            for (int i = 0; i < 4; i++) aR[i] = As[kk][ty * 4 + i];
#pragma unroll
            for (int j = 0; j < 4; j++) bR[j] = Ws[kk][tx * 4 + j];
#pragma unroll
            for (int i = 0; i < 4; i++)
#pragma unroll
                for (int j = 0; j < 4; j++) acc[i][j] += aR[i] * bR[j];
        }
        __syncthreads();
    }

#pragma unroll
    for (int i = 0; i < 4; i++) {
        int m = blockIdx.y * BM + ty * 4 + i;
        if (m >= M) continue;
#pragma unroll
        for (int j = 0; j < 4; j++) {
            int n = blockIdx.x * BN + tx * 4 + j;
            float v = acc[i][j] + bias[n];
            if (mode == 1) {
                v = 0.5f * v * (1.0f + erff(v * 0.70710678118654752f));
            } else if (mode == 2) {
                v += res[(size_t)m * N + n];
            }
            C[(size_t)m * N + n] = v;
        }
    }
}

// ---------------- bf16 MFMA GEMM: fused K+V projection, bf16 output ---------
#define TM 128
#define TN 128
#define TK 32
#define LSTR 40

__global__ __launch_bounds__(256, 2) void gemm_kv_mfma(
        const float* __restrict__ A, const float* __restrict__ W,
        const float* __restrict__ bias, unsigned short* __restrict__ C,
        int M, int N, int K) {
    __shared__ unsigned short As[TM][LSTR];
    __shared__ unsigned short Bs[TN][LSTR];
    int tid = threadIdx.x;
    int wave = tid / 64, lane = tid % 64;
    int m0 = blockIdx.y * TM, n0 = blockIdx.x * TN;
    int wm = (wave % 2) * 64, wn = (wave / 2) * 64;
    int lr = tid / 4;
    int lc = (tid % 4) * 8;
    int fr = lane % 16, quad = lane / 16;

    f32x4 acc[4][4] = {};

    for (int k0 = 0; k0 < K; k0 += TK) {
        __syncthreads();
#pragma unroll
        for (int half = 0; half < 2; half++) {
            int r = lr + half * 64;
            float4 a0 = *(const float4*)(A + (size_t)(m0 + r) * K + k0 + lc);
            float4 a1 = *(const float4*)(A + (size_t)(m0 + r) * K + k0 + lc + 4);
            uint4 pa;
            pa.x = (unsigned)f2bf(a0.x) | ((unsigned)f2bf(a0.y) << 16);
            pa.y = (unsigned)f2bf(a0.z) | ((unsigned)f2bf(a0.w) << 16);
            pa.z = (unsigned)f2bf(a1.x) | ((unsigned)f2bf(a1.y) << 16);
            pa.w = (unsigned)f2bf(a1.z) | ((unsigned)f2bf(a1.w) << 16);
            *(uint4*)&As[r][lc] = pa;
            float4 b0 = *(const float4*)(W + (size_t)(n0 + r) * K + k0 + lc);
            float4 b1 = *(const float4*)(W + (size_t)(n0 + r) * K + k0 + lc + 4);
            uint4 pb;
            pb.x = (unsigned)f2bf(b0.x) | ((unsigned)f2bf(b0.y) << 16);
            pb.y = (unsigned)f2bf(b0.z) | ((unsigned)f2bf(b0.w) << 16);
            pb.z = (unsigned)f2bf(b1.x) | ((unsigned)f2bf(b1.y) << 16);
            pb.w = (unsigned)f2bf(b1.z) | ((unsigned)f2bf(b1.w) << 16);
            *(uint4*)&Bs[r][lc] = pb;
        }
        __syncthreads();
        bf16x8 af[4], bf[4];
#pragma unroll
        for (int mi = 0; mi < 4; mi++)
            af[mi] = *(const bf16x8*)&As[wm + mi * 16 + fr][quad * 8];
#pragma unroll
        for (int ni = 0; ni < 4; ni++)
            bf[ni] = *(const bf16x8*)&Bs[wn + ni * 16 + fr][quad * 8];
#pragma unroll
        for (int mi = 0; mi < 4; mi++)
#pragma unroll
            for (int ni = 0; ni < 4; ni++)
                acc[mi][ni] = __builtin_amdgcn_mfma_f32_16x16x32_bf16(
                    af[mi], bf[ni], acc[mi][ni], 0, 0, 0);
    }

    float bv[4];
#pragma unroll
    for (int ni = 0; ni < 4; ni++) bv[ni] = bias[n0 + wn + ni * 16 + fr];
#pragma unroll
    for (int mi = 0; mi < 4; mi++) {
#pragma unroll
        for (int ni = 0; ni < 4; ni++) {
            int n = n0 + wn + ni * 16 + fr;
#pragma unroll
            for (int r = 0; r < 4; r++) {
                int m = m0 + wm + mi * 16 + quad * 4 + r;
                C[(size_t)m * N + n] = f2bf(acc[mi][ni][r] + bv[ni]);
            }
        }
    }
}

// ---------------- MFMA flash cross-attention, split-S -----------------------
// grid (4, H, B*NSPLIT), 256 thr. QK^T -> S^T via mfma (A=K[s][d], B=Q[q][d]);
// softmax stats in LDS; P->bf16 LDS [q][s]; PV via mfma (B=Vt[d][s]).
#define QT 32
#define ST 128

__global__ __launch_bounds__(256) void cross_attn_mfma(
        const float* __restrict__ Qm,
        const unsigned short* __restrict__ KV,   // [B*SS][512] bf16: K | V
        const unsigned* __restrict__ Mbits,      // [B*BQ][128]
        float* __restrict__ Opart,
        float* __restrict__ mpart,
        float* __restrict__ lpart) {
    __shared__ unsigned short Qs[QT][40];
    __shared__ unsigned short Ks[ST][40];
    __shared__ unsigned short Vt[HDD][136];
    __shared__ unsigned short Ps[QT][136];
    __shared__ unsigned Mq[QT][4];
    __shared__ float red[QT][17];
    __shared__ float m_s[QT], alpha_s[QT], l_s[QT];

    const int qt = blockIdx.x, h = blockIdx.y;
    const int b = blockIdx.z / NSPLIT, sp = blockIdx.z % NSPLIT;
    const int t = threadIdx.x;
    const int w = t >> 6, lane = t & 63;
    const int fr = lane & 15, quad = lane >> 4;
    const int q0 = qt * QT;
    const int qlim = min(BQ - q0, QT);

    // ---- stage Q (bf16, pre-scaled), init state ----
    {
        int q = t >> 3, seg = t & 7;
        float4 v = make_float4(0.f, 0.f, 0.f, 0.f);
        if (q < qlim)
            v = *(const float4*)(Qm + (size_t)(b * BQ + q0 + q) * DD + h * HDD + seg * 4);
        const float sc = 0.17677669529663687f;
        ushort4 pk;
        pk.x = f2bf(v.x * sc); pk.y = f2bf(v.y * sc);
        pk.z = f2bf(v.z * sc); pk.w = f2bf(v.w * sc);
        *(ushort4*)&Qs[q][seg * 4] = pk;
        if (t < QT) { m_s[t] = -1e30f; l_s[t] = 0.f; }
    }

    f32x4 oacc = {0.f, 0.f, 0.f, 0.f};
    const int mtq = w & 1, ntd = w >> 1;

    for (int s0 = sp * SCHUNK; s0 < (sp + 1) * SCHUNK; s0 += ST) {
        __syncthreads();
        // ---- stage K rows + transpose V into Vt ----
        {
            int r = t >> 1, half = t & 1;
            const unsigned short* kp = KV + (size_t)(b * SS + s0 + r) * 512 + h * HDD + half * 16;
            uint4 k0v = *(const uint4*)(kp);
            uint4 k1v = *(const uint4*)(kp + 8);
            *(uint4*)&Ks[r][half * 16] = k0v;
            *(uint4*)&Ks[r][half * 16 + 8] = k1v;
            union { uint4 u; unsigned short s[8]; } v0, v1;
            v0.u = *(const uint4*)(kp + DD);
            v1.u = *(const uint4*)(kp + DD + 8);
#pragma unroll
            for (int j = 0; j < 8; j++) Vt[half * 16 + j][r] = v0.s[j];
#pragma unroll
            for (int j = 0; j < 8; j++) Vt[half * 16 + 8 + j][r] = v1.s[j];
        }
        // ---- stage mask bits ----
        if (t < 128) {
            int q = t >> 2, wd = t & 3;
            unsigned mword = 0xFFFFFFFFu;
            if (q < qlim)
                mword = Mbits[(size_t)(b * BQ + q0 + q) * 128 + (s0 >> 5) + wd];
            Mq[q][wd] = mword;
        }
        __syncthreads();

        // ---- QK^T (S^T): wave w covers s range w*32..w*32+32 ----
        bf16x8 af[2], bq[2];
#pragma unroll
        for (int mt = 0; mt < 2; mt++)
            af[mt] = *(const bf16x8*)&Ks[w * 32 + mt * 16 + fr][quad * 8];
#pragma unroll
        for (int nt = 0; nt < 2; nt++)
            bq[nt] = *(const bf16x8*)&Qs[nt * 16 + fr][quad * 8];
        f32x4 st[2][2];
#pragma unroll
        for (int mt = 0; mt < 2; mt++)
#pragma unroll
            for (int nt = 0; nt < 2; nt++) {
                f32x4 z = {0.f, 0.f, 0.f, 0.f};
                st[mt][nt] = __builtin_amdgcn_mfma_f32_16x16x32_bf16(af[mt], bq[nt], z, 0, 0, 0);
            }

        // ---- mask + per-lane max ----
        float pmax[2] = {-1e30f, -1e30f};
#pragma unroll
        for (int nt = 0; nt < 2; nt++) {
            unsigned mword = Mq[nt * 16 + fr][w];
#pragma unroll
            for (int mt = 0; mt < 2; mt++)
#pragma unroll
                for (int r = 0; r < 4; r++) {
                    int bitpos = mt * 16 + quad * 4 + r;
                    float v = st[mt][nt][r];
                    if (!((mword >> bitpos) & 1u)) v -= 10000.f;
                    st[mt][nt][r] = v;
                    pmax[nt] = fmaxf(pmax[nt], v);
                }
        }
#pragma unroll
        for (int nt = 0; nt < 2; nt++)
            red[nt * 16 + fr][w * 4 + quad] = pmax[nt];
        __syncthreads();

        if (t < QT) {
            float mt_ = -1e30f;
#pragma unroll
            for (int k = 0; k < 16; k++) mt_ = fmaxf(mt_, red[t][k]);
            float mo = m_s[t], mn = fmaxf(mo, mt_);
            m_s[t] = mn;
            alpha_s[t] = __expf(mo - mn);
        }
        __syncthreads();

        // ---- p = exp(s - m): store bf16 P[q][s], partial sums ----
        float psum[2] = {0.f, 0.f};
#pragma unroll
        for (int nt = 0; nt < 2; nt++) {
            float mrow = m_s[nt * 16 + fr];
#pragma unroll
            for (int mt = 0; mt < 2; mt++) {
                float p0 = __expf(st[mt][nt][0] - mrow);
                float p1 = __expf(st[mt][nt][1] - mrow);
                float p2 = __expf(st[mt][nt][2] - mrow);
                float p3 = __expf(st[mt][nt][3] - mrow);
                psum[nt] += p0 + p1 + p2 + p3;
                ushort4 pk;
                pk.x = f2bf(p0); pk.y = f2bf(p1); pk.z = f2bf(p2); pk.w = f2bf(p3);
                *(ushort4*)&Ps[nt * 16 + fr][w * 32 + mt * 16 + quad * 4] = pk;
            }
        }
#pragma unroll
        for (int nt = 0; nt < 2; nt++)
            red[nt * 16 + fr][w * 4 + quad] = psum[nt];
        __syncthreads();

        if (t < QT) {
            float s = 0.f;
#pragma unroll
            for (int k = 0; k < 16; k++) s += red[t][k];
            l_s[t] = l_s[t] * alpha_s[t] + s;
        }

        // ---- PV: wave w owns (q-tile mtq, d-tile ntd); rescale then mfma ----
#pragma unroll
        for (int r = 0; r < 4; r++) oacc[r] *= alpha_s[mtq * 16 + quad * 4 + r];
#pragma unroll
        for (int k0 = 0; k0 < ST; k0 += 32) {
            bf16x8 ap = *(const bf16x8*)&Ps[mtq * 16 + fr][k0 + quad * 8];
            bf16x8 bv = *(const bf16x8*)&Vt[ntd * 16 + fr][k0 + quad * 8];
            oacc = __builtin_amdgcn_mfma_f32_16x16x32_bf16(ap, bv, oacc, 0, 0, 0);
        }
    }
    __syncthreads();

    int part = b * NSPLIT + sp;
    if (t < qlim) {
        mpart[((size_t)part * HH + h) * BQ + q0 + t] = m_s[t];
        lpart[((size_t)part * HH + h) * BQ + q0 + t] = l_s[t];
    }
#pragma unroll
    for (int r = 0; r < 4; r++) {
        int q = mtq * 16 + quad * 4 + r;
        if (q < qlim)
            Opart[((size_t)part * BQ + q0 + q) * DD + h * HDD + ntd * 16 + fr] = oacc[r];
    }
}

// ---------------- split-S combine -------------------------------------------
__global__ void attn_combine_kernel(const float* __restrict__ Opart,
                                    const float* __restrict__ mpart,
                                    const float* __restrict__ lpart,
                                    float* __restrict__ Out) {
    int row = blockIdx.x;
    int b = row / BQ, q = row % BQ;
    int t = threadIdx.x;
    int h = t / 32, d = t % 32;
    float mv[NSPLIT];
    float m_star = -1e30f;
#pragma unroll
    for (int sp = 0; sp < NSPLIT; sp++) {
        mv[sp] = mpart[((size_t)(b * NSPLIT + sp) * HH + h) * BQ + q];
        m_star = fmaxf(m_star, mv[sp]);
    }
    float l_star = 0.f, o = 0.f;
#pragma unroll
    for (int sp = 0; sp < NSPLIT; sp++) {
        float w = __expf(mv[sp] - m_star);
        l_star += lpart[((size_t)(b * NSPLIT + sp) * HH + h) * BQ + q] * w;
        o += Opart[((size_t)(b * NSPLIT + sp) * BQ + q) * DD + h * HDD + d] * w;
    }
    Out[(size_t)row * DD + h * HDD + d] = o / l_star;
}

// ---------------- attention (small-S path, self-attn) ------------------------
__global__ void attn_kernel(const float* __restrict__ Qm, int sq, int qo0,
                            const float* __restrict__ Km, int sk, int ko0,
                            const float* __restrict__ Vm, int sv, int vo0,
                            float* __restrict__ Out, int so, int oo0,
                            int Slen, int Qlen, float scale) {
    int q = blockIdx.x, h = blockIdx.y, b = blockIdx.z;
    int tid = threadIdx.x;
    __shared__ float qv[32];
    __shared__ float sc[4096];
    __shared__ float red[256];
    __shared__ float part[8][33];
    int qrow = b * Qlen + q;
    if (tid < 32) qv[tid] = Qm[(size_t)qrow * sq + qo0 + h * HDD + tid] * scale;
    __syncthreads();

    float lmax = -1e30f;
    for (int s = tid; s < Slen; s += 256) {
        const float* kp = Km + (size_t)(b * Slen + s) * sk + ko0 + h * HDD;
        float dot = 0.f;
#pragma unroll
        for (int d = 0; d < HDD; d += 4) {
            float4 k4 = *(const float4*)(kp + d);
            dot += qv[d] * k4.x + qv[d + 1] * k4.y + qv[d + 2] * k4.z + qv[d + 3] * k4.w;
        }
        sc[s] = dot;
        lmax = fmaxf(lmax, dot);
    }
    red[tid] = lmax; __syncthreads();
    for (int off = 128; off > 0; off >>= 1) {
        if (tid < off) red[tid] = fmaxf(red[tid], red[tid + off]);
        __syncthreads();
    }
    float m = red[0];
    __syncthreads();
    float lsum = 0.f;
    for (int s = tid; s < Slen; s += 256) {
        float e = __expf(sc[s] - m);
        sc[s] = e;
        lsum += e;
    }
    red[tid] = lsum; __syncthreads();
    for (int off = 128; off > 0; off >>= 1) {
        if (tid < off) red[tid] += red[tid + off];
        __syncthreads();
    }
    float inv = 1.0f / red[0];

    int d = tid & 31, g = tid >> 5;
    float acc = 0.f;
    for (int s = g; s < Slen; s += 8)
        acc += sc[s] * Vm[(size_t)(b * Slen + s) * sv + vo0 + h * HDD + d];
    part[g][d] = acc; __syncthreads();
    if (g == 0) {
        float t = 0.f;
#pragma unroll
        for (int gg = 0; gg < 8; gg++) t += part[gg][d];
        Out[(size_t)qrow * so + oo0 + h * HDD + d] = t * inv;
    }
}

extern "C" void kernel_launch(void* const* d_in, const int* in_sizes, int n_in,
                              void* d_out, int out_size, void* d_ws, size_t ws_size,
                              hipStream_t stream) {
    const float* queries    = (const float*)d_in[0];
    const float* pixel_feat = (const float*)d_in[1];
    const float* prev_mask  = (const float*)d_in[2];
    const float* cross_in_w  = (const float*)d_in[3];
    const float* cross_in_b  = (const float*)d_in[4];
    const float* cross_out_w = (const float*)d_in[5];
    const float* cross_out_b = (const float*)d_in[6];
    const float* self_in_w   = (const float*)d_in[7];
    const float* self_in_b   = (const float*)d_in[8];
    const float* self_out_w  = (const float*)d_in[9];
    const float* self_out_b  = (const float*)d_in[10];
    const float* ln_cross_g  = (const float*)d_in[11];
    const float* ln_cross_b  = (const float*)d_in[12];
    const float* ln_self_g   = (const float*)d_in[13];
    const float* ln_self_b   = (const float*)d_in[14];
    const float* ln_ffn_g    = (const float*)d_in[15];
    const float* ln_ffn_b    = (const float*)d_in[16];
    const float* ffn_w1 = (const float*)d_in[17];
    const float* ffn_b1 = (const float*)d_in[18];
    const float* ffn_w2 = (const float*)d_in[19];
    const float* ffn_b2 = (const float*)d_in[20];
    float* out = (float*)d_out;

    const int NQ = SB * BQ;        // 800
    const int NK = SB * SS;        // 32768

    float* ws = (float*)d_ws;
    unsigned* Mbits = (unsigned*)ws;   ws += (size_t)NQ * 128;          // 400 KB
    float* ln_buf   = ws;              ws += (size_t)NQ * DD;
    float* q_cross  = ws;              ws += (size_t)NQ * DD;
    unsigned short* KVbuf = (unsigned short*)ws;
    ws += (size_t)NK * DD;             // 32768 x 512 bf16 = NK*256 floats... (NK*512 ushorts)
    float* attn_out = ws;              ws += (size_t)NQ * DD;
    float* queries1 = ws;              ws += (size_t)NQ * DD;
    float* qkv      = ws;              ws += (size_t)NQ * 3 * DD;
    float* attn2    = ws;              ws += (size_t)NQ * DD;
    float* queries2 = ws;              ws += (size_t)NQ * DD;
    float* ffn_h    = ws;              ws += (size_t)NQ * 4 * DD;
    float* Opart    = ws;              ws += (size_t)SB * NSPLIT * BQ * DD;
    float* mpart    = ws;              ws += (size_t)SB * NSPLIT * HH * BQ;
    float* lpart    = ws;              ws += (size_t)SB * NSPLIT * HH * BQ;

    const float scale = 0.17677669529663687f;

    maskpack_kernel<<<NQ, 256, 0, stream>>>(prev_mask, Mbits);

    // ---- cross attention ----
    ln_kernel<<<NQ, 256, 0, stream>>>(queries, ln_cross_g, ln_cross_b, ln_buf);
    gemm_nt<<<dim3(DD / BN, (NQ + BM - 1) / BM), 256, 0, stream>>>(
        ln_buf, cross_in_w, cross_in_b, nullptr, q_cross, NQ, DD, DD, 0);
    // fused K+V projection -> bf16 [K|V], 32768 x 512
    gemm_kv_mfma<<<dim3(2 * DD / TN, NK / TM), 256, 0, stream>>>(
        pixel_feat, cross_in_w + (size_t)DD * DD, cross_in_b + DD,
        KVbuf, NK, 2 * DD, DD);
    cross_attn_mfma<<<dim3(4, HH, SB * NSPLIT), 256, 0, stream>>>(
        q_cross, KVbuf, Mbits, Opart, mpart, lpart);
    attn_combine_kernel<<<NQ, 256, 0, stream>>>(Opart, mpart, lpart, attn_out);
    gemm_nt<<<dim3(DD / BN, (NQ + BM - 1) / BM), 256, 0, stream>>>(
        attn_out, cross_out_w, cross_out_b, queries, queries1, NQ, DD, DD, 2);

    // ---- self attention ----
    ln_kernel<<<NQ, 256, 0, stream>>>(queries1, ln_self_g, ln_self_b, ln_buf);
    gemm_nt<<<dim3(3 * DD / BN, (NQ + BM - 1) / BM), 256, 0, stream>>>(
        ln_buf, self_in_w, self_in_b, nullptr, qkv, NQ, 3 * DD, DD, 0);
    attn_kernel<<<dim3(BQ, HH, SB), 256, 0, stream>>>(
        qkv, 3 * DD, 0, qkv, 3 * DD, DD, qkv, 3 * DD, 2 * DD,
        attn2, DD, 0, BQ, BQ, scale);
    gemm_nt<<<dim3(DD / BN, (NQ + BM - 1) / BM), 256, 0, stream>>>(
        attn2, self_out_w, self_out_b, queries1, queries2, NQ, DD, DD, 2);

    // ---- FFN ----
    ln_kernel<<<NQ, 256, 0, stream>>>(queries2, ln_ffn_g, ln_ffn_b, ln_buf);
    gemm_nt<<<dim3(4 * DD / BN, (NQ + BM - 1) / BM), 256, 0, stream>>>(
        ln_buf, ffn_w1, ffn_b1, nullptr, ffn_h, NQ, 4 * DD, DD, 1);
    gemm_nt<<<dim3(DD / BN, (NQ + BM - 1) / BM), 256, 0, stream>>>(
        ffn_h, ffn_w2, ffn_b2, queries2, out, NQ, DD, 4 * DD, 2);
}

// Round 5
// 329.793 us; speedup vs baseline: 4.3111x; 1.3225x over previous
//
#include <hip/hip_runtime.h>
#include <hip/hip_bf16.h>
#include <math.h>

#define BQ 100
#define SB 8
#define SS 4096
#define DD 256
#define HH 8
#define HDD 32
#define NSPLIT 4
#define SCHUNK (SS / NSPLIT)   // 1024

typedef __attribute__((ext_vector_type(8))) short bf16x8;
typedef __attribute__((ext_vector_type(4))) float f32x4;

__device__ inline unsigned short f2bf(float f) {
    union { float f; unsigned u; } v; v.f = f;
    unsigned r = v.u + 0x7fff + ((v.u >> 16) & 1);
    return (unsigned short)(r >> 16);
}

__device__ inline bf16x8 load_bf8(const float* p) {
    float4 a = *(const float4*)p;
    float4 b = *(const float4*)(p + 4);
    bf16x8 r;
    r[0] = (short)f2bf(a.x); r[1] = (short)f2bf(a.y);
    r[2] = (short)f2bf(a.z); r[3] = (short)f2bf(a.w);
    r[4] = (short)f2bf(b.x); r[5] = (short)f2bf(b.y);
    r[6] = (short)f2bf(b.z); r[7] = (short)f2bf(b.w);
    return r;
}

// ---------------- mask pack: bit s of row (b,q); all-ones if row empty ------
__global__ void maskpack_kernel(const float* __restrict__ mask, unsigned* __restrict__ Mbits) {
    int row = blockIdx.x, t = threadIdx.x;
    int w = t >> 6, lane = t & 63;
    __shared__ unsigned words[128];
    __shared__ unsigned orred[4];
    unsigned lor = 0;
    for (int i = 0; i < 16; i++) {
        int s = (w * 16 + i) * 64 + lane;
        unsigned long long bal = __ballot(mask[(size_t)row * SS + s] > 0.f);
        if (lane == 0) {
            words[(w * 16 + i) * 2] = (unsigned)bal;
            words[(w * 16 + i) * 2 + 1] = (unsigned)(bal >> 32);
        }
        lor |= (unsigned)(bal | (bal >> 32));
    }
    if (lane == 0) orred[w] = lor;
    __syncthreads();
    unsigned anyv = orred[0] | orred[1] | orred[2] | orred[3];
    if (t < 128) Mbits[(size_t)row * 128 + t] = anyv ? words[t] : 0xFFFFFFFFu;
}

// ---------------- LayerNorm over D=256, one block per row -------------------
__global__ void ln_kernel(const float* __restrict__ x, const float* __restrict__ g,
                          const float* __restrict__ b, float* __restrict__ y) {
    int row = blockIdx.x, tid = threadIdx.x;
    __shared__ float red[256];
    float v = x[(size_t)row * DD + tid];
    red[tid] = v; __syncthreads();
    for (int off = 128; off > 0; off >>= 1) {
        if (tid < off) red[tid] += red[tid + off];
        __syncthreads();
    }
    float mu = red[0] * (1.0f / DD);
    __syncthreads();
    float dv = v - mu;
    red[tid] = dv * dv; __syncthreads();
    for (int off = 128; off > 0; off >>= 1) {
        if (tid < off) red[tid] += red[tid + off];
        __syncthreads();
    }
    float var = red[0] * (1.0f / DD);
    float r = rsqrtf(var + 1e-5f);
    y[(size_t)row * DD + tid] = dv * r * g[tid] + b[tid];
}

// ---------------- skinny-M MFMA GEMM: barrier-free, wave-per-32x32 ----------
// C[m,n] = dot(A[m,:], W[n,:]) + bias[n]; MODE 0: none, 1: gelu, 2: +res.
// grid (N/128, M/32), 256 thr (4 waves); wave w owns cols n0=bx*128+w*32.
template<int KK, int MODE>
__global__ __launch_bounds__(256) void gemm_skinny(
        const float* __restrict__ A, const float* __restrict__ W,
        const float* __restrict__ bias, const float* __restrict__ res,
        float* __restrict__ C, int N) {
    const int w = threadIdx.x >> 6, lane = threadIdx.x & 63;
    const int fr = lane & 15, quad = lane >> 4;
    const int m0 = blockIdx.y * 32;
    const int n0 = blockIdx.x * 128 + w * 32;

    f32x4 acc[2][2] = {};
    const float* Ap0 = A + (size_t)(m0 + fr) * KK + quad * 8;
    const float* Ap1 = Ap0 + (size_t)16 * KK;
    const float* Wp0 = W + (size_t)(n0 + fr) * KK + quad * 8;
    const float* Wp1 = Wp0 + (size_t)16 * KK;

#pragma unroll 4
    for (int k0 = 0; k0 < KK; k0 += 32) {
        bf16x8 a0 = load_bf8(Ap0 + k0);
        bf16x8 a1 = load_bf8(Ap1 + k0);
        bf16x8 w0 = load_bf8(Wp0 + k0);
        bf16x8 w1 = load_bf8(Wp1 + k0);
        acc[0][0] = __builtin_amdgcn_mfma_f32_16x16x32_bf16(a0, w0, acc[0][0], 0, 0, 0);
        acc[0][1] = __builtin_amdgcn_mfma_f32_16x16x32_bf16(a0, w1, acc[0][1], 0, 0, 0);
        acc[1][0] = __builtin_amdgcn_mfma_f32_16x16x32_bf16(a1, w0, acc[1][0], 0, 0, 0);
        acc[1][1] = __builtin_amdgcn_mfma_f32_16x16x32_bf16(a1, w1, acc[1][1], 0, 0, 0);
    }

#pragma unroll
    for (int ni = 0; ni < 2; ni++) {
        int n = n0 + ni * 16 + fr;
        float bv = bias[n];
#pragma unroll
        for (int mi = 0; mi < 2; mi++) {
#pragma unroll
            for (int r = 0; r < 4; r++) {
                int m = m0 + mi * 16 + quad * 4 + r;
                float v = acc[mi][ni][r] + bv;
                if (MODE == 1) {
                    v = 0.5f * v * (1.0f + erff(v * 0.70710678118654752f));
                } else if (MODE == 2) {
                    v += res[(size_t)m * N + n];
                }
                C[(size_t)m * N + n] = v;
            }
        }
    }
}

// ---------------- bf16 MFMA GEMM: fused K+V projection, bf16 output ---------
#define TM 128
#define TN 128
#define TK 32
#define LSTR 40

__global__ __launch_bounds__(256, 2) void gemm_kv_mfma(
        const float* __restrict__ A, const float* __restrict__ W,
        const float* __restrict__ bias, unsigned short* __restrict__ C,
        int M, int N, int K) {
    __shared__ unsigned short As[TM][LSTR];
    __shared__ unsigned short Bs[TN][LSTR];
    int tid = threadIdx.x;
    int wave = tid / 64, lane = tid % 64;
    int m0 = blockIdx.y * TM, n0 = blockIdx.x * TN;
    int wm = (wave % 2) * 64, wn = (wave / 2) * 64;
    int lr = tid / 4;
    int lc = (tid % 4) * 8;
    int fr = lane % 16, quad = lane / 16;

    f32x4 acc[4][4] = {};

    for (int k0 = 0; k0 < K; k0 += TK) {
        __syncthreads();
#pragma unroll
        for (int half = 0; half < 2; half++) {
            int r = lr + half * 64;
            float4 a0 = *(const float4*)(A + (size_t)(m0 + r) * K + k0 + lc);
            float4 a1 = *(const float4*)(A + (size_t)(m0 + r) * K + k0 + lc + 4);
            uint4 pa;
            pa.x = (unsigned)f2bf(a0.x) | ((unsigned)f2bf(a0.y) << 16);
            pa.y = (unsigned)f2bf(a0.z) | ((unsigned)f2bf(a0.w) << 16);
            pa.z = (unsigned)f2bf(a1.x) | ((unsigned)f2bf(a1.y) << 16);
            pa.w = (unsigned)f2bf(a1.z) | ((unsigned)f2bf(a1.w) << 16);
            *(uint4*)&As[r][lc] = pa;
            float4 b0 = *(const float4*)(W + (size_t)(n0 + r) * K + k0 + lc);
            float4 b1 = *(const float4*)(W + (size_t)(n0 + r) * K + k0 + lc + 4);
            uint4 pb;
            pb.x = (unsigned)f2bf(b0.x) | ((unsigned)f2bf(b0.y) << 16);
            pb.y = (unsigned)f2bf(b0.z) | ((unsigned)f2bf(b0.w) << 16);
            pb.z = (unsigned)f2bf(b1.x) | ((unsigned)f2bf(b1.y) << 16);
            pb.w = (unsigned)f2bf(b1.z) | ((unsigned)f2bf(b1.w) << 16);
            *(uint4*)&Bs[r][lc] = pb;
        }
        __syncthreads();
        bf16x8 af[4], bf[4];
#pragma unroll
        for (int mi = 0; mi < 4; mi++)
            af[mi] = *(const bf16x8*)&As[wm + mi * 16 + fr][quad * 8];
#pragma unroll
        for (int ni = 0; ni < 4; ni++)
            bf[ni] = *(const bf16x8*)&Bs[wn + ni * 16 + fr][quad * 8];
#pragma unroll
        for (int mi = 0; mi < 4; mi++)
#pragma unroll
            for (int ni = 0; ni < 4; ni++)
                acc[mi][ni] = __builtin_amdgcn_mfma_f32_16x16x32_bf16(
                    af[mi], bf[ni], acc[mi][ni], 0, 0, 0);
    }

    float bv[4];
#pragma unroll
    for (int ni = 0; ni < 4; ni++) bv[ni] = bias[n0 + wn + ni * 16 + fr];
#pragma unroll
    for (int mi = 0; mi < 4; mi++) {
#pragma unroll
        for (int ni = 0; ni < 4; ni++) {
            int n = n0 + wn + ni * 16 + fr;
#pragma unroll
            for (int r = 0; r < 4; r++) {
                int m = m0 + wm + mi * 16 + quad * 4 + r;
                C[(size_t)m * N + n] = f2bf(acc[mi][ni][r] + bv[ni]);
            }
        }
    }
}

// ---------------- MFMA flash cross-attention, split-S -----------------------
#define QT 32
#define ST 128

__global__ __launch_bounds__(256) void cross_attn_mfma(
        const float* __restrict__ Qm,
        const unsigned short* __restrict__ KV,   // [B*SS][512] bf16: K | V
        const unsigned* __restrict__ Mbits,      // [B*BQ][128]
        float* __restrict__ Opart,
        float* __restrict__ mpart,
        float* __restrict__ lpart) {
    __shared__ unsigned short Qs[QT][40];
    __shared__ unsigned short Ks[ST][40];
    __shared__ unsigned short Vt[HDD][136];
    __shared__ unsigned short Ps[QT][136];
    __shared__ unsigned Mq[QT][4];
    __shared__ float red[QT][17];
    __shared__ float m_s[QT], alpha_s[QT], l_s[QT];

    const int qt = blockIdx.x, h = blockIdx.y;
    const int b = blockIdx.z / NSPLIT, sp = blockIdx.z % NSPLIT;
    const int t = threadIdx.x;
    const int w = t >> 6, lane = t & 63;
    const int fr = lane & 15, quad = lane >> 4;
    const int q0 = qt * QT;
    const int qlim = min(BQ - q0, QT);

    {
        int q = t >> 3, seg = t & 7;
        float4 v = make_float4(0.f, 0.f, 0.f, 0.f);
        if (q < qlim)
            v = *(const float4*)(Qm + (size_t)(b * BQ + q0 + q) * DD + h * HDD + seg * 4);
        const float sc = 0.17677669529663687f;
        ushort4 pk;
        pk.x = f2bf(v.x * sc); pk.y = f2bf(v.y * sc);
        pk.z = f2bf(v.z * sc); pk.w = f2bf(v.w * sc);
        *(ushort4*)&Qs[q][seg * 4] = pk;
        if (t < QT) { m_s[t] = -1e30f; l_s[t] = 0.f; }
    }

    f32x4 oacc = {0.f, 0.f, 0.f, 0.f};
    const int mtq = w & 1, ntd = w >> 1;

    for (int s0 = sp * SCHUNK; s0 < (sp + 1) * SCHUNK; s0 += ST) {
        __syncthreads();
        {
            int r = t >> 1, half = t & 1;
            const unsigned short* kp = KV + (size_t)(b * SS + s0 + r) * 512 + h * HDD + half * 16;
            uint4 k0v = *(const uint4*)(kp);
            uint4 k1v = *(const uint4*)(kp + 8);
            *(uint4*)&Ks[r][half * 16] = k0v;
            *(uint4*)&Ks[r][half * 16 + 8] = k1v;
            union { uint4 u; unsigned short s[8]; } v0, v1;
            v0.u = *(const uint4*)(kp + DD);
            v1.u = *(const uint4*)(kp + DD + 8);
#pragma unroll
            for (int j = 0; j < 8; j++) Vt[half * 16 + j][r] = v0.s[j];
#pragma unroll
            for (int j = 0; j < 8; j++) Vt[half * 16 + 8 + j][r] = v1.s[j];
        }
        if (t < 128) {
            int q = t >> 2, wd = t & 3;
            unsigned mword = 0xFFFFFFFFu;
            if (q < qlim)
                mword = Mbits[(size_t)(b * BQ + q0 + q) * 128 + (s0 >> 5) + wd];
            Mq[q][wd] = mword;
        }
        __syncthreads();

        bf16x8 af[2], bq[2];
#pragma unroll
        for (int mt = 0; mt < 2; mt++)
            af[mt] = *(const bf16x8*)&Ks[w * 32 + mt * 16 + fr][quad * 8];
#pragma unroll
        for (int nt = 0; nt < 2; nt++)
            bq[nt] = *(const bf16x8*)&Qs[nt * 16 + fr][quad * 8];
        f32x4 st[2][2];
#pragma unroll
        for (int mt = 0; mt < 2; mt++)
#pragma unroll
            for (int nt = 0; nt < 2; nt++) {
                f32x4 z = {0.f, 0.f, 0.f, 0.f};
                st[mt][nt] = __builtin_amdgcn_mfma_f32_16x16x32_bf16(af[mt], bq[nt], z, 0, 0, 0);
            }

        float pmax[2] = {-1e30f, -1e30f};
#pragma unroll
        for (int nt = 0; nt < 2; nt++) {
            unsigned mword = Mq[nt * 16 + fr][w];
#pragma unroll
            for (int mt = 0; mt < 2; mt++)
#pragma unroll
                for (int r = 0; r < 4; r++) {
                    int bitpos = mt * 16 + quad * 4 + r;
                    float v = st[mt][nt][r];
                    if (!((mword >> bitpos) & 1u)) v -= 10000.f;
                    st[mt][nt][r] = v;
                    pmax[nt] = fmaxf(pmax[nt], v);
                }
        }
#pragma unroll
        for (int nt = 0; nt < 2; nt++)
            red[nt * 16 + fr][w * 4 + quad] = pmax[nt];
        __syncthreads();

        if (t < QT) {
            float mt_ = -1e30f;
#pragma unroll
            for (int k = 0; k < 16; k++) mt_ = fmaxf(mt_, red[t][k]);
            float mo = m_s[t], mn = fmaxf(mo, mt_);
            m_s[t] = mn;
            alpha_s[t] = __expf(mo - mn);
        }
        __syncthreads();

        float psum[2] = {0.f, 0.f};
#pragma unroll
        for (int nt = 0; nt < 2; nt++) {
            float mrow = m_s[nt * 16 + fr];
#pragma unroll
            for (int mt = 0; mt < 2; mt++) {
                float p0 = __expf(st[mt][nt][0] - mrow);
                float p1 = __expf(st[mt][nt][1] - mrow);
                float p2 = __expf(st[mt][nt][2] - mrow);
                float p3 = __expf(st[mt][nt][3] - mrow);
                psum[nt] += p0 + p1 + p2 + p3;
                ushort4 pk;
                pk.x = f2bf(p0); pk.y = f2bf(p1); pk.z = f2bf(p2); pk.w = f2bf(p3);
                *(ushort4*)&Ps[nt * 16 + fr][w * 32 + mt * 16 + quad * 4] = pk;
            }
        }
#pragma unroll
        for (int nt = 0; nt < 2; nt++)
            red[nt * 16 + fr][w * 4 + quad] = psum[nt];
        __syncthreads();

        if (t < QT) {
            float s = 0.f;
#pragma unroll
            for (int k = 0; k < 16; k++) s += red[t][k];
            l_s[t] = l_s[t] * alpha_s[t] + s;
        }

#pragma unroll
        for (int r = 0; r < 4; r++) oacc[r] *= alpha_s[mtq * 16 + quad * 4 + r];
#pragma unroll
        for (int k0 = 0; k0 < ST; k0 += 32) {
            bf16x8 ap = *(const bf16x8*)&Ps[mtq * 16 + fr][k0 + quad * 8];
            bf16x8 bv = *(const bf16x8*)&Vt[ntd * 16 + fr][k0 + quad * 8];
            oacc = __builtin_amdgcn_mfma_f32_16x16x32_bf16(ap, bv, oacc, 0, 0, 0);
        }
    }
    __syncthreads();

    int part = b * NSPLIT + sp;
    if (t < qlim) {
        mpart[((size_t)part * HH + h) * BQ + q0 + t] = m_s[t];
        lpart[((size_t)part * HH + h) * BQ + q0 + t] = l_s[t];
    }
#pragma unroll
    for (int r = 0; r < 4; r++) {
        int q = mtq * 16 + quad * 4 + r;
        if (q < qlim)
            Opart[((size_t)part * BQ + q0 + q) * DD + h * HDD + ntd * 16 + fr] = oacc[r];
    }
}

// ---------------- split-S combine -------------------------------------------
__global__ void attn_combine_kernel(const float* __restrict__ Opart,
                                    const float* __restrict__ mpart,
                                    const float* __restrict__ lpart,
                                    float* __restrict__ Out) {
    int row = blockIdx.x;
    int b = row / BQ, q = row % BQ;
    int t = threadIdx.x;
    int h = t / 32, d = t % 32;
    float mv[NSPLIT];
    float m_star = -1e30f;
#pragma unroll
    for (int sp = 0; sp < NSPLIT; sp++) {
        mv[sp] = mpart[((size_t)(b * NSPLIT + sp) * HH + h) * BQ + q];
        m_star = fmaxf(m_star, mv[sp]);
    }
    float l_star = 0.f, o = 0.f;
#pragma unroll
    for (int sp = 0; sp < NSPLIT; sp++) {
        float w = __expf(mv[sp] - m_star);
        l_star += lpart[((size_t)(b * NSPLIT + sp) * HH + h) * BQ + q] * w;
        o += Opart[((size_t)(b * NSPLIT + sp) * BQ + q) * DD + h * HDD + d] * w;
    }
    Out[(size_t)row * DD + h * HDD + d] = o / l_star;
}

// ---------------- attention (small-S path, self-attn) ------------------------
__global__ void attn_kernel(const float* __restrict__ Qm, int sq, int qo0,
                            const float* __restrict__ Km, int sk, int ko0,
                            const float* __restrict__ Vm, int sv, int vo0,
                            float* __restrict__ Out, int so, int oo0,
                            int Slen, int Qlen, float scale) {
    int q = blockIdx.x, h = blockIdx.y, b = blockIdx.z;
    int tid = threadIdx.x;
    __shared__ float qv[32];
    __shared__ float sc[4096];
    __shared__ float red[256];
    __shared__ float part[8][33];
    int qrow = b * Qlen + q;
    if (tid < 32) qv[tid] = Qm[(size_t)qrow * sq + qo0 + h * HDD + tid] * scale;
    __syncthreads();

    float lmax = -1e30f;
    for (int s = tid; s < Slen; s += 256) {
        const float* kp = Km + (size_t)(b * Slen + s) * sk + ko0 + h * HDD;
        float dot = 0.f;
#pragma unroll
        for (int d = 0; d < HDD; d += 4) {
            float4 k4 = *(const float4*)(kp + d);
            dot += qv[d] * k4.x + qv[d + 1] * k4.y + qv[d + 2] * k4.z + qv[d + 3] * k4.w;
        }
        sc[s] = dot;
        lmax = fmaxf(lmax, dot);
    }
    red[tid] = lmax; __syncthreads();
    for (int off = 128; off > 0; off >>= 1) {
        if (tid < off) red[tid] = fmaxf(red[tid], red[tid + off]);
        __syncthreads();
    }
    float m = red[0];
    __syncthreads();
    float lsum = 0.f;
    for (int s = tid; s < Slen; s += 256) {
        float e = __expf(sc[s] - m);
        sc[s] = e;
        lsum += e;
    }
    red[tid] = lsum; __syncthreads();
    for (int off = 128; off > 0; off >>= 1) {
        if (tid < off) red[tid] += red[tid + off];
        __syncthreads();
    }
    float inv = 1.0f / red[0];

    int d = tid & 31, g = tid >> 5;
    float acc = 0.f;
    for (int s = g; s < Slen; s += 8)
        acc += sc[s] * Vm[(size_t)(b * Slen + s) * sv + vo0 + h * HDD + d];
    part[g][d] = acc; __syncthreads();
    if (g == 0) {
        float t = 0.f;
#pragma unroll
        for (int gg = 0; gg < 8; gg++) t += part[gg][d];
        Out[(size_t)qrow * so + oo0 + h * HDD + d] = t * inv;
    }
}

extern "C" void kernel_launch(void* const* d_in, const int* in_sizes, int n_in,
                              void* d_out, int out_size, void* d_ws, size_t ws_size,
                              hipStream_t stream) {
    const float* queries    = (const float*)d_in[0];
    const float* pixel_feat = (const float*)d_in[1];
    const float* prev_mask  = (const float*)d_in[2];
    const float* cross_in_w  = (const float*)d_in[3];
    const float* cross_in_b  = (const float*)d_in[4];
    const float* cross_out_w = (const float*)d_in[5];
    const float* cross_out_b = (const float*)d_in[6];
    const float* self_in_w   = (const float*)d_in[7];
    const float* self_in_b   = (const float*)d_in[8];
    const float* self_out_w  = (const float*)d_in[9];
    const float* self_out_b  = (const float*)d_in[10];
    const float* ln_cross_g  = (const float*)d_in[11];
    const float* ln_cross_b  = (const float*)d_in[12];
    const float* ln_self_g   = (const float*)d_in[13];
    const float* ln_self_b   = (const float*)d_in[14];
    const float* ln_ffn_g    = (const float*)d_in[15];
    const float* ln_ffn_b    = (const float*)d_in[16];
    const float* ffn_w1 = (const float*)d_in[17];
    const float* ffn_b1 = (const float*)d_in[18];
    const float* ffn_w2 = (const float*)d_in[19];
    const float* ffn_b2 = (const float*)d_in[20];
    float* out = (float*)d_out;

    const int NQ = SB * BQ;        // 800
    const int NK = SB * SS;        // 32768

    float* ws = (float*)d_ws;
    unsigned* Mbits = (unsigned*)ws;   ws += (size_t)NQ * 128;
    float* ln_buf   = ws;              ws += (size_t)NQ * DD;
    float* q_cross  = ws;              ws += (size_t)NQ * DD;
    unsigned short* KVbuf = (unsigned short*)ws;
    ws += (size_t)NK * DD;             // NK x 512 bf16
    float* attn_out = ws;              ws += (size_t)NQ * DD;
    float* queries1 = ws;              ws += (size_t)NQ * DD;
    float* qkv      = ws;              ws += (size_t)NQ * 3 * DD;
    float* attn2    = ws;              ws += (size_t)NQ * DD;
    float* queries2 = ws;              ws += (size_t)NQ * DD;
    float* ffn_h    = ws;              ws += (size_t)NQ * 4 * DD;
    float* Opart    = ws;              ws += (size_t)SB * NSPLIT * BQ * DD;
    float* mpart    = ws;              ws += (size_t)SB * NSPLIT * HH * BQ;
    float* lpart    = ws;              ws += (size_t)SB * NSPLIT * HH * BQ;

    const float scale = 0.17677669529663687f;

    maskpack_kernel<<<NQ, 256, 0, stream>>>(prev_mask, Mbits);

    // ---- cross attention ----
    ln_kernel<<<NQ, 256, 0, stream>>>(queries, ln_cross_g, ln_cross_b, ln_buf);
    gemm_skinny<256, 0><<<dim3(2, 25), 256, 0, stream>>>(
        ln_buf, cross_in_w, cross_in_b, nullptr, q_cross, DD);
    gemm_kv_mfma<<<dim3(2 * DD / TN, NK / TM), 256, 0, stream>>>(
        pixel_feat, cross_in_w + (size_t)DD * DD, cross_in_b + DD,
        KVbuf, NK, 2 * DD, DD);
    cross_attn_mfma<<<dim3(4, HH, SB * NSPLIT), 256, 0, stream>>>(
        q_cross, KVbuf, Mbits, Opart, mpart, lpart);
    attn_combine_kernel<<<NQ, 256, 0, stream>>>(Opart, mpart, lpart, attn_out);
    gemm_skinny<256, 2><<<dim3(2, 25), 256, 0, stream>>>(
        attn_out, cross_out_w, cross_out_b, queries, queries1, DD);

    // ---- self attention ----
    ln_kernel<<<NQ, 256, 0, stream>>>(queries1, ln_self_g, ln_self_b, ln_buf);
    gemm_skinny<256, 0><<<dim3(6, 25), 256, 0, stream>>>(
        ln_buf, self_in_w, self_in_b, nullptr, qkv, 3 * DD);
    attn_kernel<<<dim3(BQ, HH, SB), 256, 0, stream>>>(
        qkv, 3 * DD, 0, qkv, 3 * DD, DD, qkv, 3 * DD, 2 * DD,
        attn2, DD, 0, BQ, BQ, scale);
    gemm_skinny<256, 2><<<dim3(2, 25), 256, 0, stream>>>(
        attn2, self_out_w, self_out_b, queries1, queries2, DD);

    // ---- FFN ----
    ln_kernel<<<NQ, 256, 0, stream>>>(queries2, ln_ffn_g, ln_ffn_b, ln_buf);
    gemm_skinny<256, 1><<<dim3(8, 25), 256, 0, stream>>>(
        ln_buf, ffn_w1, ffn_b1, nullptr, ffn_h, 4 * DD);
    gemm_skinny<1024, 2><<<dim3(2, 25), 256, 0, stream>>>(
        ffn_h, ffn_w2, ffn_b2, queries2, out, DD);
}

// Round 7
// 308.841 us; speedup vs baseline: 4.6036x; 1.0678x over previous
//
#include <hip/hip_runtime.h>
#include <hip/hip_bf16.h>
#include <math.h>

#define BQ 100
#define SB 8
#define SS 4096
#define DD 256
#define HH 8
#define HDD 32
#define NSPLIT 4
#define SCHUNK (SS / NSPLIT)   // 1024

typedef __attribute__((ext_vector_type(8))) short bf16x8;
typedef __attribute__((ext_vector_type(4))) float f32x4;

__device__ inline unsigned short f2bf(float f) {
    union { float f; unsigned u; } v; v.f = f;
    unsigned r = v.u + 0x7fff + ((v.u >> 16) & 1);
    return (unsigned short)(r >> 16);
}

__device__ inline bf16x8 load_bf8(const float* p) {
    float4 a = *(const float4*)p;
    float4 b = *(const float4*)(p + 4);
    bf16x8 r;
    r[0] = (short)f2bf(a.x); r[1] = (short)f2bf(a.y);
    r[2] = (short)f2bf(a.z); r[3] = (short)f2bf(a.w);
    r[4] = (short)f2bf(b.x); r[5] = (short)f2bf(b.y);
    r[6] = (short)f2bf(b.z); r[7] = (short)f2bf(b.w);
    return r;
}

// ---------------- mask pack: bit s of row (b,q); all-ones if row empty ------
__global__ void maskpack_kernel(const float* __restrict__ mask, unsigned* __restrict__ Mbits) {
    int row = blockIdx.x, t = threadIdx.x;
    int w = t >> 6, lane = t & 63;
    __shared__ unsigned words[128];
    __shared__ unsigned orred[4];
    unsigned lor = 0;
    for (int i = 0; i < 16; i++) {
        int s = (w * 16 + i) * 64 + lane;
        unsigned long long bal = __ballot(mask[(size_t)row * SS + s] > 0.f);
        if (lane == 0) {
            words[(w * 16 + i) * 2] = (unsigned)bal;
            words[(w * 16 + i) * 2 + 1] = (unsigned)(bal >> 32);
        }
        lor |= (unsigned)(bal | (bal >> 32));
    }
    if (lane == 0) orred[w] = lor;
    __syncthreads();
    unsigned anyv = orred[0] | orred[1] | orred[2] | orred[3];
    if (t < 128) Mbits[(size_t)row * 128 + t] = anyv ? words[t] : 0xFFFFFFFFu;
}

// ---------------- LayerNorm over D=256, one block per row -------------------
__global__ void ln_kernel(const float* __restrict__ x, const float* __restrict__ g,
                          const float* __restrict__ b, float* __restrict__ y) {
    int row = blockIdx.x, tid = threadIdx.x;
    __shared__ float red[256];
    float v = x[(size_t)row * DD + tid];
    red[tid] = v; __syncthreads();
    for (int off = 128; off > 0; off >>= 1) {
        if (tid < off) red[tid] += red[tid + off];
        __syncthreads();
    }
    float mu = red[0] * (1.0f / DD);
    __syncthreads();
    float dv = v - mu;
    red[tid] = dv * dv; __syncthreads();
    for (int off = 128; off > 0; off >>= 1) {
        if (tid < off) red[tid] += red[tid + off];
        __syncthreads();
    }
    float var = red[0] * (1.0f / DD);
    float r = rsqrtf(var + 1e-5f);
    y[(size_t)row * DD + tid] = dv * r * g[tid] + b[tid];
}

// ---------------- skinny-M MFMA GEMM: barrier-free, wave-per-32x32 ----------
template<int KK, int MODE>
__global__ __launch_bounds__(256) void gemm_skinny(
        const float* __restrict__ A, const float* __restrict__ W,
        const float* __restrict__ bias, const float* __restrict__ res,
        float* __restrict__ C, int N) {
    const int w = threadIdx.x >> 6, lane = threadIdx.x & 63;
    const int fr = lane & 15, quad = lane >> 4;
    const int m0 = blockIdx.y * 32;
    const int n0 = blockIdx.x * 128 + w * 32;

    f32x4 acc[2][2] = {};
    const float* Ap0 = A + (size_t)(m0 + fr) * KK + quad * 8;
    const float* Ap1 = Ap0 + (size_t)16 * KK;
    const float* Wp0 = W + (size_t)(n0 + fr) * KK + quad * 8;
    const float* Wp1 = Wp0 + (size_t)16 * KK;

#pragma unroll 4
    for (int k0 = 0; k0 < KK; k0 += 32) {
        bf16x8 a0 = load_bf8(Ap0 + k0);
        bf16x8 a1 = load_bf8(Ap1 + k0);
        bf16x8 w0 = load_bf8(Wp0 + k0);
        bf16x8 w1 = load_bf8(Wp1 + k0);
        acc[0][0] = __builtin_amdgcn_mfma_f32_16x16x32_bf16(a0, w0, acc[0][0], 0, 0, 0);
        acc[0][1] = __builtin_amdgcn_mfma_f32_16x16x32_bf16(a0, w1, acc[0][1], 0, 0, 0);
        acc[1][0] = __builtin_amdgcn_mfma_f32_16x16x32_bf16(a1, w0, acc[1][0], 0, 0, 0);
        acc[1][1] = __builtin_amdgcn_mfma_f32_16x16x32_bf16(a1, w1, acc[1][1], 0, 0, 0);
    }

#pragma unroll
    for (int ni = 0; ni < 2; ni++) {
        int n = n0 + ni * 16 + fr;
        float bv = bias[n];
#pragma unroll
        for (int mi = 0; mi < 2; mi++) {
#pragma unroll
            for (int r = 0; r < 4; r++) {
                int m = m0 + mi * 16 + quad * 4 + r;
                float v = acc[mi][ni][r] + bv;
                if (MODE == 1) {
                    v = 0.5f * v * (1.0f + erff(v * 0.70710678118654752f));
                } else if (MODE == 2) {
                    v += res[(size_t)m * N + n];
                }
                C[(size_t)m * N + n] = v;
            }
        }
    }
}

// ---------------- bf16 MFMA GEMM: fused K+V projection ----------------------
// Writes head-blocked bf16: Kb[b][h][s][32], Vb[b][h][s][32].
#define TM 128
#define TN 128
#define TK 32
#define LSTR 40

__global__ __launch_bounds__(256, 2) void gemm_kv_mfma(
        const float* __restrict__ A, const float* __restrict__ W,
        const float* __restrict__ bias,
        unsigned short* __restrict__ Kb, unsigned short* __restrict__ Vb,
        int M, int K) {
    __shared__ unsigned short As[TM][LSTR];
    __shared__ unsigned short Bs[TN][LSTR];
    int tid = threadIdx.x;
    int wave = tid / 64, lane = tid % 64;
    int m0 = blockIdx.y * TM, n0 = blockIdx.x * TN;
    int wm = (wave % 2) * 64, wn = (wave / 2) * 64;
    int lr = tid / 4;
    int lc = (tid % 4) * 8;
    int fr = lane % 16, quad = lane / 16;

    f32x4 acc[4][4] = {};

    for (int k0 = 0; k0 < K; k0 += TK) {
        __syncthreads();
#pragma unroll
        for (int half = 0; half < 2; half++) {
            int r = lr + half * 64;
            float4 a0 = *(const float4*)(A + (size_t)(m0 + r) * K + k0 + lc);
            float4 a1 = *(const float4*)(A + (size_t)(m0 + r) * K + k0 + lc + 4);
            uint4 pa;
            pa.x = (unsigned)f2bf(a0.x) | ((unsigned)f2bf(a0.y) << 16);
            pa.y = (unsigned)f2bf(a0.z) | ((unsigned)f2bf(a0.w) << 16);
            pa.z = (unsigned)f2bf(a1.x) | ((unsigned)f2bf(a1.y) << 16);
            pa.w = (unsigned)f2bf(a1.z) | ((unsigned)f2bf(a1.w) << 16);
            *(uint4*)&As[r][lc] = pa;
            float4 b0 = *(const float4*)(W + (size_t)(n0 + r) * K + k0 + lc);
            float4 b1 = *(const float4*)(W + (size_t)(n0 + r) * K + k0 + lc + 4);
            uint4 pb;
            pb.x = (unsigned)f2bf(b0.x) | ((unsigned)f2bf(b0.y) << 16);
            pb.y = (unsigned)f2bf(b0.z) | ((unsigned)f2bf(b0.w) << 16);
            pb.z = (unsigned)f2bf(b1.x) | ((unsigned)f2bf(b1.y) << 16);
            pb.w = (unsigned)f2bf(b1.z) | ((unsigned)f2bf(b1.w) << 16);
            *(uint4*)&Bs[r][lc] = pb;
        }
        __syncthreads();
        bf16x8 af[4], bf[4];
#pragma unroll
        for (int mi = 0; mi < 4; mi++)
            af[mi] = *(const bf16x8*)&As[wm + mi * 16 + fr][quad * 8];
#pragma unroll
        for (int ni = 0; ni < 4; ni++)
            bf[ni] = *(const bf16x8*)&Bs[wn + ni * 16 + fr][quad * 8];
#pragma unroll
        for (int mi = 0; mi < 4; mi++)
#pragma unroll
            for (int ni = 0; ni < 4; ni++)
                acc[mi][ni] = __builtin_amdgcn_mfma_f32_16x16x32_bf16(
                    af[mi], bf[ni], acc[mi][ni], 0, 0, 0);
    }

#pragma unroll
    for (int ni = 0; ni < 4; ni++) {
        int n = n0 + wn + ni * 16 + fr;          // 0..511
        float bv = bias[n];
        unsigned short* dst = (n < 256) ? Kb : Vb;
        int hh = (n >> 5) & 7;
        int d = n & 31;
#pragma unroll
        for (int mi = 0; mi < 4; mi++) {
#pragma unroll
            for (int r = 0; r < 4; r++) {
                int m = m0 + wm + mi * 16 + quad * 4 + r;
                int bb = m >> 12;                 // m / SS
                int s = m & (SS - 1);
                dst[((((size_t)bb * HH + hh) * SS + s) << 5) + d] =
                    f2bf(acc[mi][ni][r] + bv);
            }
        }
    }
}

// ---------------- MFMA flash cross-attention, split-S, 64-q tiles -----------
// grid (2, H, B*NSPLIT); block handles 64 queries x SCHUNK keys.
#define QT 64
#define ST 128

__global__ __launch_bounds__(256) void cross_attn_mfma(
        const float* __restrict__ Qm,
        const unsigned short* __restrict__ Kb,   // [b][h][s][32] bf16
        const unsigned short* __restrict__ Vb,   // [b][h][s][32] bf16
        const unsigned* __restrict__ Mbits,      // [B*BQ][128]
        float* __restrict__ Opart,
        float* __restrict__ mpart,
        float* __restrict__ lpart) {
    __shared__ unsigned short Qs[QT][40];
    __shared__ unsigned short Ks[ST][40];
    __shared__ unsigned short Vt[HDD][136];
    __shared__ unsigned short Ps[QT][136];
    __shared__ unsigned Mq[QT][4];
    __shared__ float red[QT][17];
    __shared__ float m_s[QT], alpha_s[QT], l_s[QT];

    const int qb = blockIdx.x, h = blockIdx.y;
    const int b = blockIdx.z / NSPLIT, sp = blockIdx.z % NSPLIT;
    const int t = threadIdx.x;
    const int w = t >> 6, lane = t & 63;
    const int fr = lane & 15, quad = lane >> 4;
    const int q0 = qb * QT;
    const int qlim = min(BQ - q0, QT);           // 64 or 36

    // ---- stage Q (bf16, pre-scaled), init state ----
    {
        int q = t >> 2, c0 = (t & 3) * 8;
        float4 v0 = make_float4(0.f, 0.f, 0.f, 0.f), v1 = v0;
        if (q < qlim) {
            const float* qp = Qm + (size_t)(b * BQ + q0 + q) * DD + h * HDD + c0;
            v0 = *(const float4*)qp;
            v1 = *(const float4*)(qp + 4);
        }
        const float sc = 0.17677669529663687f;
        uint4 pq;
        pq.x = (unsigned)f2bf(v0.x * sc) | ((unsigned)f2bf(v0.y * sc) << 16);
        pq.y = (unsigned)f2bf(v0.z * sc) | ((unsigned)f2bf(v0.w * sc) << 16);
        pq.z = (unsigned)f2bf(v1.x * sc) | ((unsigned)f2bf(v1.y * sc) << 16);
        pq.w = (unsigned)f2bf(v1.z * sc) | ((unsigned)f2bf(v1.w * sc) << 16);
        *(uint4*)&Qs[q][c0] = pq;
        if (t < QT) { m_s[t] = -1e30f; l_s[t] = 0.f; }
    }

    f32x4 oacc[2] = {};
    const unsigned short* Kbase = Kb + (((size_t)(b * HH + h)) * SS << 5);
    const unsigned short* Vbase = Vb + (((size_t)(b * HH + h)) * SS << 5);

    for (int s0 = sp * SCHUNK; s0 < (sp + 1) * SCHUNK; s0 += ST) {
        __syncthreads();
        // ---- stage K tile (dense) + transpose V ----
        {
            int r = t >> 1, half = t & 1;
            const unsigned short* kp = Kbase + ((size_t)(s0 + r) << 5) + half * 16;
            *(uint4*)&Ks[r][half * 16] = *(const uint4*)kp;
            *(uint4*)&Ks[r][half * 16 + 8] = *(const uint4*)(kp + 8);
            const unsigned short* vp = Vbase + ((size_t)(s0 + r) << 5) + half * 16;
            union { uint4 u; unsigned short s[8]; } v0, v1;
            v0.u = *(const uint4*)vp;
            v1.u = *(const uint4*)(vp + 8);
#pragma unroll
            for (int j = 0; j < 8; j++) Vt[half * 16 + j][r] = v0.s[j];
#pragma unroll
            for (int j = 0; j < 8; j++) Vt[half * 16 + 8 + j][r] = v1.s[j];
        }
        // ---- stage mask bits: 4 words (=128 s-bits) per q ----
        {
            int q = t >> 2, wd = t & 3;
            unsigned mword = 0xFFFFFFFFu;
            if (q < qlim)
                mword = Mbits[(size_t)(b * BQ + q0 + q) * 128 + (s0 >> 5) + wd];
            Mq[q][wd] = mword;
        }
        __syncthreads();

        // ---- QK^T (S^T): wave w covers s in [w*32, w*32+32), all 64 q ----
        bf16x8 af[2];
#pragma unroll
        for (int mt = 0; mt < 2; mt++)
            af[mt] = *(const bf16x8*)&Ks[w * 32 + mt * 16 + fr][quad * 8];
        f32x4 st[2][4];
#pragma unroll
        for (int nt = 0; nt < 4; nt++) {
            bf16x8 bq = *(const bf16x8*)&Qs[nt * 16 + fr][quad * 8];
#pragma unroll
            for (int mt = 0; mt < 2; mt++) {
                f32x4 z = {0.f, 0.f, 0.f, 0.f};
                st[mt][nt] = __builtin_amdgcn_mfma_f32_16x16x32_bf16(af[mt], bq, z, 0, 0, 0);
            }
        }

        // ---- mask + per-lane max ----
        float pmax[4] = {-1e30f, -1e30f, -1e30f, -1e30f};
#pragma unroll
        for (int nt = 0; nt < 4; nt++) {
            unsigned mword = Mq[nt * 16 + fr][w];
#pragma unroll
            for (int mt = 0; mt < 2; mt++)
#pragma unroll
                for (int r = 0; r < 4; r++) {
                    int bitpos = mt * 16 + quad * 4 + r;
                    float v = st[mt][nt][r];
                    if (!((mword >> bitpos) & 1u)) v -= 10000.f;
                    st[mt][nt][r] = v;
                    pmax[nt] = fmaxf(pmax[nt], v);
                }
        }
#pragma unroll
        for (int nt = 0; nt < 4; nt++)
            red[nt * 16 + fr][w * 4 + quad] = pmax[nt];
        __syncthreads();

        if (t < QT) {
            float mt_ = -1e30f;
#pragma unroll
            for (int k = 0; k < 16; k++) mt_ = fmaxf(mt_, red[t][k]);
            float mo = m_s[t], mn = fmaxf(mo, mt_);
            m_s[t] = mn;
            alpha_s[t] = __expf(mo - mn);
        }
        __syncthreads();

        // ---- p = exp(s - m): bf16 P[q][s] + partial sums ----
        float psum[4] = {0.f, 0.f, 0.f, 0.f};
#pragma unroll
        for (int nt = 0; nt < 4; nt++) {
            float mrow = m_s[nt * 16 + fr];
#pragma unroll
            for (int mt = 0; mt < 2; mt++) {
                float p0 = __expf(st[mt][nt][0] - mrow);
                float p1 = __expf(st[mt][nt][1] - mrow);
                float p2 = __expf(st[mt][nt][2] - mrow);
                float p3 = __expf(st[mt][nt][3] - mrow);
                psum[nt] += p0 + p1 + p2 + p3;
                ushort4 pk;
                pk.x = f2bf(p0); pk.y = f2bf(p1); pk.z = f2bf(p2); pk.w = f2bf(p3);
                *(ushort4*)&Ps[nt * 16 + fr][w * 32 + mt * 16 + quad * 4] = pk;
            }
        }
#pragma unroll
        for (int nt = 0; nt < 4; nt++)
            red[nt * 16 + fr][w * 4 + quad] = psum[nt];
        __syncthreads();

        if (t < QT) {
            float s = 0.f;
#pragma unroll
            for (int k = 0; k < 16; k++) s += red[t][k];
            l_s[t] = l_s[t] * alpha_s[t] + s;
        }

        // ---- PV: wave w owns q-subtile w (16 q rows), d-tiles 0 and 1 ----
#pragma unroll
        for (int r = 0; r < 4; r++) {
            float a = alpha_s[w * 16 + quad * 4 + r];
            oacc[0][r] *= a; oacc[1][r] *= a;
        }
#pragma unroll
        for (int k0 = 0; k0 < ST; k0 += 32) {
            bf16x8 ap = *(const bf16x8*)&Ps[w * 16 + fr][k0 + quad * 8];
            bf16x8 bv0 = *(const bf16x8*)&Vt[fr][k0 + quad * 8];
            bf16x8 bv1 = *(const bf16x8*)&Vt[16 + fr][k0 + quad * 8];
            oacc[0] = __builtin_amdgcn_mfma_f32_16x16x32_bf16(ap, bv0, oacc[0], 0, 0, 0);
            oacc[1] = __builtin_amdgcn_mfma_f32_16x16x32_bf16(ap, bv1, oacc[1], 0, 0, 0);
        }
    }
    __syncthreads();

    int part = b * NSPLIT + sp;
    if (t < qlim) {
        mpart[((size_t)part * HH + h) * BQ + q0 + t] = m_s[t];
        lpart[((size_t)part * HH + h) * BQ + q0 + t] = l_s[t];
    }
#pragma unroll
    for (int nd = 0; nd < 2; nd++) {
#pragma unroll
        for (int r = 0; r < 4; r++) {
            int q = w * 16 + quad * 4 + r;
            if (q < qlim)
                Opart[((size_t)part * BQ + q0 + q) * DD + h * HDD + nd * 16 + fr] = oacc[nd][r];
        }
    }
}

// ---------------- split-S combine -------------------------------------------
__global__ void attn_combine_kernel(const float* __restrict__ Opart,
                                    const float* __restrict__ mpart,
                                    const float* __restrict__ lpart,
                                    float* __restrict__ Out) {
    int row = blockIdx.x;
    int b = row / BQ, q = row % BQ;
    int t = threadIdx.x;
    int h = t / 32, d = t % 32;
    float mv[NSPLIT];
    float m_star = -1e30f;
#pragma unroll
    for (int sp = 0; sp < NSPLIT; sp++) {
        mv[sp] = mpart[((size_t)(b * NSPLIT + sp) * HH + h) * BQ + q];
        m_star = fmaxf(m_star, mv[sp]);
    }
    float l_star = 0.f, o = 0.f;
#pragma unroll
    for (int sp = 0; sp < NSPLIT; sp++) {
        float w = __expf(mv[sp] - m_star);
        l_star += lpart[((size_t)(b * NSPLIT + sp) * HH + h) * BQ + q] * w;
        o += Opart[((size_t)(b * NSPLIT + sp) * BQ + q) * DD + h * HDD + d] * w;
    }
    Out[(size_t)row * DD + h * HDD + d] = o / l_star;
}

// ---------------- attention (small-S path, self-attn) ------------------------
__global__ void attn_kernel(const float* __restrict__ Qm, int sq, int qo0,
                            const float* __restrict__ Km, int sk, int ko0,
                            const float* __restrict__ Vm, int sv, int vo0,
                            float* __restrict__ Out, int so, int oo0,
                            int Slen, int Qlen, float scale) {
    int q = blockIdx.x, h = blockIdx.y, b = blockIdx.z;
    int tid = threadIdx.x;
    __shared__ float qv[32];
    __shared__ float sc[4096];
    __shared__ float red[256];
    __shared__ float part[8][33];
    int qrow = b * Qlen + q;
    if (tid < 32) qv[tid] = Qm[(size_t)qrow * sq + qo0 + h * HDD + tid] * scale;
    __syncthreads();

    float lmax = -1e30f;
    for (int s = tid; s < Slen; s += 256) {
        const float* kp = Km + (size_t)(b * Slen + s) * sk + ko0 + h * HDD;
        float dot = 0.f;
#pragma unroll
        for (int d = 0; d < HDD; d += 4) {
            float4 k4 = *(const float4*)(kp + d);
            dot += qv[d] * k4.x + qv[d + 1] * k4.y + qv[d + 2] * k4.z + qv[d + 3] * k4.w;
        }
        sc[s] = dot;
        lmax = fmaxf(lmax, dot);
    }
    red[tid] = lmax; __syncthreads();
    for (int off = 128; off > 0; off >>= 1) {
        if (tid < off) red[tid] = fmaxf(red[tid], red[tid + off]);
        __syncthreads();
    }
    float m = red[0];
    __syncthreads();
    float lsum = 0.f;
    for (int s = tid; s < Slen; s += 256) {
        float e = __expf(sc[s] - m);
        sc[s] = e;
        lsum += e;
    }
    red[tid] = lsum; __syncthreads();
    for (int off = 128; off > 0; off >>= 1) {
        if (tid < off) red[tid] += red[tid + off];
        __syncthreads();
    }
    float inv = 1.0f / red[0];

    int d = tid & 31, g = tid >> 5;
    float acc = 0.f;
    for (int s = g; s < Slen; s += 8)
        acc += sc[s] * Vm[(size_t)(b * Slen + s) * sv + vo0 + h * HDD + d];
    part[g][d] = acc; __syncthreads();
    if (g == 0) {
        float t = 0.f;
#pragma unroll
        for (int gg = 0; gg < 8; gg++) t += part[gg][d];
        Out[(size_t)qrow * so + oo0 + h * HDD + d] = t * inv;
    }
}

extern "C" void kernel_launch(void* const* d_in, const int* in_sizes, int n_in,
                              void* d_out, int out_size, void* d_ws, size_t ws_size,
                              hipStream_t stream) {
    const float* queries    = (const float*)d_in[0];
    const float* pixel_feat = (const float*)d_in[1];
    const float* prev_mask  = (const float*)d_in[2];
    const float* cross_in_w  = (const float*)d_in[3];
    const float* cross_in_b  = (const float*)d_in[4];
    const float* cross_out_w = (const float*)d_in[5];
    const float* cross_out_b = (const float*)d_in[6];
    const float* self_in_w   = (const float*)d_in[7];
    const float* self_in_b   = (const float*)d_in[8];
    const float* self_out_w  = (const float*)d_in[9];
    const float* self_out_b  = (const float*)d_in[10];
    const float* ln_cross_g  = (const float*)d_in[11];
    const float* ln_cross_b  = (const float*)d_in[12];
    const float* ln_self_g   = (const float*)d_in[13];
    const float* ln_self_b   = (const float*)d_in[14];
    const float* ln_ffn_g    = (const float*)d_in[15];
    const float* ln_ffn_b    = (const float*)d_in[16];
    const float* ffn_w1 = (const float*)d_in[17];
    const float* ffn_b1 = (const float*)d_in[18];
    const float* ffn_w2 = (const float*)d_in[19];
    const float* ffn_b2 = (const float*)d_in[20];
    float* out = (float*)d_out;

    const int NQ = SB * BQ;        // 800
    const int NK = SB * SS;        // 32768

    float* ws = (float*)d_ws;
    unsigned* Mbits = (unsigned*)ws;   ws += (size_t)NQ * 128;
    float* ln_buf   = ws;              ws += (size_t)NQ * DD;
    float* q_cross  = ws;              ws += (size_t)NQ * DD;
    unsigned short* Kbk = (unsigned short*)ws;
    ws += (size_t)NK * DD / 2;         // NK x 256 bf16 (head-blocked) = 16 MB
    unsigned short* Vbk = (unsigned short*)ws;
    ws += (size_t)NK * DD / 2;         // 16 MB
    float* attn_out = ws;              ws += (size_t)NQ * DD;
    float* queries1 = ws;              ws += (size_t)NQ * DD;
    float* qkv      = ws;              ws += (size_t)NQ * 3 * DD;
    float* attn2    = ws;              ws += (size_t)NQ * DD;
    float* queries2 = ws;              ws += (size_t)NQ * DD;
    float* ffn_h    = ws;              ws += (size_t)NQ * 4 * DD;
    float* Opart    = ws;              ws += (size_t)SB * NSPLIT * BQ * DD;
    float* mpart    = ws;              ws += (size_t)SB * NSPLIT * HH * BQ;
    float* lpart    = ws;              ws += (size_t)SB * NSPLIT * HH * BQ;

    const float scale = 0.17677669529663687f;

    maskpack_kernel<<<NQ, 256, 0, stream>>>(prev_mask, Mbits);

    // ---- cross attention ----
    ln_kernel<<<NQ, 256, 0, stream>>>(queries, ln_cross_g, ln_cross_b, ln_buf);
    gemm_skinny<256, 0><<<dim3(2, 25), 256, 0, stream>>>(
        ln_buf, cross_in_w, cross_in_b, nullptr, q_cross, DD);
    gemm_kv_mfma<<<dim3(2 * DD / TN, NK / TM), 256, 0, stream>>>(
        pixel_feat, cross_in_w + (size_t)DD * DD, cross_in_b + DD,
        Kbk, Vbk, NK, DD);
    cross_attn_mfma<<<dim3(2, HH, SB * NSPLIT), 256, 0, stream>>>(
        q_cross, Kbk, Vbk, Mbits, Opart, mpart, lpart);
    attn_combine_kernel<<<NQ, 256, 0, stream>>>(Opart, mpart, lpart, attn_out);
    gemm_skinny<256, 2><<<dim3(2, 25), 256, 0, stream>>>(
        attn_out, cross_out_w, cross_out_b, queries, queries1, DD);

    // ---- self attention ----
    ln_kernel<<<NQ, 256, 0, stream>>>(queries1, ln_self_g, ln_self_b, ln_buf);
    gemm_skinny<256, 0><<<dim3(6, 25), 256, 0, stream>>>(
        ln_buf, self_in_w, self_in_b, nullptr, qkv, 3 * DD);
    attn_kernel<<<dim3(BQ, HH, SB), 256, 0, stream>>>(
        qkv, 3 * DD, 0, qkv, 3 * DD, DD, qkv, 3 * DD, 2 * DD,
        attn2, DD, 0, BQ, BQ, scale);
    gemm_skinny<256, 2><<<dim3(2, 25), 256, 0, stream>>>(
        attn2, self_out_w, self_out_b, queries1, queries2, DD);

    // ---- FFN ----
    ln_kernel<<<NQ, 256, 0, stream>>>(queries2, ln_ffn_g, ln_ffn_b, ln_buf);
    gemm_skinny<256, 1><<<dim3(8, 25), 256, 0, stream>>>(
        ln_buf, ffn_w1, ffn_b1, nullptr, ffn_h, 4 * DD);
    gemm_skinny<1024, 2><<<dim3(2, 25), 256, 0, stream>>>(
        ffn_h, ffn_w2, ffn_b2, queries2, out, DD);
}

// Round 8
// 286.247 us; speedup vs baseline: 4.9670x; 1.0789x over previous
//
#include <hip/hip_runtime.h>
#include <hip/hip_bf16.h>
#include <math.h>

#define BQ 100
#define SB 8
#define SS 4096
#define DD 256
#define HH 8
#define HDD 32
#define NSPLIT 4
#define SCHUNK (SS / NSPLIT)   // 1024
#define MROWS 800              // SB*BQ

typedef __attribute__((ext_vector_type(8))) short bf16x8;
typedef __attribute__((ext_vector_type(4))) float f32x4;

__device__ inline unsigned short f2bf(float f) {
    union { float f; unsigned u; } v; v.f = f;
    unsigned r = v.u + 0x7fff + ((v.u >> 16) & 1);
    return (unsigned short)(r >> 16);
}

__device__ inline bf16x8 load_bf8(const float* p) {
    float4 a = *(const float4*)p;
    float4 b = *(const float4*)(p + 4);
    bf16x8 r;
    r[0] = (short)f2bf(a.x); r[1] = (short)f2bf(a.y);
    r[2] = (short)f2bf(a.z); r[3] = (short)f2bf(a.w);
    r[4] = (short)f2bf(b.x); r[5] = (short)f2bf(b.y);
    r[6] = (short)f2bf(b.z); r[7] = (short)f2bf(b.w);
    return r;
}

// ---------------- mask pack: bit s of row (b,q); all-ones if row empty ------
__global__ void maskpack_kernel(const float* __restrict__ mask, unsigned* __restrict__ Mbits) {
    int row = blockIdx.x, t = threadIdx.x;
    int w = t >> 6, lane = t & 63;
    __shared__ unsigned words[128];
    __shared__ unsigned orred[4];
    unsigned lor = 0;
    for (int i = 0; i < 16; i++) {
        int s = (w * 16 + i) * 64 + lane;
        unsigned long long bal = __ballot(mask[(size_t)row * SS + s] > 0.f);
        if (lane == 0) {
            words[(w * 16 + i) * 2] = (unsigned)bal;
            words[(w * 16 + i) * 2 + 1] = (unsigned)(bal >> 32);
        }
        lor |= (unsigned)(bal | (bal >> 32));
    }
    if (lane == 0) orred[w] = lor;
    __syncthreads();
    unsigned anyv = orred[0] | orred[1] | orred[2] | orred[3];
    if (t < 128) Mbits[(size_t)row * 128 + t] = anyv ? words[t] : 0xFFFFFFFFu;
}

// ---------------- LayerNorm over D=256, one block per row -------------------
__global__ void ln_kernel(const float* __restrict__ x, const float* __restrict__ g,
                          const float* __restrict__ b, float* __restrict__ y) {
    int row = blockIdx.x, tid = threadIdx.x;
    __shared__ float red[256];
    float v = x[(size_t)row * DD + tid];
    red[tid] = v; __syncthreads();
    for (int off = 128; off > 0; off >>= 1) {
        if (tid < off) red[tid] += red[tid + off];
        __syncthreads();
    }
    float mu = red[0] * (1.0f / DD);
    __syncthreads();
    float dv = v - mu;
    red[tid] = dv * dv; __syncthreads();
    for (int off = 128; off > 0; off >>= 1) {
        if (tid < off) red[tid] += red[tid + off];
        __syncthreads();
    }
    float var = red[0] * (1.0f / DD);
    float r = rsqrtf(var + 1e-5f);
    y[(size_t)row * DD + tid] = dv * r * g[tid] + b[tid];
}

// ---------------- one-wave MFMA GEMM: 32x32 tile/block, optional split-K ----
// grid (N/32, M/32, SPLITK), 64 thr. SPLITK==1: full epilogue (MODE).
// SPLITK>1: fp32 partial to Cp[sk][m][n]; combine kernel applies epilogue.
template<int KK, int SPLITK, int MODE>
__global__ __launch_bounds__(64, 4) void gemm_skinny2(
        const float* __restrict__ A, const float* __restrict__ W,
        const float* __restrict__ bias, const float* __restrict__ res,
        float* __restrict__ C, float* __restrict__ Cp, int N) {
    const int lane = threadIdx.x;
    const int fr = lane & 15, quad = lane >> 4;
    const int m0 = blockIdx.y * 32;
    const int n0 = blockIdx.x * 32;
    const int sk = blockIdx.z;
    const int KCH = KK / SPLITK;

    f32x4 acc[2][2] = {};
    const float* Ap0 = A + (size_t)(m0 + fr) * KK + sk * KCH + quad * 8;
    const float* Ap1 = Ap0 + (size_t)16 * KK;
    const float* Wp0 = W + (size_t)(n0 + fr) * KK + sk * KCH + quad * 8;
    const float* Wp1 = Wp0 + (size_t)16 * KK;

#pragma unroll
    for (int k0 = 0; k0 < KCH; k0 += 32) {
        bf16x8 a0 = load_bf8(Ap0 + k0);
        bf16x8 a1 = load_bf8(Ap1 + k0);
        bf16x8 w0 = load_bf8(Wp0 + k0);
        bf16x8 w1 = load_bf8(Wp1 + k0);
        acc[0][0] = __builtin_amdgcn_mfma_f32_16x16x32_bf16(a0, w0, acc[0][0], 0, 0, 0);
        acc[0][1] = __builtin_amdgcn_mfma_f32_16x16x32_bf16(a0, w1, acc[0][1], 0, 0, 0);
        acc[1][0] = __builtin_amdgcn_mfma_f32_16x16x32_bf16(a1, w0, acc[1][0], 0, 0, 0);
        acc[1][1] = __builtin_amdgcn_mfma_f32_16x16x32_bf16(a1, w1, acc[1][1], 0, 0, 0);
    }

    if (SPLITK == 1) {
#pragma unroll
        for (int ni = 0; ni < 2; ni++) {
            int n = n0 + ni * 16 + fr;
            float bv = bias[n];
#pragma unroll
            for (int mi = 0; mi < 2; mi++) {
#pragma unroll
                for (int r = 0; r < 4; r++) {
                    int m = m0 + mi * 16 + quad * 4 + r;
                    float v = acc[mi][ni][r] + bv;
                    if (MODE == 1) {
                        v = 0.5f * v * (1.0f + erff(v * 0.70710678118654752f));
                    } else if (MODE == 2) {
                        v += res[(size_t)m * N + n];
                    }
                    C[(size_t)m * N + n] = v;
                }
            }
        }
    } else {
        float* dst = Cp + (size_t)sk * MROWS * N;
#pragma unroll
        for (int ni = 0; ni < 2; ni++) {
            int n = n0 + ni * 16 + fr;
#pragma unroll
            for (int mi = 0; mi < 2; mi++) {
#pragma unroll
                for (int r = 0; r < 4; r++) {
                    int m = m0 + mi * 16 + quad * 4 + r;
                    dst[(size_t)m * N + n] = acc[mi][ni][r];
                }
            }
        }
    }
}

// ---------------- split-K combine: sum partials + epilogue ------------------
template<int SPLITK, int MODE>
__global__ void gemm_combine(const float* __restrict__ Cp,
                             const float* __restrict__ bias,
                             const float* __restrict__ res,
                             float* __restrict__ C, int N) {
    int m = blockIdx.x;
    for (int n = threadIdx.x; n < N; n += 256) {
        float v = bias[n];
#pragma unroll
        for (int sk = 0; sk < SPLITK; sk++)
            v += Cp[((size_t)sk * MROWS + m) * N + n];
        if (MODE == 1) {
            v = 0.5f * v * (1.0f + erff(v * 0.70710678118654752f));
        } else if (MODE == 2) {
            v += res[(size_t)m * N + n];
        }
        C[(size_t)m * N + n] = v;
    }
}

// ---------------- bf16 MFMA GEMM: fused K+V projection ----------------------
// Writes head-blocked bf16: Kb[b][h][s][32], Vb[b][h][s][32].
#define TM 128
#define TN 128
#define TK 32
#define LSTR 40

__global__ __launch_bounds__(256, 2) void gemm_kv_mfma(
        const float* __restrict__ A, const float* __restrict__ W,
        const float* __restrict__ bias,
        unsigned short* __restrict__ Kb, unsigned short* __restrict__ Vb,
        int M, int K) {
    __shared__ unsigned short As[TM][LSTR];
    __shared__ unsigned short Bs[TN][LSTR];
    int tid = threadIdx.x;
    int wave = tid / 64, lane = tid % 64;
    int m0 = blockIdx.y * TM, n0 = blockIdx.x * TN;
    int wm = (wave % 2) * 64, wn = (wave / 2) * 64;
    int lr = tid / 4;
    int lc = (tid % 4) * 8;
    int fr = lane % 16, quad = lane / 16;

    f32x4 acc[4][4] = {};

    for (int k0 = 0; k0 < K; k0 += TK) {
        __syncthreads();
#pragma unroll
        for (int half = 0; half < 2; half++) {
            int r = lr + half * 64;
            float4 a0 = *(const float4*)(A + (size_t)(m0 + r) * K + k0 + lc);
            float4 a1 = *(const float4*)(A + (size_t)(m0 + r) * K + k0 + lc + 4);
            uint4 pa;
            pa.x = (unsigned)f2bf(a0.x) | ((unsigned)f2bf(a0.y) << 16);
            pa.y = (unsigned)f2bf(a0.z) | ((unsigned)f2bf(a0.w) << 16);
            pa.z = (unsigned)f2bf(a1.x) | ((unsigned)f2bf(a1.y) << 16);
            pa.w = (unsigned)f2bf(a1.z) | ((unsigned)f2bf(a1.w) << 16);
            *(uint4*)&As[r][lc] = pa;
            float4 b0 = *(const float4*)(W + (size_t)(n0 + r) * K + k0 + lc);
            float4 b1 = *(const float4*)(W + (size_t)(n0 + r) * K + k0 + lc + 4);
            uint4 pb;
            pb.x = (unsigned)f2bf(b0.x) | ((unsigned)f2bf(b0.y) << 16);
            pb.y = (unsigned)f2bf(b0.z) | ((unsigned)f2bf(b0.w) << 16);
            pb.z = (unsigned)f2bf(b1.x) | ((unsigned)f2bf(b1.y) << 16);
            pb.w = (unsigned)f2bf(b1.z) | ((unsigned)f2bf(b1.w) << 16);
            *(uint4*)&Bs[r][lc] = pb;
        }
        __syncthreads();
        bf16x8 af[4], bf[4];
#pragma unroll
        for (int mi = 0; mi < 4; mi++)
            af[mi] = *(const bf16x8*)&As[wm + mi * 16 + fr][quad * 8];
#pragma unroll
        for (int ni = 0; ni < 4; ni++)
            bf[ni] = *(const bf16x8*)&Bs[wn + ni * 16 + fr][quad * 8];
#pragma unroll
        for (int mi = 0; mi < 4; mi++)
#pragma unroll
            for (int ni = 0; ni < 4; ni++)
                acc[mi][ni] = __builtin_amdgcn_mfma_f32_16x16x32_bf16(
                    af[mi], bf[ni], acc[mi][ni], 0, 0, 0);
    }

#pragma unroll
    for (int ni = 0; ni < 4; ni++) {
        int n = n0 + wn + ni * 16 + fr;          // 0..511
        float bv = bias[n];
        unsigned short* dst = (n < 256) ? Kb : Vb;
        int hh = (n >> 5) & 7;
        int d = n & 31;
#pragma unroll
        for (int mi = 0; mi < 4; mi++) {
#pragma unroll
            for (int r = 0; r < 4; r++) {
                int m = m0 + wm + mi * 16 + quad * 4 + r;
                int bb = m >> 12;                 // m / SS
                int s = m & (SS - 1);
                dst[((((size_t)bb * HH + hh) * SS + s) << 5) + d] =
                    f2bf(acc[mi][ni][r] + bv);
            }
        }
    }
}

// ---------------- MFMA flash cross-attention, split-S, 64-q tiles -----------
#define QT 64
#define ST 128

__global__ __launch_bounds__(256) void cross_attn_mfma(
        const float* __restrict__ Qm,
        const unsigned short* __restrict__ Kb,   // [b][h][s][32] bf16
        const unsigned short* __restrict__ Vb,   // [b][h][s][32] bf16
        const unsigned* __restrict__ Mbits,      // [B*BQ][128]
        float* __restrict__ Opart,
        float* __restrict__ mpart,
        float* __restrict__ lpart) {
    __shared__ unsigned short Qs[QT][40];
    __shared__ unsigned short Ks[ST][40];
    __shared__ unsigned short Vt[HDD][136];
    __shared__ unsigned short Ps[QT][136];
    __shared__ unsigned Mq[QT][4];
    __shared__ float red[QT][17];
    __shared__ float m_s[QT], alpha_s[QT], l_s[QT];

    const int qb = blockIdx.x, h = blockIdx.y;
    const int b = blockIdx.z / NSPLIT, sp = blockIdx.z % NSPLIT;
    const int t = threadIdx.x;
    const int w = t >> 6, lane = t & 63;
    const int fr = lane & 15, quad = lane >> 4;
    const int q0 = qb * QT;
    const int qlim = min(BQ - q0, QT);           // 64 or 36

    {
        int q = t >> 2, c0 = (t & 3) * 8;
        float4 v0 = make_float4(0.f, 0.f, 0.f, 0.f), v1 = v0;
        if (q < qlim) {
            const float* qp = Qm + (size_t)(b * BQ + q0 + q) * DD + h * HDD + c0;
            v0 = *(const float4*)qp;
            v1 = *(const float4*)(qp + 4);
        }
        const float sc = 0.17677669529663687f;
        uint4 pq;
        pq.x = (unsigned)f2bf(v0.x * sc) | ((unsigned)f2bf(v0.y * sc) << 16);
        pq.y = (unsigned)f2bf(v0.z * sc) | ((unsigned)f2bf(v0.w * sc) << 16);
        pq.z = (unsigned)f2bf(v1.x * sc) | ((unsigned)f2bf(v1.y * sc) << 16);
        pq.w = (unsigned)f2bf(v1.z * sc) | ((unsigned)f2bf(v1.w * sc) << 16);
        *(uint4*)&Qs[q][c0] = pq;
        if (t < QT) { m_s[t] = -1e30f; l_s[t] = 0.f; }
    }

    f32x4 oacc[2] = {};
    const unsigned short* Kbase = Kb + (((size_t)(b * HH + h)) * SS << 5);
    const unsigned short* Vbase = Vb + (((size_t)(b * HH + h)) * SS << 5);

    for (int s0 = sp * SCHUNK; s0 < (sp + 1) * SCHUNK; s0 += ST) {
        __syncthreads();
        {
            int r = t >> 1, half = t & 1;
            const unsigned short* kp = Kbase + ((size_t)(s0 + r) << 5) + half * 16;
            *(uint4*)&Ks[r][half * 16] = *(const uint4*)kp;
            *(uint4*)&Ks[r][half * 16 + 8] = *(const uint4*)(kp + 8);
            const unsigned short* vp = Vbase + ((size_t)(s0 + r) << 5) + half * 16;
            union { uint4 u; unsigned short s[8]; } v0, v1;
            v0.u = *(const uint4*)vp;
            v1.u = *(const uint4*)(vp + 8);
#pragma unroll
            for (int j = 0; j < 8; j++) Vt[half * 16 + j][r] = v0.s[j];
#pragma unroll
            for (int j = 0; j < 8; j++) Vt[half * 16 + 8 + j][r] = v1.s[j];
        }
        {
            int q = t >> 2, wd = t & 3;
            unsigned mword = 0xFFFFFFFFu;
            if (q < qlim)
                mword = Mbits[(size_t)(b * BQ + q0 + q) * 128 + (s0 >> 5) + wd];
            Mq[q][wd] = mword;
        }
        __syncthreads();

        bf16x8 af[2];
#pragma unroll
        for (int mt = 0; mt < 2; mt++)
            af[mt] = *(const bf16x8*)&Ks[w * 32 + mt * 16 + fr][quad * 8];
        f32x4 st[2][4];
#pragma unroll
        for (int nt = 0; nt < 4; nt++) {
            bf16x8 bq = *(const bf16x8*)&Qs[nt * 16 + fr][quad * 8];
#pragma unroll
            for (int mt = 0; mt < 2; mt++) {
                f32x4 z = {0.f, 0.f, 0.f, 0.f};
                st[mt][nt] = __builtin_amdgcn_mfma_f32_16x16x32_bf16(af[mt], bq, z, 0, 0, 0);
            }
        }

        float pmax[4] = {-1e30f, -1e30f, -1e30f, -1e30f};
#pragma unroll
        for (int nt = 0; nt < 4; nt++) {
            unsigned mword = Mq[nt * 16 + fr][w];
#pragma unroll
            for (int mt = 0; mt < 2; mt++)
#pragma unroll
                for (int r = 0; r < 4; r++) {
                    int bitpos = mt * 16 + quad * 4 + r;
                    float v = st[mt][nt][r];
                    if (!((mword >> bitpos) & 1u)) v -= 10000.f;
                    st[mt][nt][r] = v;
                    pmax[nt] = fmaxf(pmax[nt], v);
                }
        }
#pragma unroll
        for (int nt = 0; nt < 4; nt++)
            red[nt * 16 + fr][w * 4 + quad] = pmax[nt];
        __syncthreads();

        if (t < QT) {
            float mt_ = -1e30f;
#pragma unroll
            for (int k = 0; k < 16; k++) mt_ = fmaxf(mt_, red[t][k]);
            float mo = m_s[t], mn = fmaxf(mo, mt_);
            m_s[t] = mn;
            alpha_s[t] = __expf(mo - mn);
        }
        __syncthreads();

        float psum[4] = {0.f, 0.f, 0.f, 0.f};
#pragma unroll
        for (int nt = 0; nt < 4; nt++) {
            float mrow = m_s[nt * 16 + fr];
#pragma unroll
            for (int mt = 0; mt < 2; mt++) {
                float p0 = __expf(st[mt][nt][0] - mrow);
                float p1 = __expf(st[mt][nt][1] - mrow);
                float p2 = __expf(st[mt][nt][2] - mrow);
                float p3 = __expf(st[mt][nt][3] - mrow);
                psum[nt] += p0 + p1 + p2 + p3;
                ushort4 pk;
                pk.x = f2bf(p0); pk.y = f2bf(p1); pk.z = f2bf(p2); pk.w = f2bf(p3);
                *(ushort4*)&Ps[nt * 16 + fr][w * 32 + mt * 16 + quad * 4] = pk;
            }
        }
#pragma unroll
        for (int nt = 0; nt < 4; nt++)
            red[nt * 16 + fr][w * 4 + quad] = psum[nt];
        __syncthreads();

        if (t < QT) {
            float s = 0.f;
#pragma unroll
            for (int k = 0; k < 16; k++) s += red[t][k];
            l_s[t] = l_s[t] * alpha_s[t] + s;
        }

#pragma unroll
        for (int r = 0; r < 4; r++) {
            float a = alpha_s[w * 16 + quad * 4 + r];
            oacc[0][r] *= a; oacc[1][r] *= a;
        }
#pragma unroll
        for (int k0 = 0; k0 < ST; k0 += 32) {
            bf16x8 ap = *(const bf16x8*)&Ps[w * 16 + fr][k0 + quad * 8];
            bf16x8 bv0 = *(const bf16x8*)&Vt[fr][k0 + quad * 8];
            bf16x8 bv1 = *(const bf16x8*)&Vt[16 + fr][k0 + quad * 8];
            oacc[0] = __builtin_amdgcn_mfma_f32_16x16x32_bf16(ap, bv0, oacc[0], 0, 0, 0);
            oacc[1] = __builtin_amdgcn_mfma_f32_16x16x32_bf16(ap, bv1, oacc[1], 0, 0, 0);
        }
    }
    __syncthreads();

    int part = b * NSPLIT + sp;
    if (t < qlim) {
        mpart[((size_t)part * HH + h) * BQ + q0 + t] = m_s[t];
        lpart[((size_t)part * HH + h) * BQ + q0 + t] = l_s[t];
    }
#pragma unroll
    for (int nd = 0; nd < 2; nd++) {
#pragma unroll
        for (int r = 0; r < 4; r++) {
            int q = w * 16 + quad * 4 + r;
            if (q < qlim)
                Opart[((size_t)part * BQ + q0 + q) * DD + h * HDD + nd * 16 + fr] = oacc[nd][r];
        }
    }
}

// ---------------- split-S combine -------------------------------------------
__global__ void attn_combine_kernel(const float* __restrict__ Opart,
                                    const float* __restrict__ mpart,
                                    const float* __restrict__ lpart,
                                    float* __restrict__ Out) {
    int row = blockIdx.x;
    int b = row / BQ, q = row % BQ;
    int t = threadIdx.x;
    int h = t / 32, d = t % 32;
    float mv[NSPLIT];
    float m_star = -1e30f;
#pragma unroll
    for (int sp = 0; sp < NSPLIT; sp++) {
        mv[sp] = mpart[((size_t)(b * NSPLIT + sp) * HH + h) * BQ + q];
        m_star = fmaxf(m_star, mv[sp]);
    }
    float l_star = 0.f, o = 0.f;
#pragma unroll
    for (int sp = 0; sp < NSPLIT; sp++) {
        float w = __expf(mv[sp] - m_star);
        l_star += lpart[((size_t)(b * NSPLIT + sp) * HH + h) * BQ + q] * w;
        o += Opart[((size_t)(b * NSPLIT + sp) * BQ + q) * DD + h * HDD + d] * w;
    }
    Out[(size_t)row * DD + h * HDD + d] = o / l_star;
}

// ---------------- attention (small-S path, self-attn) ------------------------
__global__ void attn_kernel(const float* __restrict__ Qm, int sq, int qo0,
                            const float* __restrict__ Km, int sk, int ko0,
                            const float* __restrict__ Vm, int sv, int vo0,
                            float* __restrict__ Out, int so, int oo0,
                            int Slen, int Qlen, float scale) {
    int q = blockIdx.x, h = blockIdx.y, b = blockIdx.z;
    int tid = threadIdx.x;
    __shared__ float qv[32];
    __shared__ float sc[4096];
    __shared__ float red[256];
    __shared__ float part[8][33];
    int qrow = b * Qlen + q;
    if (tid < 32) qv[tid] = Qm[(size_t)qrow * sq + qo0 + h * HDD + tid] * scale;
    __syncthreads();

    float lmax = -1e30f;
    for (int s = tid; s < Slen; s += 256) {
        const float* kp = Km + (size_t)(b * Slen + s) * sk + ko0 + h * HDD;
        float dot = 0.f;
#pragma unroll
        for (int d = 0; d < HDD; d += 4) {
            float4 k4 = *(const float4*)(kp + d);
            dot += qv[d] * k4.x + qv[d + 1] * k4.y + qv[d + 2] * k4.z + qv[d + 3] * k4.w;
        }
        sc[s] = dot;
        lmax = fmaxf(lmax, dot);
    }
    red[tid] = lmax; __syncthreads();
    for (int off = 128; off > 0; off >>= 1) {
        if (tid < off) red[tid] = fmaxf(red[tid], red[tid + off]);
        __syncthreads();
    }
    float m = red[0];
    __syncthreads();
    float lsum = 0.f;
    for (int s = tid; s < Slen; s += 256) {
        float e = __expf(sc[s] - m);
        sc[s] = e;
        lsum += e;
    }
    red[tid] = lsum; __syncthreads();
    for (int off = 128; off > 0; off >>= 1) {
        if (tid < off) red[tid] += red[tid + off];
        __syncthreads();
    }
    float inv = 1.0f / red[0];

    int d = tid & 31, g = tid >> 5;
    float acc = 0.f;
    for (int s = g; s < Slen; s += 8)
        acc += sc[s] * Vm[(size_t)(b * Slen + s) * sv + vo0 + h * HDD + d];
    part[g][d] = acc; __syncthreads();
    if (g == 0) {
        float t = 0.f;
#pragma unroll
        for (int gg = 0; gg < 8; gg++) t += part[gg][d];
        Out[(size_t)qrow * so + oo0 + h * HDD + d] = t * inv;
    }
}

extern "C" void kernel_launch(void* const* d_in, const int* in_sizes, int n_in,
                              void* d_out, int out_size, void* d_ws, size_t ws_size,
                              hipStream_t stream) {
    const float* queries    = (const float*)d_in[0];
    const float* pixel_feat = (const float*)d_in[1];
    const float* prev_mask  = (const float*)d_in[2];
    const float* cross_in_w  = (const float*)d_in[3];
    const float* cross_in_b  = (const float*)d_in[4];
    const float* cross_out_w = (const float*)d_in[5];
    const float* cross_out_b = (const float*)d_in[6];
    const float* self_in_w   = (const float*)d_in[7];
    const float* self_in_b   = (const float*)d_in[8];
    const float* self_out_w  = (const float*)d_in[9];
    const float* self_out_b  = (const float*)d_in[10];
    const float* ln_cross_g  = (const float*)d_in[11];
    const float* ln_cross_b  = (const float*)d_in[12];
    const float* ln_self_g   = (const float*)d_in[13];
    const float* ln_self_b   = (const float*)d_in[14];
    const float* ln_ffn_g    = (const float*)d_in[15];
    const float* ln_ffn_b    = (const float*)d_in[16];
    const float* ffn_w1 = (const float*)d_in[17];
    const float* ffn_b1 = (const float*)d_in[18];
    const float* ffn_w2 = (const float*)d_in[19];
    const float* ffn_b2 = (const float*)d_in[20];
    float* out = (float*)d_out;

    const int NQ = SB * BQ;        // 800
    const int NK = SB * SS;        // 32768

    float* ws = (float*)d_ws;
    unsigned* Mbits = (unsigned*)ws;   ws += (size_t)NQ * 128;
    float* ln_buf   = ws;              ws += (size_t)NQ * DD;
    float* q_cross  = ws;              ws += (size_t)NQ * DD;
    unsigned short* Kbk = (unsigned short*)ws;
    ws += (size_t)NK * DD / 2;         // NK x 256 bf16 (head-blocked) = 16 MB
    unsigned short* Vbk = (unsigned short*)ws;
    ws += (size_t)NK * DD / 2;         // 16 MB
    float* attn_out = ws;              ws += (size_t)NQ * DD;
    float* queries1 = ws;              ws += (size_t)NQ * DD;
    float* qkv      = ws;              ws += (size_t)NQ * 3 * DD;
    float* attn2    = ws;              ws += (size_t)NQ * DD;
    float* queries2 = ws;              ws += (size_t)NQ * DD;
    float* ffn_h    = ws;              ws += (size_t)NQ * 4 * DD;
    float* Csplit   = ws;              ws += (size_t)4 * MROWS * DD;   // split-K partials
    float* Opart    = ws;              ws += (size_t)SB * NSPLIT * BQ * DD;
    float* mpart    = ws;              ws += (size_t)SB * NSPLIT * HH * BQ;
    float* lpart    = ws;              ws += (size_t)SB * NSPLIT * HH * BQ;

    const float scale = 0.17677669529663687f;

    maskpack_kernel<<<NQ, 256, 0, stream>>>(prev_mask, Mbits);

    // ---- cross attention ----
    ln_kernel<<<NQ, 256, 0, stream>>>(queries, ln_cross_g, ln_cross_b, ln_buf);
    gemm_skinny2<256, 1, 0><<<dim3(8, 25), 64, 0, stream>>>(
        ln_buf, cross_in_w, cross_in_b, nullptr, q_cross, nullptr, DD);
    gemm_kv_mfma<<<dim3(2 * DD / TN, NK / TM), 256, 0, stream>>>(
        pixel_feat, cross_in_w + (size_t)DD * DD, cross_in_b + DD,
        Kbk, Vbk, NK, DD);
    cross_attn_mfma<<<dim3(2, HH, SB * NSPLIT), 256, 0, stream>>>(
        q_cross, Kbk, Vbk, Mbits, Opart, mpart, lpart);
    attn_combine_kernel<<<NQ, 256, 0, stream>>>(Opart, mpart, lpart, attn_out);
    gemm_skinny2<256, 1, 2><<<dim3(8, 25), 64, 0, stream>>>(
        attn_out, cross_out_w, cross_out_b, queries, queries1, nullptr, DD);

    // ---- self attention ----
    ln_kernel<<<NQ, 256, 0, stream>>>(queries1, ln_self_g, ln_self_b, ln_buf);
    gemm_skinny2<256, 1, 0><<<dim3(24, 25), 64, 0, stream>>>(
        ln_buf, self_in_w, self_in_b, nullptr, qkv, nullptr, 3 * DD);
    attn_kernel<<<dim3(BQ, HH, SB), 256, 0, stream>>>(
        qkv, 3 * DD, 0, qkv, 3 * DD, DD, qkv, 3 * DD, 2 * DD,
        attn2, DD, 0, BQ, BQ, scale);
    gemm_skinny2<256, 1, 2><<<dim3(8, 25), 64, 0, stream>>>(
        attn2, self_out_w, self_out_b, queries1, queries2, nullptr, DD);

    // ---- FFN ----
    ln_kernel<<<NQ, 256, 0, stream>>>(queries2, ln_ffn_g, ln_ffn_b, ln_buf);
    gemm_skinny2<256, 1, 1><<<dim3(32, 25), 64, 0, stream>>>(
        ln_buf, ffn_w1, ffn_b1, nullptr, ffn_h, nullptr, 4 * DD);
    gemm_skinny2<1024, 4, 2><<<dim3(8, 25, 4), 64, 0, stream>>>(
        ffn_h, ffn_w2, ffn_b2, nullptr, nullptr, Csplit, DD);
    gemm_combine<4, 2><<<MROWS, 256, 0, stream>>>(
        Csplit, ffn_b2, queries2, out, DD);
}

// Round 9
// 282.677 us; speedup vs baseline: 5.0297x; 1.0126x over previous
//
#include <hip/hip_runtime.h>
#include <hip/hip_bf16.h>
#include <math.h>

#define BQ 100
#define SB 8
#define SS 4096
#define DD 256
#define HH 8
#define HDD 32
#define NSPLIT 4
#define SCHUNK (SS / NSPLIT)   // 1024
#define MROWS 800              // SB*BQ

typedef __attribute__((ext_vector_type(8))) short bf16x8;
typedef __attribute__((ext_vector_type(4))) float f32x4;

__device__ inline unsigned short f2bf(float f) {
    union { float f; unsigned u; } v; v.f = f;
    unsigned r = v.u + 0x7fff + ((v.u >> 16) & 1);
    return (unsigned short)(r >> 16);
}

__device__ inline bf16x8 load_bf8(const float* p) {
    float4 a = *(const float4*)p;
    float4 b = *(const float4*)(p + 4);
    bf16x8 r;
    r[0] = (short)f2bf(a.x); r[1] = (short)f2bf(a.y);
    r[2] = (short)f2bf(a.z); r[3] = (short)f2bf(a.w);
    r[4] = (short)f2bf(b.x); r[5] = (short)f2bf(b.y);
    r[6] = (short)f2bf(b.z); r[7] = (short)f2bf(b.w);
    return r;
}

// ---------------- mask pack: bit s of row (b,q); all-ones if row empty ------
__global__ void maskpack_kernel(const float* __restrict__ mask, unsigned* __restrict__ Mbits) {
    int row = blockIdx.x, t = threadIdx.x;
    int w = t >> 6, lane = t & 63;
    __shared__ unsigned words[128];
    __shared__ unsigned orred[4];
    unsigned lor = 0;
    for (int i = 0; i < 16; i++) {
        int s = (w * 16 + i) * 64 + lane;
        unsigned long long bal = __ballot(mask[(size_t)row * SS + s] > 0.f);
        if (lane == 0) {
            words[(w * 16 + i) * 2] = (unsigned)bal;
            words[(w * 16 + i) * 2 + 1] = (unsigned)(bal >> 32);
        }
        lor |= (unsigned)(bal | (bal >> 32));
    }
    if (lane == 0) orred[w] = lor;
    __syncthreads();
    unsigned anyv = orred[0] | orred[1] | orred[2] | orred[3];
    if (t < 128) Mbits[(size_t)row * 128 + t] = anyv ? words[t] : 0xFFFFFFFFu;
}

// ---------------- fused LayerNorm + one-wave MFMA GEMM ----------------------
// X fp32 [M][256]; per-block: LN 32 rows -> bf16 LDS, then 32x32 tile GEMM.
// MODE 0: bias only; 1: bias+gelu; 2: bias+res.
template<int MODE>
__global__ __launch_bounds__(64, 4) void ln_gemm(
        const float* __restrict__ X, const float* __restrict__ gam,
        const float* __restrict__ bet,
        const float* __restrict__ W, const float* __restrict__ bias,
        const float* __restrict__ res,
        float* __restrict__ C, int N) {
    __shared__ unsigned short As[32][264];
    __shared__ float mu_s[32], rs_s[32];
    __shared__ float prt[32][2][2];
    const int t = threadIdx.x;
    const int fr = t & 15, quad = t >> 4;
    const int m0 = blockIdx.y * 32, n0 = blockIdx.x * 32;
    const int row = t & 31, half = t >> 5;

    // pass 1: stats (each thread: half a row)
    const float* xp = X + (size_t)(m0 + row) * DD + half * 128;
    float s = 0.f, ss = 0.f;
#pragma unroll
    for (int c = 0; c < 128; c += 4) {
        float4 v = *(const float4*)(xp + c);
        s += v.x + v.y + v.z + v.w;
        ss += v.x * v.x + v.y * v.y + v.z * v.z + v.w * v.w;
    }
    prt[row][half][0] = s;
    prt[row][half][1] = ss;
    __syncthreads();
    if (t < 32) {
        float sum = prt[t][0][0] + prt[t][1][0];
        float sq  = prt[t][0][1] + prt[t][1][1];
        float mu = sum * (1.0f / DD);
        float var = sq * (1.0f / DD) - mu * mu;
        mu_s[t] = mu;
        rs_s[t] = rsqrtf(var + 1e-5f);
    }
    __syncthreads();
    // pass 2: normalize -> bf16 LDS
    {
        float mu = mu_s[row], r = rs_s[row];
#pragma unroll
        for (int c = 0; c < 128; c += 8) {
            int col = half * 128 + c;
            float4 v0 = *(const float4*)(xp + c);
            float4 v1 = *(const float4*)(xp + c + 4);
            float4 g0 = *(const float4*)(gam + col);
            float4 g1 = *(const float4*)(gam + col + 4);
            float4 b0 = *(const float4*)(bet + col);
            float4 b1 = *(const float4*)(bet + col + 4);
            uint4 pk;
            pk.x = (unsigned)f2bf((v0.x - mu) * r * g0.x + b0.x) |
                   ((unsigned)f2bf((v0.y - mu) * r * g0.y + b0.y) << 16);
            pk.y = (unsigned)f2bf((v0.z - mu) * r * g0.z + b0.z) |
                   ((unsigned)f2bf((v0.w - mu) * r * g0.w + b0.w) << 16);
            pk.z = (unsigned)f2bf((v1.x - mu) * r * g1.x + b1.x) |
                   ((unsigned)f2bf((v1.y - mu) * r * g1.y + b1.y) << 16);
            pk.w = (unsigned)f2bf((v1.z - mu) * r * g1.z + b1.z) |
                   ((unsigned)f2bf((v1.w - mu) * r * g1.w + b1.w) << 16);
            *(uint4*)&As[row][col] = pk;
        }
    }
    __syncthreads();

    // GEMM: 32x32 tile, K=256
    f32x4 acc[2][2] = {};
    const float* Wp0 = W + (size_t)(n0 + fr) * DD + quad * 8;
    const float* Wp1 = Wp0 + (size_t)16 * DD;
#pragma unroll
    for (int k0 = 0; k0 < DD; k0 += 32) {
        bf16x8 a0 = *(const bf16x8*)&As[fr][k0 + quad * 8];
        bf16x8 a1 = *(const bf16x8*)&As[16 + fr][k0 + quad * 8];
        bf16x8 w0 = load_bf8(Wp0 + k0);
        bf16x8 w1 = load_bf8(Wp1 + k0);
        acc[0][0] = __builtin_amdgcn_mfma_f32_16x16x32_bf16(a0, w0, acc[0][0], 0, 0, 0);
        acc[0][1] = __builtin_amdgcn_mfma_f32_16x16x32_bf16(a0, w1, acc[0][1], 0, 0, 0);
        acc[1][0] = __builtin_amdgcn_mfma_f32_16x16x32_bf16(a1, w0, acc[1][0], 0, 0, 0);
        acc[1][1] = __builtin_amdgcn_mfma_f32_16x16x32_bf16(a1, w1, acc[1][1], 0, 0, 0);
    }

#pragma unroll
    for (int ni = 0; ni < 2; ni++) {
        int n = n0 + ni * 16 + fr;
        float bv = bias[n];
#pragma unroll
        for (int mi = 0; mi < 2; mi++) {
#pragma unroll
            for (int r = 0; r < 4; r++) {
                int m = m0 + mi * 16 + quad * 4 + r;
                float v = acc[mi][ni][r] + bv;
                if (MODE == 1) {
                    v = 0.5f * v * (1.0f + erff(v * 0.70710678118654752f));
                } else if (MODE == 2) {
                    v += res[(size_t)m * N + n];
                }
                C[(size_t)m * N + n] = v;
            }
        }
    }
}

// ---------------- fused split-S combine + output projection -----------------
// Rebuilds combined cross-attn rows (bf16 LDS) from Opart/m/l, then GEMM
// with residual epilogue: C = comb @ W^T + bias + res.
__global__ __launch_bounds__(64, 4) void comb_gemm(
        const float* __restrict__ Opart, const float* __restrict__ mpart,
        const float* __restrict__ lpart,
        const float* __restrict__ W, const float* __restrict__ bias,
        const float* __restrict__ res,
        float* __restrict__ C) {
    __shared__ unsigned short As[32][264];
    const int t = threadIdx.x;
    const int fr = t & 15, quad = t >> 4;
    const int m0 = blockIdx.y * 32, n0 = blockIdx.x * 32;
    const int row = t & 31, half = t >> 5;

    {
        int m = m0 + row;
        int b = m / BQ, q = m % BQ;
#pragma unroll
        for (int h = half * 4; h < half * 4 + 4; h++) {
            float mv[NSPLIT], wsp[NSPLIT];
            float mstar = -1e30f;
#pragma unroll
            for (int sp = 0; sp < NSPLIT; sp++) {
                mv[sp] = mpart[((size_t)(b * NSPLIT + sp) * HH + h) * BQ + q];
                mstar = fmaxf(mstar, mv[sp]);
            }
            float lstar = 0.f;
#pragma unroll
            for (int sp = 0; sp < NSPLIT; sp++) {
                wsp[sp] = __expf(mv[sp] - mstar);
                lstar += lpart[((size_t)(b * NSPLIT + sp) * HH + h) * BQ + q] * wsp[sp];
            }
            float inv = 1.0f / lstar;
#pragma unroll
            for (int d = 0; d < HDD; d += 8) {
                float o[8] = {};
#pragma unroll
                for (int sp = 0; sp < NSPLIT; sp++) {
                    const float* op = Opart +
                        ((size_t)(b * NSPLIT + sp) * BQ + q) * DD + h * HDD + d;
                    float4 a = *(const float4*)op;
                    float4 b4 = *(const float4*)(op + 4);
                    o[0] += a.x * wsp[sp];  o[1] += a.y * wsp[sp];
                    o[2] += a.z * wsp[sp];  o[3] += a.w * wsp[sp];
                    o[4] += b4.x * wsp[sp]; o[5] += b4.y * wsp[sp];
                    o[6] += b4.z * wsp[sp]; o[7] += b4.w * wsp[sp];
                }
                uint4 pk;
                pk.x = (unsigned)f2bf(o[0] * inv) | ((unsigned)f2bf(o[1] * inv) << 16);
                pk.y = (unsigned)f2bf(o[2] * inv) | ((unsigned)f2bf(o[3] * inv) << 16);
                pk.z = (unsigned)f2bf(o[4] * inv) | ((unsigned)f2bf(o[5] * inv) << 16);
                pk.w = (unsigned)f2bf(o[6] * inv) | ((unsigned)f2bf(o[7] * inv) << 16);
                *(uint4*)&As[row][h * HDD + d] = pk;
            }
        }
    }
    __syncthreads();

    f32x4 acc[2][2] = {};
    const float* Wp0 = W + (size_t)(n0 + fr) * DD + quad * 8;
    const float* Wp1 = Wp0 + (size_t)16 * DD;
#pragma unroll
    for (int k0 = 0; k0 < DD; k0 += 32) {
        bf16x8 a0 = *(const bf16x8*)&As[fr][k0 + quad * 8];
        bf16x8 a1 = *(const bf16x8*)&As[16 + fr][k0 + quad * 8];
        bf16x8 w0 = load_bf8(Wp0 + k0);
        bf16x8 w1 = load_bf8(Wp1 + k0);
        acc[0][0] = __builtin_amdgcn_mfma_f32_16x16x32_bf16(a0, w0, acc[0][0], 0, 0, 0);
        acc[0][1] = __builtin_amdgcn_mfma_f32_16x16x32_bf16(a0, w1, acc[0][1], 0, 0, 0);
        acc[1][0] = __builtin_amdgcn_mfma_f32_16x16x32_bf16(a1, w0, acc[1][0], 0, 0, 0);
        acc[1][1] = __builtin_amdgcn_mfma_f32_16x16x32_bf16(a1, w1, acc[1][1], 0, 0, 0);
    }

#pragma unroll
    for (int ni = 0; ni < 2; ni++) {
        int n = n0 + ni * 16 + fr;
        float bv = bias[n];
#pragma unroll
        for (int mi = 0; mi < 2; mi++) {
#pragma unroll
            for (int r = 0; r < 4; r++) {
                int m = m0 + mi * 16 + quad * 4 + r;
                float v = acc[mi][ni][r] + bv + res[(size_t)m * DD + n];
                C[(size_t)m * DD + n] = v;
            }
        }
    }
}

// ---------------- one-wave MFMA GEMM: 32x32 tile/block, optional split-K ----
template<int KK, int SPLITK, int MODE>
__global__ __launch_bounds__(64, 4) void gemm_skinny2(
        const float* __restrict__ A, const float* __restrict__ W,
        const float* __restrict__ bias, const float* __restrict__ res,
        float* __restrict__ C, float* __restrict__ Cp, int N) {
    const int lane = threadIdx.x;
    const int fr = lane & 15, quad = lane >> 4;
    const int m0 = blockIdx.y * 32;
    const int n0 = blockIdx.x * 32;
    const int sk = blockIdx.z;
    const int KCH = KK / SPLITK;

    f32x4 acc[2][2] = {};
    const float* Ap0 = A + (size_t)(m0 + fr) * KK + sk * KCH + quad * 8;
    const float* Ap1 = Ap0 + (size_t)16 * KK;
    const float* Wp0 = W + (size_t)(n0 + fr) * KK + sk * KCH + quad * 8;
    const float* Wp1 = Wp0 + (size_t)16 * KK;

#pragma unroll
    for (int k0 = 0; k0 < KCH; k0 += 32) {
        bf16x8 a0 = load_bf8(Ap0 + k0);
        bf16x8 a1 = load_bf8(Ap1 + k0);
        bf16x8 w0 = load_bf8(Wp0 + k0);
        bf16x8 w1 = load_bf8(Wp1 + k0);
        acc[0][0] = __builtin_amdgcn_mfma_f32_16x16x32_bf16(a0, w0, acc[0][0], 0, 0, 0);
        acc[0][1] = __builtin_amdgcn_mfma_f32_16x16x32_bf16(a0, w1, acc[0][1], 0, 0, 0);
        acc[1][0] = __builtin_amdgcn_mfma_f32_16x16x32_bf16(a1, w0, acc[1][0], 0, 0, 0);
        acc[1][1] = __builtin_amdgcn_mfma_f32_16x16x32_bf16(a1, w1, acc[1][1], 0, 0, 0);
    }

    if (SPLITK == 1) {
#pragma unroll
        for (int ni = 0; ni < 2; ni++) {
            int n = n0 + ni * 16 + fr;
            float bv = bias[n];
#pragma unroll
            for (int mi = 0; mi < 2; mi++) {
#pragma unroll
                for (int r = 0; r < 4; r++) {
                    int m = m0 + mi * 16 + quad * 4 + r;
                    float v = acc[mi][ni][r] + bv;
                    if (MODE == 1) {
                        v = 0.5f * v * (1.0f + erff(v * 0.70710678118654752f));
                    } else if (MODE == 2) {
                        v += res[(size_t)m * N + n];
                    }
                    C[(size_t)m * N + n] = v;
                }
            }
        }
    } else {
        float* dst = Cp + (size_t)sk * MROWS * N;
#pragma unroll
        for (int ni = 0; ni < 2; ni++) {
            int n = n0 + ni * 16 + fr;
#pragma unroll
            for (int mi = 0; mi < 2; mi++) {
#pragma unroll
                for (int r = 0; r < 4; r++) {
                    int m = m0 + mi * 16 + quad * 4 + r;
                    dst[(size_t)m * N + n] = acc[mi][ni][r];
                }
            }
        }
    }
}

// ---------------- split-K combine: sum partials + epilogue ------------------
template<int SPLITK, int MODE>
__global__ void gemm_combine(const float* __restrict__ Cp,
                             const float* __restrict__ bias,
                             const float* __restrict__ res,
                             float* __restrict__ C, int N) {
    int m = blockIdx.x;
    for (int n = threadIdx.x; n < N; n += 256) {
        float v = bias[n];
#pragma unroll
        for (int sk = 0; sk < SPLITK; sk++)
            v += Cp[((size_t)sk * MROWS + m) * N + n];
        if (MODE == 1) {
            v = 0.5f * v * (1.0f + erff(v * 0.70710678118654752f));
        } else if (MODE == 2) {
            v += res[(size_t)m * N + n];
        }
        C[(size_t)m * N + n] = v;
    }
}

// ---------------- bf16 MFMA GEMM: fused K+V projection ----------------------
// Writes head-blocked bf16: Kb[b][h][s][32], Vb[b][h][s][32].
#define TM 128
#define TN 128
#define TK 32
#define LSTR 40

__global__ __launch_bounds__(256, 2) void gemm_kv_mfma(
        const float* __restrict__ A, const float* __restrict__ W,
        const float* __restrict__ bias,
        unsigned short* __restrict__ Kb, unsigned short* __restrict__ Vb,
        int M, int K) {
    __shared__ unsigned short As[TM][LSTR];
    __shared__ unsigned short Bs[TN][LSTR];
    int tid = threadIdx.x;
    int wave = tid / 64, lane = tid % 64;
    int m0 = blockIdx.y * TM, n0 = blockIdx.x * TN;
    int wm = (wave % 2) * 64, wn = (wave / 2) * 64;
    int lr = tid / 4;
    int lc = (tid % 4) * 8;
    int fr = lane % 16, quad = lane / 16;

    f32x4 acc[4][4] = {};

    for (int k0 = 0; k0 < K; k0 += TK) {
        __syncthreads();
#pragma unroll
        for (int half = 0; half < 2; half++) {
            int r = lr + half * 64;
            float4 a0 = *(const float4*)(A + (size_t)(m0 + r) * K + k0 + lc);
            float4 a1 = *(const float4*)(A + (size_t)(m0 + r) * K + k0 + lc + 4);
            uint4 pa;
            pa.x = (unsigned)f2bf(a0.x) | ((unsigned)f2bf(a0.y) << 16);
            pa.y = (unsigned)f2bf(a0.z) | ((unsigned)f2bf(a0.w) << 16);
            pa.z = (unsigned)f2bf(a1.x) | ((unsigned)f2bf(a1.y) << 16);
            pa.w = (unsigned)f2bf(a1.z) | ((unsigned)f2bf(a1.w) << 16);
            *(uint4*)&As[r][lc] = pa;
            float4 b0 = *(const float4*)(W + (size_t)(n0 + r) * K + k0 + lc);
            float4 b1 = *(const float4*)(W + (size_t)(n0 + r) * K + k0 + lc + 4);
            uint4 pb;
            pb.x = (unsigned)f2bf(b0.x) | ((unsigned)f2bf(b0.y) << 16);
            pb.y = (unsigned)f2bf(b0.z) | ((unsigned)f2bf(b0.w) << 16);
            pb.z = (unsigned)f2bf(b1.x) | ((unsigned)f2bf(b1.y) << 16);
            pb.w = (unsigned)f2bf(b1.z) | ((unsigned)f2bf(b1.w) << 16);
            *(uint4*)&Bs[r][lc] = pb;
        }
        __syncthreads();
        bf16x8 af[4], bf[4];
#pragma unroll
        for (int mi = 0; mi < 4; mi++)
            af[mi] = *(const bf16x8*)&As[wm + mi * 16 + fr][quad * 8];
#pragma unroll
        for (int ni = 0; ni < 4; ni++)
            bf[ni] = *(const bf16x8*)&Bs[wn + ni * 16 + fr][quad * 8];
#pragma unroll
        for (int mi = 0; mi < 4; mi++)
#pragma unroll
            for (int ni = 0; ni < 4; ni++)
                acc[mi][ni] = __builtin_amdgcn_mfma_f32_16x16x32_bf16(
                    af[mi], bf[ni], acc[mi][ni], 0, 0, 0);
    }

#pragma unroll
    for (int ni = 0; ni < 4; ni++) {
        int n = n0 + wn + ni * 16 + fr;          // 0..511
        float bv = bias[n];
        unsigned short* dst = (n < 256) ? Kb : Vb;
        int hh = (n >> 5) & 7;
        int d = n & 31;
#pragma unroll
        for (int mi = 0; mi < 4; mi++) {
#pragma unroll
            for (int r = 0; r < 4; r++) {
                int m = m0 + wm + mi * 16 + quad * 4 + r;
                int bb = m >> 12;                 // m / SS
                int s = m & (SS - 1);
                dst[((((size_t)bb * HH + hh) * SS + s) << 5) + d] =
                    f2bf(acc[mi][ni][r] + bv);
            }
        }
    }
}

// ---------------- MFMA flash cross-attention, split-S, 64-q tiles -----------
#define QT 64
#define ST 128

__global__ __launch_bounds__(256) void cross_attn_mfma(
        const float* __restrict__ Qm,
        const unsigned short* __restrict__ Kb,   // [b][h][s][32] bf16
        const unsigned short* __restrict__ Vb,   // [b][h][s][32] bf16
        const unsigned* __restrict__ Mbits,      // [B*BQ][128]
        float* __restrict__ Opart,
        float* __restrict__ mpart,
        float* __restrict__ lpart) {
    __shared__ unsigned short Qs[QT][40];
    __shared__ unsigned short Ks[ST][40];
    __shared__ unsigned short Vt[HDD][136];
    __shared__ unsigned short Ps[QT][136];
    __shared__ unsigned Mq[QT][4];
    __shared__ float red[QT][17];
    __shared__ float m_s[QT], alpha_s[QT], l_s[QT];

    const int qb = blockIdx.x, h = blockIdx.y;
    const int b = blockIdx.z / NSPLIT, sp = blockIdx.z % NSPLIT;
    const int t = threadIdx.x;
    const int w = t >> 6, lane = t & 63;
    const int fr = lane & 15, quad = lane >> 4;
    const int q0 = qb * QT;
    const int qlim = min(BQ - q0, QT);           // 64 or 36

    {
        int q = t >> 2, c0 = (t & 3) * 8;
        float4 v0 = make_float4(0.f, 0.f, 0.f, 0.f), v1 = v0;
        if (q < qlim) {
            const float* qp = Qm + (size_t)(b * BQ + q0 + q) * DD + h * HDD + c0;
            v0 = *(const float4*)qp;
            v1 = *(const float4*)(qp + 4);
        }
        const float sc = 0.17677669529663687f;
        uint4 pq;
        pq.x = (unsigned)f2bf(v0.x * sc) | ((unsigned)f2bf(v0.y * sc) << 16);
        pq.y = (unsigned)f2bf(v0.z * sc) | ((unsigned)f2bf(v0.w * sc) << 16);
        pq.z = (unsigned)f2bf(v1.x * sc) | ((unsigned)f2bf(v1.y * sc) << 16);
        pq.w = (unsigned)f2bf(v1.z * sc) | ((unsigned)f2bf(v1.w * sc) << 16);
        *(uint4*)&Qs[q][c0] = pq;
        if (t < QT) { m_s[t] = -1e30f; l_s[t] = 0.f; }
    }

    f32x4 oacc[2] = {};
    const unsigned short* Kbase = Kb + (((size_t)(b * HH + h)) * SS << 5);
    const unsigned short* Vbase = Vb + (((size_t)(b * HH + h)) * SS << 5);

    for (int s0 = sp * SCHUNK; s0 < (sp + 1) * SCHUNK; s0 += ST) {
        __syncthreads();
        {
            int r = t >> 1, half = t & 1;
            const unsigned short* kp = Kbase + ((size_t)(s0 + r) << 5) + half * 16;
            *(uint4*)&Ks[r][half * 16] = *(const uint4*)kp;
            *(uint4*)&Ks[r][half * 16 + 8] = *(const uint4*)(kp + 8);
            const unsigned short* vp = Vbase + ((size_t)(s0 + r) << 5) + half * 16;
            union { uint4 u; unsigned short s[8]; } v0, v1;
            v0.u = *(const uint4*)vp;
            v1.u = *(const uint4*)(vp + 8);
#pragma unroll
            for (int j = 0; j < 8; j++) Vt[half * 16 + j][r] = v0.s[j];
#pragma unroll
            for (int j = 0; j < 8; j++) Vt[half * 16 + 8 + j][r] = v1.s[j];
        }
        {
            int q = t >> 2, wd = t & 3;
            unsigned mword = 0xFFFFFFFFu;
            if (q < qlim)
                mword = Mbits[(size_t)(b * BQ + q0 + q) * 128 + (s0 >> 5) + wd];
            Mq[q][wd] = mword;
        }
        __syncthreads();

        bf16x8 af[2];
#pragma unroll
        for (int mt = 0; mt < 2; mt++)
            af[mt] = *(const bf16x8*)&Ks[w * 32 + mt * 16 + fr][quad * 8];
        f32x4 st[2][4];
#pragma unroll
        for (int nt = 0; nt < 4; nt++) {
            bf16x8 bq = *(const bf16x8*)&Qs[nt * 16 + fr][quad * 8];
#pragma unroll
            for (int mt = 0; mt < 2; mt++) {
                f32x4 z = {0.f, 0.f, 0.f, 0.f};
                st[mt][nt] = __builtin_amdgcn_mfma_f32_16x16x32_bf16(af[mt], bq, z, 0, 0, 0);
            }
        }

        float pmax[4] = {-1e30f, -1e30f, -1e30f, -1e30f};
#pragma unroll
        for (int nt = 0; nt < 4; nt++) {
            unsigned mword = Mq[nt * 16 + fr][w];
#pragma unroll
            for (int mt = 0; mt < 2; mt++)
#pragma unroll
                for (int r = 0; r < 4; r++) {
                    int bitpos = mt * 16 + quad * 4 + r;
                    float v = st[mt][nt][r];
                    if (!((mword >> bitpos) & 1u)) v -= 10000.f;
                    st[mt][nt][r] = v;
                    pmax[nt] = fmaxf(pmax[nt], v);
                }
        }
#pragma unroll
        for (int nt = 0; nt < 4; nt++)
            red[nt * 16 + fr][w * 4 + quad] = pmax[nt];
        __syncthreads();

        if (t < QT) {
            float mt_ = -1e30f;
#pragma unroll
            for (int k = 0; k < 16; k++) mt_ = fmaxf(mt_, red[t][k]);
            float mo = m_s[t], mn = fmaxf(mo, mt_);
            m_s[t] = mn;
            alpha_s[t] = __expf(mo - mn);
        }
        __syncthreads();

        float psum[4] = {0.f, 0.f, 0.f, 0.f};
#pragma unroll
        for (int nt = 0; nt < 4; nt++) {
            float mrow = m_s[nt * 16 + fr];
#pragma unroll
            for (int mt = 0; mt < 2; mt++) {
                float p0 = __expf(st[mt][nt][0] - mrow);
                float p1 = __expf(st[mt][nt][1] - mrow);
                float p2 = __expf(st[mt][nt][2] - mrow);
                float p3 = __expf(st[mt][nt][3] - mrow);
                psum[nt] += p0 + p1 + p2 + p3;
                ushort4 pk;
                pk.x = f2bf(p0); pk.y = f2bf(p1); pk.z = f2bf(p2); pk.w = f2bf(p3);
                *(ushort4*)&Ps[nt * 16 + fr][w * 32 + mt * 16 + quad * 4] = pk;
            }
        }
#pragma unroll
        for (int nt = 0; nt < 4; nt++)
            red[nt * 16 + fr][w * 4 + quad] = psum[nt];
        __syncthreads();

        if (t < QT) {
            float s = 0.f;
#pragma unroll
            for (int k = 0; k < 16; k++) s += red[t][k];
            l_s[t] = l_s[t] * alpha_s[t] + s;
        }

#pragma unroll
        for (int r = 0; r < 4; r++) {
            float a = alpha_s[w * 16 + quad * 4 + r];
            oacc[0][r] *= a; oacc[1][r] *= a;
        }
#pragma unroll
        for (int k0 = 0; k0 < ST; k0 += 32) {
            bf16x8 ap = *(const bf16x8*)&Ps[w * 16 + fr][k0 + quad * 8];
            bf16x8 bv0 = *(const bf16x8*)&Vt[fr][k0 + quad * 8];
            bf16x8 bv1 = *(const bf16x8*)&Vt[16 + fr][k0 + quad * 8];
            oacc[0] = __builtin_amdgcn_mfma_f32_16x16x32_bf16(ap, bv0, oacc[0], 0, 0, 0);
            oacc[1] = __builtin_amdgcn_mfma_f32_16x16x32_bf16(ap, bv1, oacc[1], 0, 0, 0);
        }
    }
    __syncthreads();

    int part = b * NSPLIT + sp;
    if (t < qlim) {
        mpart[((size_t)part * HH + h) * BQ + q0 + t] = m_s[t];
        lpart[((size_t)part * HH + h) * BQ + q0 + t] = l_s[t];
    }
#pragma unroll
    for (int nd = 0; nd < 2; nd++) {
#pragma unroll
        for (int r = 0; r < 4; r++) {
            int q = w * 16 + quad * 4 + r;
            if (q < qlim)
                Opart[((size_t)part * BQ + q0 + q) * DD + h * HDD + nd * 16 + fr] = oacc[nd][r];
        }
    }
}

// ---------------- self-attention (S=Q=100), slim LDS ------------------------
__global__ void attn_kernel(const float* __restrict__ Qm, int sq, int qo0,
                            const float* __restrict__ Km, int sk, int ko0,
                            const float* __restrict__ Vm, int sv, int vo0,
                            float* __restrict__ Out, int so, int oo0,
                            int Slen, int Qlen, float scale) {
    int q = blockIdx.x, h = blockIdx.y, b = blockIdx.z;
    int tid = threadIdx.x;
    __shared__ float qv[32];
    __shared__ float sc[128];
    __shared__ float red[256];
    __shared__ float part[8][33];
    int qrow = b * Qlen + q;
    if (tid < 32) qv[tid] = Qm[(size_t)qrow * sq + qo0 + h * HDD + tid] * scale;
    __syncthreads();

    float lmax = -1e30f;
    for (int s = tid; s < Slen; s += 256) {
        const float* kp = Km + (size_t)(b * Slen + s) * sk + ko0 + h * HDD;
        float dot = 0.f;
#pragma unroll
        for (int d = 0; d < HDD; d += 4) {
            float4 k4 = *(const float4*)(kp + d);
            dot += qv[d] * k4.x + qv[d + 1] * k4.y + qv[d + 2] * k4.z + qv[d + 3] * k4.w;
        }
        sc[s] = dot;
        lmax = fmaxf(lmax, dot);
    }
    red[tid] = lmax; __syncthreads();
    for (int off = 128; off > 0; off >>= 1) {
        if (tid < off) red[tid] = fmaxf(red[tid], red[tid + off]);
        __syncthreads();
    }
    float m = red[0];
    __syncthreads();
    float lsum = 0.f;
    for (int s = tid; s < Slen; s += 256) {
        float e = __expf(sc[s] - m);
        sc[s] = e;
        lsum += e;
    }
    red[tid] = lsum; __syncthreads();
    for (int off = 128; off > 0; off >>= 1) {
        if (tid < off) red[tid] += red[tid + off];
        __syncthreads();
    }
    float inv = 1.0f / red[0];

    int d = tid & 31, g = tid >> 5;
    float acc = 0.f;
    for (int s = g; s < Slen; s += 8)
        acc += sc[s] * Vm[(size_t)(b * Slen + s) * sv + vo0 + h * HDD + d];
    part[g][d] = acc; __syncthreads();
    if (g == 0) {
        float t = 0.f;
#pragma unroll
        for (int gg = 0; gg < 8; gg++) t += part[gg][d];
        Out[(size_t)qrow * so + oo0 + h * HDD + d] = t * inv;
    }
}

extern "C" void kernel_launch(void* const* d_in, const int* in_sizes, int n_in,
                              void* d_out, int out_size, void* d_ws, size_t ws_size,
                              hipStream_t stream) {
    const float* queries    = (const float*)d_in[0];
    const float* pixel_feat = (const float*)d_in[1];
    const float* prev_mask  = (const float*)d_in[2];
    const float* cross_in_w  = (const float*)d_in[3];
    const float* cross_in_b  = (const float*)d_in[4];
    const float* cross_out_w = (const float*)d_in[5];
    const float* cross_out_b = (const float*)d_in[6];
    const float* self_in_w   = (const float*)d_in[7];
    const float* self_in_b   = (const float*)d_in[8];
    const float* self_out_w  = (const float*)d_in[9];
    const float* self_out_b  = (const float*)d_in[10];
    const float* ln_cross_g  = (const float*)d_in[11];
    const float* ln_cross_b  = (const float*)d_in[12];
    const float* ln_self_g   = (const float*)d_in[13];
    const float* ln_self_b   = (const float*)d_in[14];
    const float* ln_ffn_g    = (const float*)d_in[15];
    const float* ln_ffn_b    = (const float*)d_in[16];
    const float* ffn_w1 = (const float*)d_in[17];
    const float* ffn_b1 = (const float*)d_in[18];
    const float* ffn_w2 = (const float*)d_in[19];
    const float* ffn_b2 = (const float*)d_in[20];
    float* out = (float*)d_out;

    const int NQ = SB * BQ;        // 800
    const int NK = SB * SS;        // 32768

    float* ws = (float*)d_ws;
    unsigned* Mbits = (unsigned*)ws;   ws += (size_t)NQ * 128;
    float* q_cross  = ws;              ws += (size_t)NQ * DD;
    unsigned short* Kbk = (unsigned short*)ws;
    ws += (size_t)NK * DD / 2;         // 16 MB
    unsigned short* Vbk = (unsigned short*)ws;
    ws += (size_t)NK * DD / 2;         // 16 MB
    float* queries1 = ws;              ws += (size_t)NQ * DD;
    float* qkv      = ws;              ws += (size_t)NQ * 3 * DD;
    float* attn2    = ws;              ws += (size_t)NQ * DD;
    float* queries2 = ws;              ws += (size_t)NQ * DD;
    float* ffn_h    = ws;              ws += (size_t)NQ * 4 * DD;
    float* Csplit   = ws;              ws += (size_t)4 * MROWS * DD;
    float* Opart    = ws;              ws += (size_t)SB * NSPLIT * BQ * DD;
    float* mpart    = ws;              ws += (size_t)SB * NSPLIT * HH * BQ;
    float* lpart    = ws;              ws += (size_t)SB * NSPLIT * HH * BQ;

    const float scale = 0.17677669529663687f;

    maskpack_kernel<<<NQ, 256, 0, stream>>>(prev_mask, Mbits);

    // ---- cross attention ----
    ln_gemm<0><<<dim3(8, 25), 64, 0, stream>>>(
        queries, ln_cross_g, ln_cross_b, cross_in_w, cross_in_b, nullptr,
        q_cross, DD);
    gemm_kv_mfma<<<dim3(2 * DD / TN, NK / TM), 256, 0, stream>>>(
        pixel_feat, cross_in_w + (size_t)DD * DD, cross_in_b + DD,
        Kbk, Vbk, NK, DD);
    cross_attn_mfma<<<dim3(2, HH, SB * NSPLIT), 256, 0, stream>>>(
        q_cross, Kbk, Vbk, Mbits, Opart, mpart, lpart);
    comb_gemm<<<dim3(8, 25), 64, 0, stream>>>(
        Opart, mpart, lpart, cross_out_w, cross_out_b, queries, queries1);

    // ---- self attention ----
    ln_gemm<0><<<dim3(24, 25), 64, 0, stream>>>(
        queries1, ln_self_g, ln_self_b, self_in_w, self_in_b, nullptr,
        qkv, 3 * DD);
    attn_kernel<<<dim3(BQ, HH, SB), 256, 0, stream>>>(
        qkv, 3 * DD, 0, qkv, 3 * DD, DD, qkv, 3 * DD, 2 * DD,
        attn2, DD, 0, BQ, BQ, scale);
    gemm_skinny2<256, 1, 2><<<dim3(8, 25), 64, 0, stream>>>(
        attn2, self_out_w, self_out_b, queries1, queries2, nullptr, DD);

    // ---- FFN ----
    ln_gemm<1><<<dim3(32, 25), 64, 0, stream>>>(
        queries2, ln_ffn_g, ln_ffn_b, ffn_w1, ffn_b1, nullptr,
        ffn_h, 4 * DD);
    gemm_skinny2<1024, 4, 2><<<dim3(8, 25, 4), 64, 0, stream>>>(
        ffn_h, ffn_w2, ffn_b2, nullptr, nullptr, Csplit, DD);
    gemm_combine<4, 2><<<MROWS, 256, 0, stream>>>(
        Csplit, ffn_b2, queries2, out, DD);
}